// Round 6
// baseline (362.268 us; speedup 1.0000x reference)
//
#include <hip/hip_runtime.h>
#include <cfloat>
#include <cstdint>

// Problem constants (B=4, N=2048, C=64, O=64, K=20)
#define M_TOTAL 8192
#define KNN 20
#define PPART 8                  // candidate partitions
#define CPB (M_TOTAL / PPART)    // 1024 candidates per K1b block
#define QT 64                    // queries per K1 block
#define SAMPLE 1024              // tau sample = candidates [0, 1024)
#define CAP 64                   // collect capacity per (query,partition)
#define SLOTS (PPART * CAP)      // 512
#define GCAP 32                  // guard-collect cap in k2a

typedef __attribute__((ext_vector_type(8))) short bf16x8;  // 8 bf16 (4 VGPRs)
typedef __attribute__((ext_vector_type(4))) float f32x4;

__device__ __forceinline__ unsigned short bf16rne(float x) {
  unsigned u = __float_as_uint(x);
  return (unsigned short)((u + 0x7FFFu + ((u >> 16) & 1u)) >> 16);
}

// ---------------------------------------------------------------------------
// K0: per-point precompute. sq, bf16-split pos, factored layer-1 (a, g).
// ---------------------------------------------------------------------------
__global__ __launch_bounds__(256) void k0_pre(
    const float* __restrict__ pos, const float* __restrict__ feat,
    const float* __restrict__ W1, const float* __restrict__ b1,
    float* __restrict__ sq, float* __restrict__ a_out, float* __restrict__ g_out,
    unsigned short* __restrict__ poshi, unsigned short* __restrict__ poslo) {
  __shared__ float fLds[4][64];
  const int lane = threadIdx.x & 63;
  const int rl = threadIdx.x >> 6;
  const int r = blockIdx.x * 4 + rl;

  float p = pos[r * 64 + lane];
  float f = feat[r * 64 + lane];
  fLds[rl][lane] = f;  // wave-private row; wave lockstep

  unsigned hib = bf16rne(p);
  float lof = p - __uint_as_float((unsigned)hib << 16);
  poshi[r * 64 + lane] = (unsigned short)hib;
  poslo[r * 64 + lane] = bf16rne(lof);

  float s = p * p;
#pragma unroll
  for (int off = 1; off < 64; off <<= 1) s += __shfl_xor(s, off, 64);
  if (lane == 0) sq[r] = s;

  float acc_a = b1[lane];
  float acc_g = 0.f;
  const float4* f4 = reinterpret_cast<const float4*>(fLds[rl]);
#pragma unroll
  for (int i = 0; i < 16; ++i) {
    float4 fv = f4[i];
    float fd[4] = {fv.x, fv.y, fv.z, fv.w};
#pragma unroll
    for (int j = 0; j < 4; ++j) {
      int d = 4 * i + j;
      float wt = W1[d * 64 + lane];
      float wb = W1[(64 + d) * 64 + lane];
      acc_a = fmaf(fd[j], wt - wb, acc_a);
      acc_g = fmaf(fd[j], wb, acc_g);
    }
  }
  a_out[r * 64 + lane] = acc_a;
  g_out[r * 64 + lane] = acc_g;
}

// ---------------------------------------------------------------------------
// K0b: swizzle W2 into bf16 B-fragment layout for 16x16x32 MFMA.
// Frag f = seg*4 + t (seg = K-half, t = N-tile): element (lane, j) =
// W2[seg*32 + (lane>>4)*8 + j][t*16 + (lane&15)].
// ---------------------------------------------------------------------------
__global__ __launch_bounds__(256) void k0b_w2sw(
    const float* __restrict__ W2, unsigned short* __restrict__ w2sw) {
  const int u = blockIdx.x * 256 + threadIdx.x;  // [0, 512)
  const int f = u >> 6, lane = u & 63;
  const int seg = f >> 2, t = f & 3;
  const int quad = lane >> 4, col = lane & 15;
#pragma unroll
  for (int j = 0; j < 8; ++j) {
    int d = seg * 32 + quad * 8 + j;
    w2sw[u * 8 + j] = bf16rne(W2[d * 64 + t * 16 + col]);
  }
}

// ---------------------------------------------------------------------------
// MFMA stripe: 64 queries x 16 candidates, K=64, bf16-split 3-product.
// A[m=lane&15][k=quad*8+j]; D: col=lane&15, row=quad*4+reg (m89-verified).
// ---------------------------------------------------------------------------
__device__ __forceinline__ void mfma_stripe(
    const unsigned short* __restrict__ poshi,
    const unsigned short* __restrict__ poslo,
    const bf16x8 (&Ahi)[4][2], const bf16x8 (&Alo)[4][2],
    int candRow, int dimOff, f32x4 (&acc)[4]) {
  const bf16x8 Bhi0 = *(const bf16x8*)(poshi + (size_t)candRow * 64 + dimOff);
  const bf16x8 Bhi1 = *(const bf16x8*)(poshi + (size_t)candRow * 64 + dimOff + 32);
  const bf16x8 Blo0 = *(const bf16x8*)(poslo + (size_t)candRow * 64 + dimOff);
  const bf16x8 Blo1 = *(const bf16x8*)(poslo + (size_t)candRow * 64 + dimOff + 32);
#pragma unroll
  for (int s = 0; s < 4; ++s) {
    f32x4 a = acc[s];
    a = __builtin_amdgcn_mfma_f32_16x16x32_bf16(Ahi[s][0], Bhi0, a, 0, 0, 0);
    a = __builtin_amdgcn_mfma_f32_16x16x32_bf16(Ahi[s][1], Bhi1, a, 0, 0, 0);
    a = __builtin_amdgcn_mfma_f32_16x16x32_bf16(Ahi[s][0], Blo0, a, 0, 0, 0);
    a = __builtin_amdgcn_mfma_f32_16x16x32_bf16(Ahi[s][1], Blo1, a, 0, 0, 0);
    a = __builtin_amdgcn_mfma_f32_16x16x32_bf16(Alo[s][0], Bhi0, a, 0, 0, 0);
    a = __builtin_amdgcn_mfma_f32_16x16x32_bf16(Alo[s][1], Bhi1, a, 0, 0, 0);
    acc[s] = a;
  }
}

// ---------------------------------------------------------------------------
// K1a: tau_q = exact 20th-smallest d-hat over the 1024-candidate sample.
// v3: selection cascade is UNCONDITIONAL value-only (2 ops/level) -- no
// divergence penalty (with 64 queries/wave the gated version fired every
// iteration anyway at wave level).
// ---------------------------------------------------------------------------
__global__ __launch_bounds__(256) void k1a_tau(
    const unsigned short* __restrict__ poshi,
    const unsigned short* __restrict__ poslo,
    const float* __restrict__ sq, float* __restrict__ tau_g) {
  __shared__ float vw[4][16][68];       // wave-private transpose
  __shared__ float sqcLds[SAMPLE];
  __shared__ float topLds[64][4][20];
  const int lane = threadIdx.x & 63;
  const int w = threadIdx.x >> 6;
  const int qbase = blockIdx.x * QT;
  const int col = lane & 15;
  const int quad = lane >> 4;
  const int dimOff = quad * 8;

  for (int i = threadIdx.x; i < SAMPLE; i += 256) sqcLds[i] = sq[i];

  bf16x8 Ahi[4][2], Alo[4][2];
#pragma unroll
  for (int s = 0; s < 4; ++s) {
    int row = qbase + s * 16 + col;
    Ahi[s][0] = *(const bf16x8*)(poshi + (size_t)row * 64 + dimOff);
    Ahi[s][1] = *(const bf16x8*)(poshi + (size_t)row * 64 + dimOff + 32);
    Alo[s][0] = *(const bf16x8*)(poslo + (size_t)row * 64 + dimOff);
    Alo[s][1] = *(const bf16x8*)(poslo + (size_t)row * 64 + dimOff + 32);
  }
  __syncthreads();

  const f32x4 zf = {0.f, 0.f, 0.f, 0.f};
  float bd[KNN];
#pragma unroll
  for (int k = 0; k < KNN; ++k) bd[k] = FLT_MAX;

  for (int c0 = 0; c0 < SAMPLE; c0 += 64) {
    const int candRow = c0 + w * 16 + col;
    f32x4 acc[4] = {zf, zf, zf, zf};
    mfma_stripe(poshi, poslo, Ahi, Alo, candRow, dimOff, acc);
    const float sqcv = sqcLds[candRow] + 256.0f;
#pragma unroll
    for (int s = 0; s < 4; ++s) {
      float4 v4;
      v4.x = fmaf(-2.f, acc[s][0], sqcv);
      v4.y = fmaf(-2.f, acc[s][1], sqcv);
      v4.z = fmaf(-2.f, acc[s][2], sqcv);
      v4.w = fmaf(-2.f, acc[s][3], sqcv);
      *reinterpret_cast<float4*>(&vw[w][col][s * 16 + quad * 4]) = v4;
    }
    __builtin_amdgcn_wave_barrier();
#pragma unroll
    for (int i = 0; i < 16; ++i) {
      float cd = vw[w][i][lane];
#pragma unroll
      for (int k = 0; k < KNN; ++k) {  // branch-free sorted insert
        float lo = fminf(cd, bd[k]);
        cd = fmaxf(cd, bd[k]);
        bd[k] = lo;
      }
    }
    __builtin_amdgcn_wave_barrier();
  }

#pragma unroll
  for (int k = 0; k < KNN; ++k) topLds[lane][w][k] = bd[k];
  __syncthreads();

  if (threadIdx.x < QT) {
    const int q = threadIdx.x;
    int p0 = 0, p1 = 0, p2 = 0, p3 = 0;
    float tau = FLT_MAX;
    for (int k = 0; k < KNN; ++k) {
      float v0 = (p0 < KNN) ? topLds[q][0][p0] : FLT_MAX;
      float v1 = (p1 < KNN) ? topLds[q][1][p1] : FLT_MAX;
      float v2 = (p2 < KNN) ? topLds[q][2][p2] : FLT_MAX;
      float v3 = (p3 < KNN) ? topLds[q][3][p3] : FLT_MAX;
      float m = fminf(fminf(v0, v1), fminf(v2, v3));
      if (m == v0) p0++;
      else if (m == v1) p1++;
      else if (m == v2) p2++;
      else p3++;
      tau = m;
    }
    tau_g[qbase + q] = tau;
  }
}

// ---------------------------------------------------------------------------
// K1b: MFMA pass over a 1024-candidate partition; collect val <= tau_q as
// packed u32 key (19-bit truncated val-float-bits | 13-bit idx).
// ---------------------------------------------------------------------------
__global__ __launch_bounds__(256) void k1b_collect(
    const unsigned short* __restrict__ poshi,
    const unsigned short* __restrict__ poslo,
    const float* __restrict__ sq, const float* __restrict__ tau_g,
    unsigned* __restrict__ list, unsigned* __restrict__ cnt_ws) {
  __shared__ float sqcLds[CPB];
  __shared__ float tauLds[QT];
  __shared__ unsigned cntLds[QT];

  const int lane = threadIdx.x & 63;
  const int w = threadIdx.x >> 6;
  const int qbase = blockIdx.x * QT;
  const int cbase = blockIdx.y * CPB;
  const int col = lane & 15;
  const int quad = lane >> 4;
  const int dimOff = quad * 8;

  for (int i = threadIdx.x; i < CPB; i += 256) sqcLds[i] = sq[cbase + i];
  if (threadIdx.x < QT) {
    tauLds[threadIdx.x] = tau_g[qbase + threadIdx.x];
    cntLds[threadIdx.x] = 0;
  }

  bf16x8 Ahi[4][2], Alo[4][2];
#pragma unroll
  for (int s = 0; s < 4; ++s) {
    int row = qbase + s * 16 + col;
    Ahi[s][0] = *(const bf16x8*)(poshi + (size_t)row * 64 + dimOff);
    Ahi[s][1] = *(const bf16x8*)(poshi + (size_t)row * 64 + dimOff + 32);
    Alo[s][0] = *(const bf16x8*)(poslo + (size_t)row * 64 + dimOff);
    Alo[s][1] = *(const bf16x8*)(poslo + (size_t)row * 64 + dimOff + 32);
  }
  __syncthreads();

  float tau_l[4][4];
#pragma unroll
  for (int s = 0; s < 4; ++s)
#pragma unroll
    for (int r = 0; r < 4; ++r) tau_l[s][r] = tauLds[s * 16 + quad * 4 + r];

  const f32x4 zf = {0.f, 0.f, 0.f, 0.f};
  for (int c0 = 0; c0 < CPB; c0 += 64) {
    const int candRow = cbase + c0 + w * 16 + col;
    f32x4 acc[4] = {zf, zf, zf, zf};
    mfma_stripe(poshi, poslo, Ahi, Alo, candRow, dimOff, acc);
    const float sqcv = sqcLds[c0 + w * 16 + col] + 256.0f;
#pragma unroll
    for (int s = 0; s < 4; ++s) {
#pragma unroll
      for (int r = 0; r < 4; ++r) {
        float val = fmaf(-2.f, acc[s][r], sqcv);
        const int qrow = s * 16 + quad * 4 + r;
        if (val <= tau_l[s][r]) {  // ~2% of lanes
          unsigned slot = atomicAdd(&cntLds[qrow], 1u);
          if (slot < CAP)
            list[(size_t)(qbase + qrow) * SLOTS + blockIdx.y * CAP + slot] =
                (__float_as_uint(val) & 0xFFFFE000u) | (unsigned)candRow;
        }
      }
    }
  }
  __syncthreads();
  if (threadIdx.x < QT) {
    unsigned c = cntLds[threadIdx.x];
    cnt_ws[(qbase + threadIdx.x) * PPART + blockIdx.y] = c > CAP ? CAP : c;
  }
}

// ---------------------------------------------------------------------------
// K2a: thread-per-query selection. Branch-free u32 cascade over the ~164
// collected keys -> 20th-smallest quant q20; collect quant <= q20+2 (guard
// covers d-hat error + quantization); exact fp32 d2 re-rank of those (<=32);
// write exact top-20 neighbor indices.
// ---------------------------------------------------------------------------
__global__ __launch_bounds__(256) void k2a_select(
    const float* __restrict__ pos, const float* __restrict__ sq,
    const unsigned* __restrict__ list, const unsigned* __restrict__ cnt_ws,
    int* __restrict__ nbr) {
  __shared__ unsigned candLds[256][GCAP];  // 32 KiB
  const int tid = threadIdx.x;
  const int q = blockIdx.x * 256 + tid;
  const unsigned* lq = list + (size_t)q * SLOTS;

  unsigned cnts[PPART];
#pragma unroll
  for (int p = 0; p < PPART; ++p) cnts[p] = cnt_ws[q * PPART + p];

  unsigned bd[KNN];
#pragma unroll
  for (int k = 0; k < KNN; ++k) bd[k] = 0xFFFFFFFFu;

#pragma unroll
  for (int p = 0; p < PPART; ++p) {
    const unsigned c = cnts[p];
    for (unsigned sl = 0; sl < c; ++sl) {
      unsigned cd = lq[p * CAP + sl];
#pragma unroll
      for (int k = 0; k < KNN; ++k) {  // branch-free u32 sorted insert
        unsigned lo = cd < bd[k] ? cd : bd[k];
        cd = cd < bd[k] ? bd[k] : cd;
        bd[k] = lo;
      }
    }
  }
  const unsigned T = (bd[KNN - 1] >> 13) + 2;

  int cc = 0;
#pragma unroll
  for (int p = 0; p < PPART; ++p) {
    const unsigned c = cnts[p];
    for (unsigned sl = 0; sl < c; ++sl) {
      unsigned kk = lq[p * CAP + sl];
      if ((kk >> 13) <= T && cc < GCAP) candLds[tid][cc++] = kk & 0x1FFFu;
    }
  }

  float qp[64];
  {
    const float4* qp4 = reinterpret_cast<const float4*>(pos + (size_t)q * 64);
#pragma unroll
    for (int i = 0; i < 16; ++i) {
      float4 v = qp4[i];
      qp[4 * i] = v.x; qp[4 * i + 1] = v.y; qp[4 * i + 2] = v.z; qp[4 * i + 3] = v.w;
    }
  }
  const float sqq = sq[q];

  unsigned long long kb[KNN];
#pragma unroll
  for (int k = 0; k < KNN; ++k) kb[k] = ~0ull;

  for (int j = 0; j < cc; ++j) {
    const unsigned idx = candLds[tid][j];
    const float4* cp4 = reinterpret_cast<const float4*>(pos + (size_t)idx * 64);
    float d0 = 0.f, d1 = 0.f, d2 = 0.f, d3 = 0.f;
#pragma unroll
    for (int t = 0; t < 16; ++t) {
      float4 cv = cp4[t];
      d0 = fmaf(cv.x, qp[4 * t], d0);
      d1 = fmaf(cv.y, qp[4 * t + 1], d1);
      d2 = fmaf(cv.z, qp[4 * t + 2], d2);
      d3 = fmaf(cv.w, qp[4 * t + 3], d3);
    }
    float dot = (d0 + d1) + (d2 + d3);
    float dd = fmaxf(fmaf(-2.f, dot, sqq + sq[idx]), 0.f);
    unsigned long long cd = ((unsigned long long)__float_as_uint(dd) << 32) | idx;
#pragma unroll
    for (int k = 0; k < KNN; ++k) {  // u64 sorted insert (tie -> smaller idx)
      unsigned long long lo = cd < kb[k] ? cd : kb[k];
      cd = cd < kb[k] ? kb[k] : cd;
      kb[k] = lo;
    }
  }
#pragma unroll
  for (int k = 0; k < KNN; ++k)
    nbr[q * KNN + k] = (int)(unsigned)(kb[k] & 0xFFFFFFFFu);
}

// ---------------------------------------------------------------------------
// K2b: MLP + max-aggregation via MFMA. One wave per query.
// H rows (20 real, padded to 32 by duplication -- harmless under max) built
// directly in A-frag registers from a_q + g_n (bf16 RNE); W2 pre-swizzled
// B-frags; 16 MFMAs; max over C rows (in-reg + cross-quad shfl); coalesced
// store. No LDS.
// ---------------------------------------------------------------------------
__global__ __launch_bounds__(256) void k2b_mlp(
    const float* __restrict__ a_in, const float* __restrict__ g_in,
    const unsigned short* __restrict__ w2sw, const float* __restrict__ b2,
    const int* __restrict__ nbr, float* __restrict__ out) {
  const int lane = threadIdx.x & 63;
  const int wv = threadIdx.x >> 6;
  const int q = blockIdx.x * 4 + wv;
  const int col = lane & 15;
  const int quad = lane >> 4;

  const int n0 = nbr[q * KNN + col];                    // M-rows 0..15 -> k 0..15
  const int n1 = nbr[q * KNN + ((16 + col) % KNN)];     // M-rows 16..31 -> k 16..19 + dups

  bf16x8 Bf[8];
#pragma unroll
  for (int f = 0; f < 8; ++f)
    Bf[f] = *(const bf16x8*)(w2sw + ((size_t)f * 64 + lane) * 8);

  const f32x4 zf = {0.f, 0.f, 0.f, 0.f};
  f32x4 acc0[4] = {zf, zf, zf, zf};
  f32x4 acc1[4] = {zf, zf, zf, zf};

#pragma unroll
  for (int seg = 0; seg < 2; ++seg) {
    const int dOff = seg * 32 + quad * 8;
    const float4* ap = reinterpret_cast<const float4*>(a_in + (size_t)q * 64 + dOff);
    const float4* g0p = reinterpret_cast<const float4*>(g_in + (size_t)n0 * 64 + dOff);
    const float4* g1p = reinterpret_cast<const float4*>(g_in + (size_t)n1 * 64 + dOff);
    float4 aa0 = ap[0], aa1 = ap[1];
    float4 gg0 = g0p[0], gg1 = g0p[1];
    float4 hh0 = g1p[0], hh1 = g1p[1];
    float av[8] = {aa0.x, aa0.y, aa0.z, aa0.w, aa1.x, aa1.y, aa1.z, aa1.w};
    float g0v[8] = {gg0.x, gg0.y, gg0.z, gg0.w, gg1.x, gg1.y, gg1.z, gg1.w};
    float g1v[8] = {hh0.x, hh0.y, hh0.z, hh0.w, hh1.x, hh1.y, hh1.z, hh1.w};
    bf16x8 A0, A1;
#pragma unroll
    for (int j = 0; j < 8; ++j) {
      A0[j] = (short)bf16rne(fmaxf(av[j] + g0v[j], 0.f));
      A1[j] = (short)bf16rne(fmaxf(av[j] + g1v[j], 0.f));
    }
#pragma unroll
    for (int t = 0; t < 4; ++t) {
      acc0[t] = __builtin_amdgcn_mfma_f32_16x16x32_bf16(A0, Bf[seg * 4 + t], acc0[t], 0, 0, 0);
      acc1[t] = __builtin_amdgcn_mfma_f32_16x16x32_bf16(A1, Bf[seg * 4 + t], acc1[t], 0, 0, 0);
    }
  }

  // epilogue: per N-tile, max over all 32 M-rows (4 regs x 4 quads x 2 tiles)
  float res = 0.f;
#pragma unroll
  for (int t = 0; t < 4; ++t) {
    float m = fmaxf(fmaxf(fmaxf(acc0[t][0], acc1[t][0]), fmaxf(acc0[t][1], acc1[t][1])),
                    fmaxf(fmaxf(acc0[t][2], acc1[t][2]), fmaxf(acc0[t][3], acc1[t][3])));
    m = fmaxf(m, __shfl_xor(m, 16, 64));
    m = fmaxf(m, __shfl_xor(m, 32, 64));
    res = (quad == t) ? m : res;  // o = t*16+col == lane iff quad==t
  }
  out[(size_t)q * 64 + lane] = res + b2[lane];
}

// ---------------------------------------------------------------------------
extern "C" void kernel_launch(void* const* d_in, const int* in_sizes, int n_in,
                              void* d_out, int out_size, void* d_ws, size_t ws_size,
                              hipStream_t stream) {
  const float* pos = (const float*)d_in[0];
  const float* feat = (const float*)d_in[1];
  const float* W1 = (const float*)d_in[2];
  const float* b1 = (const float*)d_in[3];
  const float* W2 = (const float*)d_in[4];
  const float* b2 = (const float*)d_in[5];
  float* out = (float*)d_out;

  // ws layout (bytes), total ~24.0 MiB:
  //   sq    @ 0         32 KiB
  //   a     @ 32768     2 MiB
  //   g     @ 2129920   2 MiB
  //   poshi @ 4227072   1 MiB
  //   poslo @ 5275648   1 MiB
  //   w2sw  @ 6324224   8 KiB
  //   list  @ 6332416   16 MiB  (8192 * 512 * 4, packed u32 keys)
  //   cnt   @ 23109632  256 KiB
  //   tau   @ 23371776  32 KiB
  //   nbr   @ 23404544  640 KiB (8192 * 20 * 4)
  char* ws = (char*)d_ws;
  float* sq = (float*)ws;
  float* a = (float*)(ws + 32768);
  float* g = (float*)(ws + 2129920);
  unsigned short* poshi = (unsigned short*)(ws + 4227072);
  unsigned short* poslo = (unsigned short*)(ws + 5275648);
  unsigned short* w2sw = (unsigned short*)(ws + 6324224);
  unsigned* list = (unsigned*)(ws + 6332416);
  unsigned* cnt_ws = (unsigned*)(ws + 23109632);
  float* tau_g = (float*)(ws + 23371776);
  int* nbr = (int*)(ws + 23404544);

  k0_pre<<<M_TOTAL / 4, 256, 0, stream>>>(pos, feat, W1, b1, sq, a, g, poshi, poslo);
  k0b_w2sw<<<2, 256, 0, stream>>>(W2, w2sw);
  k1a_tau<<<M_TOTAL / QT, 256, 0, stream>>>(poshi, poslo, sq, tau_g);
  k1b_collect<<<dim3(M_TOTAL / QT, PPART), 256, 0, stream>>>(poshi, poslo, sq, tau_g, list, cnt_ws);
  k2a_select<<<M_TOTAL / 256, 256, 0, stream>>>(pos, sq, list, cnt_ws, nbr);
  k2b_mlp<<<M_TOTAL / 4, 256, 0, stream>>>(a, g, w2sw, b2, nbr, out);
}

// Round 7
// 261.387 us; speedup vs baseline: 1.3859x; 1.3859x over previous
//
#include <hip/hip_runtime.h>
#include <cfloat>
#include <cstdint>

// Problem constants (B=4, N=2048, C=64, O=64, K=20)
#define M_TOTAL 8192
#define KNN 20
#define PPART 8                  // candidate partitions
#define CPB (M_TOTAL / PPART)    // 1024 candidates per K1b block
#define QT 64                    // queries per K1 block
#define SAMPLE 1024              // tau sample = candidates [0, 1024) = partition 0
#define CAP 64                   // collect capacity per (query,partition)
#define SLOTS (PPART * CAP)      // 512
#define GCAP 32                  // guard-collect cap in k2a

typedef __attribute__((ext_vector_type(8))) short bf16x8;  // 8 bf16 (4 VGPRs)
typedef __attribute__((ext_vector_type(4))) float f32x4;

__device__ __forceinline__ unsigned short bf16rne(float x) {
  unsigned u = __float_as_uint(x);
  return (unsigned short)((u + 0x7FFFu + ((u >> 16) & 1u)) >> 16);
}

// ---------------------------------------------------------------------------
// K0: per-point precompute. sq, bf16-split pos, factored layer-1 (a, g).
// ---------------------------------------------------------------------------
__global__ __launch_bounds__(256) void k0_pre(
    const float* __restrict__ pos, const float* __restrict__ feat,
    const float* __restrict__ W1, const float* __restrict__ b1,
    float* __restrict__ sq, float* __restrict__ a_out, float* __restrict__ g_out,
    unsigned short* __restrict__ poshi, unsigned short* __restrict__ poslo) {
  __shared__ float fLds[4][64];
  const int lane = threadIdx.x & 63;
  const int rl = threadIdx.x >> 6;
  const int r = blockIdx.x * 4 + rl;

  float p = pos[r * 64 + lane];
  float f = feat[r * 64 + lane];
  fLds[rl][lane] = f;  // wave-private row; wave lockstep

  unsigned hib = bf16rne(p);
  float lof = p - __uint_as_float((unsigned)hib << 16);
  poshi[r * 64 + lane] = (unsigned short)hib;
  poslo[r * 64 + lane] = bf16rne(lof);

  float s = p * p;
#pragma unroll
  for (int off = 1; off < 64; off <<= 1) s += __shfl_xor(s, off, 64);
  if (lane == 0) sq[r] = s;

  float acc_a = b1[lane];
  float acc_g = 0.f;
  const float4* f4 = reinterpret_cast<const float4*>(fLds[rl]);
#pragma unroll
  for (int i = 0; i < 16; ++i) {
    float4 fv = f4[i];
    float fd[4] = {fv.x, fv.y, fv.z, fv.w};
#pragma unroll
    for (int j = 0; j < 4; ++j) {
      int d = 4 * i + j;
      float wt = W1[d * 64 + lane];
      float wb = W1[(64 + d) * 64 + lane];
      acc_a = fmaf(fd[j], wt - wb, acc_a);
      acc_g = fmaf(fd[j], wb, acc_g);
    }
  }
  a_out[r * 64 + lane] = acc_a;
  g_out[r * 64 + lane] = acc_g;
}

// ---------------------------------------------------------------------------
// K0b: swizzle W2 into bf16 B-fragment layout for 16x16x32 MFMA.
// ---------------------------------------------------------------------------
__global__ __launch_bounds__(256) void k0b_w2sw(
    const float* __restrict__ W2, unsigned short* __restrict__ w2sw) {
  const int u = blockIdx.x * 256 + threadIdx.x;  // [0, 512)
  const int f = u >> 6, lane = u & 63;
  const int seg = f >> 2, t = f & 3;
  const int quad = lane >> 4, col = lane & 15;
#pragma unroll
  for (int j = 0; j < 8; ++j) {
    int d = seg * 32 + quad * 8 + j;
    w2sw[u * 8 + j] = bf16rne(W2[d * 64 + t * 16 + col]);
  }
}

// ---------------------------------------------------------------------------
// MFMA stripe: 64 queries x 16 candidates, K=64, bf16-split 3-product.
// A[m=lane&15][k=quad*8+j]; D: col=lane&15, row=quad*4+reg (m89-verified).
// ---------------------------------------------------------------------------
__device__ __forceinline__ void mfma_stripe(
    const unsigned short* __restrict__ poshi,
    const unsigned short* __restrict__ poslo,
    const bf16x8 (&Ahi)[4][2], const bf16x8 (&Alo)[4][2],
    int candRow, int dimOff, f32x4 (&acc)[4]) {
  const bf16x8 Bhi0 = *(const bf16x8*)(poshi + (size_t)candRow * 64 + dimOff);
  const bf16x8 Bhi1 = *(const bf16x8*)(poshi + (size_t)candRow * 64 + dimOff + 32);
  const bf16x8 Blo0 = *(const bf16x8*)(poslo + (size_t)candRow * 64 + dimOff);
  const bf16x8 Blo1 = *(const bf16x8*)(poslo + (size_t)candRow * 64 + dimOff + 32);
#pragma unroll
  for (int s = 0; s < 4; ++s) {
    f32x4 a = acc[s];
    a = __builtin_amdgcn_mfma_f32_16x16x32_bf16(Ahi[s][0], Bhi0, a, 0, 0, 0);
    a = __builtin_amdgcn_mfma_f32_16x16x32_bf16(Ahi[s][1], Bhi1, a, 0, 0, 0);
    a = __builtin_amdgcn_mfma_f32_16x16x32_bf16(Ahi[s][0], Blo0, a, 0, 0, 0);
    a = __builtin_amdgcn_mfma_f32_16x16x32_bf16(Ahi[s][1], Blo1, a, 0, 0, 0);
    a = __builtin_amdgcn_mfma_f32_16x16x32_bf16(Alo[s][0], Bhi0, a, 0, 0, 0);
    a = __builtin_amdgcn_mfma_f32_16x16x32_bf16(Alo[s][1], Bhi1, a, 0, 0, 0);
    acc[s] = a;
  }
}

// ---------------------------------------------------------------------------
// K1a: tau_q = exact 20th-smallest d-hat over the 1024-candidate sample.
// ---------------------------------------------------------------------------
__global__ __launch_bounds__(256) void k1a_tau(
    const unsigned short* __restrict__ poshi,
    const unsigned short* __restrict__ poslo,
    const float* __restrict__ sq, float* __restrict__ tau_g) {
  __shared__ float vw[4][16][68];       // wave-private transpose
  __shared__ float sqcLds[SAMPLE];
  __shared__ float topLds[64][4][20];
  const int lane = threadIdx.x & 63;
  const int w = threadIdx.x >> 6;
  const int qbase = blockIdx.x * QT;
  const int col = lane & 15;
  const int quad = lane >> 4;
  const int dimOff = quad * 8;

  for (int i = threadIdx.x; i < SAMPLE; i += 256) sqcLds[i] = sq[i];

  bf16x8 Ahi[4][2], Alo[4][2];
#pragma unroll
  for (int s = 0; s < 4; ++s) {
    int row = qbase + s * 16 + col;
    Ahi[s][0] = *(const bf16x8*)(poshi + (size_t)row * 64 + dimOff);
    Ahi[s][1] = *(const bf16x8*)(poshi + (size_t)row * 64 + dimOff + 32);
    Alo[s][0] = *(const bf16x8*)(poslo + (size_t)row * 64 + dimOff);
    Alo[s][1] = *(const bf16x8*)(poslo + (size_t)row * 64 + dimOff + 32);
  }
  __syncthreads();

  const f32x4 zf = {0.f, 0.f, 0.f, 0.f};
  float bd[KNN];
#pragma unroll
  for (int k = 0; k < KNN; ++k) bd[k] = FLT_MAX;

  for (int c0 = 0; c0 < SAMPLE; c0 += 64) {
    const int candRow = c0 + w * 16 + col;
    f32x4 acc[4] = {zf, zf, zf, zf};
    mfma_stripe(poshi, poslo, Ahi, Alo, candRow, dimOff, acc);
    const float sqcv = sqcLds[candRow] + 256.0f;
#pragma unroll
    for (int s = 0; s < 4; ++s) {
      float4 v4;
      v4.x = fmaf(-2.f, acc[s][0], sqcv);
      v4.y = fmaf(-2.f, acc[s][1], sqcv);
      v4.z = fmaf(-2.f, acc[s][2], sqcv);
      v4.w = fmaf(-2.f, acc[s][3], sqcv);
      *reinterpret_cast<float4*>(&vw[w][col][s * 16 + quad * 4]) = v4;
    }
    __builtin_amdgcn_wave_barrier();
#pragma unroll
    for (int i = 0; i < 16; ++i) {
      float cd = vw[w][i][lane];
#pragma unroll
      for (int k = 0; k < KNN; ++k) {  // branch-free sorted insert
        float lo = fminf(cd, bd[k]);
        cd = fmaxf(cd, bd[k]);
        bd[k] = lo;
      }
    }
    __builtin_amdgcn_wave_barrier();
  }

#pragma unroll
  for (int k = 0; k < KNN; ++k) topLds[lane][w][k] = bd[k];
  __syncthreads();

  if (threadIdx.x < QT) {
    const int q = threadIdx.x;
    int p0 = 0, p1 = 0, p2 = 0, p3 = 0;
    float tau = FLT_MAX;
    for (int k = 0; k < KNN; ++k) {
      float v0 = (p0 < KNN) ? topLds[q][0][p0] : FLT_MAX;
      float v1 = (p1 < KNN) ? topLds[q][1][p1] : FLT_MAX;
      float v2 = (p2 < KNN) ? topLds[q][2][p2] : FLT_MAX;
      float v3 = (p3 < KNN) ? topLds[q][3][p3] : FLT_MAX;
      float m = fminf(fminf(v0, v1), fminf(v2, v3));
      if (m == v0) p0++;
      else if (m == v1) p1++;
      else if (m == v2) p2++;
      else p3++;
      tau = m;
    }
    tau_g[qbase + q] = tau;
  }
}

// ---------------------------------------------------------------------------
// K1b: MFMA pass over a 1024-candidate partition; collect val <= tau_q as
// packed u32 key (19-bit truncated val-float-bits | 13-bit idx).
// v2: TRANSPOSED output layout -- list[(p*CAP+slot)*M + q], cnt[p*M + q] --
// so K2a reads coalesce (lane = query).
// ---------------------------------------------------------------------------
__global__ __launch_bounds__(256) void k1b_collect(
    const unsigned short* __restrict__ poshi,
    const unsigned short* __restrict__ poslo,
    const float* __restrict__ sq, const float* __restrict__ tau_g,
    unsigned* __restrict__ list, unsigned* __restrict__ cnt_ws) {
  __shared__ float sqcLds[CPB];
  __shared__ float tauLds[QT];
  __shared__ unsigned cntLds[QT];

  const int lane = threadIdx.x & 63;
  const int w = threadIdx.x >> 6;
  const int qbase = blockIdx.x * QT;
  const int cbase = blockIdx.y * CPB;
  const int col = lane & 15;
  const int quad = lane >> 4;
  const int dimOff = quad * 8;

  for (int i = threadIdx.x; i < CPB; i += 256) sqcLds[i] = sq[cbase + i];
  if (threadIdx.x < QT) {
    tauLds[threadIdx.x] = tau_g[qbase + threadIdx.x];
    cntLds[threadIdx.x] = 0;
  }

  bf16x8 Ahi[4][2], Alo[4][2];
#pragma unroll
  for (int s = 0; s < 4; ++s) {
    int row = qbase + s * 16 + col;
    Ahi[s][0] = *(const bf16x8*)(poshi + (size_t)row * 64 + dimOff);
    Ahi[s][1] = *(const bf16x8*)(poshi + (size_t)row * 64 + dimOff + 32);
    Alo[s][0] = *(const bf16x8*)(poslo + (size_t)row * 64 + dimOff);
    Alo[s][1] = *(const bf16x8*)(poslo + (size_t)row * 64 + dimOff + 32);
  }
  __syncthreads();

  float tau_l[4][4];
#pragma unroll
  for (int s = 0; s < 4; ++s)
#pragma unroll
    for (int r = 0; r < 4; ++r) tau_l[s][r] = tauLds[s * 16 + quad * 4 + r];

  const f32x4 zf = {0.f, 0.f, 0.f, 0.f};
  for (int c0 = 0; c0 < CPB; c0 += 64) {
    const int candRow = cbase + c0 + w * 16 + col;
    f32x4 acc[4] = {zf, zf, zf, zf};
    mfma_stripe(poshi, poslo, Ahi, Alo, candRow, dimOff, acc);
    const float sqcv = sqcLds[c0 + w * 16 + col] + 256.0f;
#pragma unroll
    for (int s = 0; s < 4; ++s) {
#pragma unroll
      for (int r = 0; r < 4; ++r) {
        float val = fmaf(-2.f, acc[s][r], sqcv);
        const int qrow = s * 16 + quad * 4 + r;
        if (val <= tau_l[s][r]) {  // ~2% of lanes
          unsigned slot = atomicAdd(&cntLds[qrow], 1u);
          if (slot < CAP)
            list[(size_t)(blockIdx.y * CAP + slot) * M_TOTAL + qbase + qrow] =
                (__float_as_uint(val) & 0xFFFFE000u) | (unsigned)candRow;
        }
      }
    }
  }
  __syncthreads();
  if (threadIdx.x < QT) {
    unsigned c = cntLds[threadIdx.x];
    cnt_ws[blockIdx.y * M_TOTAL + qbase + threadIdx.x] = c > CAP ? CAP : c;
  }
}

// ---------------------------------------------------------------------------
// K2a v2: selection, restructured for parallelism + coalescing.
// Block = 64 queries x 4 slices (256 thr), grid = 128 blocks.
// Ph1: slice s cascades top-20 (u32) over partitions {2s,2s+1} -- list reads
//      coalesced (lane = query).
// Ph2: thread/query merges 4 sorted lists -> 20th-smallest key -> guard T.
// Ph3: coalesced rescan, collect quant <= T (~21) via LDS atomic.
// Ph4: 4 thr/query exact fp32 d2 on <=8 cands each -> sorted-8 u64; merge
//      top-20 -> nbr. Identical final sets to round-6 semantics.
// ---------------------------------------------------------------------------
__global__ __launch_bounds__(256) void k2a_select(
    const float* __restrict__ pos, const float* __restrict__ sq,
    const unsigned* __restrict__ list, const unsigned* __restrict__ cnt_ws,
    int* __restrict__ nbr) {
  __shared__ unsigned topLds[4][QT][21];           // 21.5 KiB (pad 21)
  __shared__ unsigned TLds[QT];
  __shared__ unsigned ccnt[QT];
  __shared__ unsigned candLds[QT][GCAP];           // 8 KiB
  __shared__ unsigned long long rrLds[4][QT][9];   // 18.4 KiB (pad 9)

  const int l = threadIdx.x & 63;   // query lane
  const int s = threadIdx.x >> 6;   // slice: partitions 2s, 2s+1
  const int q = blockIdx.x * QT + l;

  // ---- phase 1: per-slice top-20 cascade over collected keys ----
  unsigned bd[KNN];
#pragma unroll
  for (int k = 0; k < KNN; ++k) bd[k] = 0xFFFFFFFFu;
#pragma unroll
  for (int pp = 0; pp < 2; ++pp) {
    const int p = s * 2 + pp;
    const unsigned c = cnt_ws[p * M_TOTAL + q];
    const unsigned* base = list + (size_t)(p * CAP) * M_TOTAL + q;
    for (unsigned sl = 0; sl < c; ++sl) {
      unsigned cd = base[(size_t)sl * M_TOTAL];  // coalesced across lanes
#pragma unroll
      for (int k = 0; k < KNN; ++k) {
        unsigned lo = cd < bd[k] ? cd : bd[k];
        cd = cd < bd[k] ? bd[k] : cd;
        bd[k] = lo;
      }
    }
  }
#pragma unroll
  for (int k = 0; k < KNN; ++k) topLds[s][l][k] = bd[k];
  __syncthreads();

  // ---- phase 2: 4-way merge -> global 20th-smallest key -> guard T ----
  if (s == 0) {
    unsigned i0 = 0, i1 = 0, i2 = 0, i3 = 0, m = 0;
    for (int k = 0; k < KNN; ++k) {
      unsigned v0 = (i0 < KNN) ? topLds[0][l][i0] : 0xFFFFFFFFu;
      unsigned v1 = (i1 < KNN) ? topLds[1][l][i1] : 0xFFFFFFFFu;
      unsigned v2 = (i2 < KNN) ? topLds[2][l][i2] : 0xFFFFFFFFu;
      unsigned v3 = (i3 < KNN) ? topLds[3][l][i3] : 0xFFFFFFFFu;
      unsigned m01 = v0 < v1 ? v0 : v1;
      unsigned m23 = v2 < v3 ? v2 : v3;
      m = m01 < m23 ? m01 : m23;
      if (m == v0) i0++;
      else if (m == v1) i1++;
      else if (m == v2) i2++;
      else i3++;
    }
    TLds[l] = (m >> 13) + 2;
    ccnt[l] = 0;
  }
  __syncthreads();

  // ---- phase 3: rescan, collect guard set (~21 per query) ----
  const unsigned T = TLds[l];
#pragma unroll
  for (int pp = 0; pp < 2; ++pp) {
    const int p = s * 2 + pp;
    const unsigned c = cnt_ws[p * M_TOTAL + q];
    const unsigned* base = list + (size_t)(p * CAP) * M_TOTAL + q;
    for (unsigned sl = 0; sl < c; ++sl) {
      unsigned kk = base[(size_t)sl * M_TOTAL];
      if ((kk >> 13) <= T) {
        unsigned pos_ = atomicAdd(&ccnt[l], 1u);
        if (pos_ < GCAP) candLds[l][pos_] = kk & 0x1FFFu;
      }
    }
  }
  __syncthreads();

  // ---- phase 4: exact fp32 d2 re-rank of the guard set ----
  const int cc = min(ccnt[l], (unsigned)GCAP);
  const float sqq = sq[q];
  const float4* qp4 = reinterpret_cast<const float4*>(pos + (size_t)q * 64);
  unsigned long long kb[8];
#pragma unroll
  for (int j = 0; j < 8; ++j) kb[j] = ~0ull;
  for (int j = s; j < cc; j += 4) {
    const unsigned idx = candLds[l][j];
    const float4* cp4 = reinterpret_cast<const float4*>(pos + (size_t)idx * 64);
    float d0 = 0.f, d1 = 0.f, d2 = 0.f, d3 = 0.f;
#pragma unroll
    for (int t = 0; t < 16; ++t) {
      float4 cv = cp4[t];
      float4 qv = qp4[t];  // L1-hot (reused across j and 4 slices)
      d0 = fmaf(cv.x, qv.x, d0);
      d1 = fmaf(cv.y, qv.y, d1);
      d2 = fmaf(cv.z, qv.z, d2);
      d3 = fmaf(cv.w, qv.w, d3);
    }
    float dot = (d0 + d1) + (d2 + d3);
    float dd = fmaxf(fmaf(-2.f, dot, sqq + sq[idx]), 0.f);
    unsigned long long cd = ((unsigned long long)__float_as_uint(dd) << 32) | idx;
#pragma unroll
    for (int k = 0; k < 8; ++k) {  // sorted-8 insert (tie -> smaller idx)
      unsigned long long lo = cd < kb[k] ? cd : kb[k];
      cd = cd < kb[k] ? kb[k] : cd;
      kb[k] = lo;
    }
  }
#pragma unroll
  for (int j = 0; j < 8; ++j) rrLds[s][l][j] = kb[j];
  __syncthreads();

  if (s == 0) {
    unsigned i0 = 0, i1 = 0, i2 = 0, i3 = 0;
    for (int k = 0; k < KNN; ++k) {
      unsigned long long v0 = (i0 < 8) ? rrLds[0][l][i0] : ~0ull;
      unsigned long long v1 = (i1 < 8) ? rrLds[1][l][i1] : ~0ull;
      unsigned long long v2 = (i2 < 8) ? rrLds[2][l][i2] : ~0ull;
      unsigned long long v3 = (i3 < 8) ? rrLds[3][l][i3] : ~0ull;
      unsigned long long m01 = v0 < v1 ? v0 : v1;
      unsigned long long m23 = v2 < v3 ? v2 : v3;
      unsigned long long m = m01 < m23 ? m01 : m23;
      if (m == v0) i0++;
      else if (m == v1) i1++;
      else if (m == v2) i2++;
      else i3++;
      nbr[q * KNN + k] = (int)(unsigned)(m & 0xFFFFFFFFu);
    }
  }
}

// ---------------------------------------------------------------------------
// K2b: MLP + max-aggregation via MFMA. One wave per query. (unchanged)
// ---------------------------------------------------------------------------
__global__ __launch_bounds__(256) void k2b_mlp(
    const float* __restrict__ a_in, const float* __restrict__ g_in,
    const unsigned short* __restrict__ w2sw, const float* __restrict__ b2,
    const int* __restrict__ nbr, float* __restrict__ out) {
  const int lane = threadIdx.x & 63;
  const int wv = threadIdx.x >> 6;
  const int q = blockIdx.x * 4 + wv;
  const int col = lane & 15;
  const int quad = lane >> 4;

  const int n0 = nbr[q * KNN + col];
  const int n1 = nbr[q * KNN + ((16 + col) % KNN)];

  bf16x8 Bf[8];
#pragma unroll
  for (int f = 0; f < 8; ++f)
    Bf[f] = *(const bf16x8*)(w2sw + ((size_t)f * 64 + lane) * 8);

  const f32x4 zf = {0.f, 0.f, 0.f, 0.f};
  f32x4 acc0[4] = {zf, zf, zf, zf};
  f32x4 acc1[4] = {zf, zf, zf, zf};

#pragma unroll
  for (int seg = 0; seg < 2; ++seg) {
    const int dOff = seg * 32 + quad * 8;
    const float4* ap = reinterpret_cast<const float4*>(a_in + (size_t)q * 64 + dOff);
    const float4* g0p = reinterpret_cast<const float4*>(g_in + (size_t)n0 * 64 + dOff);
    const float4* g1p = reinterpret_cast<const float4*>(g_in + (size_t)n1 * 64 + dOff);
    float4 aa0 = ap[0], aa1 = ap[1];
    float4 gg0 = g0p[0], gg1 = g0p[1];
    float4 hh0 = g1p[0], hh1 = g1p[1];
    float av[8] = {aa0.x, aa0.y, aa0.z, aa0.w, aa1.x, aa1.y, aa1.z, aa1.w};
    float g0v[8] = {gg0.x, gg0.y, gg0.z, gg0.w, gg1.x, gg1.y, gg1.z, gg1.w};
    float g1v[8] = {hh0.x, hh0.y, hh0.z, hh0.w, hh1.x, hh1.y, hh1.z, hh1.w};
    bf16x8 A0, A1;
#pragma unroll
    for (int j = 0; j < 8; ++j) {
      A0[j] = (short)bf16rne(fmaxf(av[j] + g0v[j], 0.f));
      A1[j] = (short)bf16rne(fmaxf(av[j] + g1v[j], 0.f));
    }
#pragma unroll
    for (int t = 0; t < 4; ++t) {
      acc0[t] = __builtin_amdgcn_mfma_f32_16x16x32_bf16(A0, Bf[seg * 4 + t], acc0[t], 0, 0, 0);
      acc1[t] = __builtin_amdgcn_mfma_f32_16x16x32_bf16(A1, Bf[seg * 4 + t], acc1[t], 0, 0, 0);
    }
  }

  float res = 0.f;
#pragma unroll
  for (int t = 0; t < 4; ++t) {
    float m = fmaxf(fmaxf(fmaxf(acc0[t][0], acc1[t][0]), fmaxf(acc0[t][1], acc1[t][1])),
                    fmaxf(fmaxf(acc0[t][2], acc1[t][2]), fmaxf(acc0[t][3], acc1[t][3])));
    m = fmaxf(m, __shfl_xor(m, 16, 64));
    m = fmaxf(m, __shfl_xor(m, 32, 64));
    res = (quad == t) ? m : res;
  }
  out[(size_t)q * 64 + lane] = res + b2[lane];
}

// ---------------------------------------------------------------------------
extern "C" void kernel_launch(void* const* d_in, const int* in_sizes, int n_in,
                              void* d_out, int out_size, void* d_ws, size_t ws_size,
                              hipStream_t stream) {
  const float* pos = (const float*)d_in[0];
  const float* feat = (const float*)d_in[1];
  const float* W1 = (const float*)d_in[2];
  const float* b1 = (const float*)d_in[3];
  const float* W2 = (const float*)d_in[4];
  const float* b2 = (const float*)d_in[5];
  float* out = (float*)d_out;

  // ws layout (bytes), total ~24.0 MiB:
  //   sq    @ 0         32 KiB
  //   a     @ 32768     2 MiB
  //   g     @ 2129920   2 MiB
  //   poshi @ 4227072   1 MiB
  //   poslo @ 5275648   1 MiB
  //   w2sw  @ 6324224   8 KiB
  //   list  @ 6332416   16 MiB  (512 slots x 8192 queries, TRANSPOSED u32 keys)
  //   cnt   @ 23109632  256 KiB (8 x 8192, transposed)
  //   tau   @ 23371776  32 KiB
  //   nbr   @ 23404544  640 KiB (8192 * 20 * 4)
  char* ws = (char*)d_ws;
  float* sq = (float*)ws;
  float* a = (float*)(ws + 32768);
  float* g = (float*)(ws + 2129920);
  unsigned short* poshi = (unsigned short*)(ws + 4227072);
  unsigned short* poslo = (unsigned short*)(ws + 5275648);
  unsigned short* w2sw = (unsigned short*)(ws + 6324224);
  unsigned* list = (unsigned*)(ws + 6332416);
  unsigned* cnt_ws = (unsigned*)(ws + 23109632);
  float* tau_g = (float*)(ws + 23371776);
  int* nbr = (int*)(ws + 23404544);

  k0_pre<<<M_TOTAL / 4, 256, 0, stream>>>(pos, feat, W1, b1, sq, a, g, poshi, poslo);
  k0b_w2sw<<<2, 256, 0, stream>>>(W2, w2sw);
  k1a_tau<<<M_TOTAL / QT, 256, 0, stream>>>(poshi, poslo, sq, tau_g);
  k1b_collect<<<dim3(M_TOTAL / QT, PPART), 256, 0, stream>>>(poshi, poslo, sq, tau_g, list, cnt_ws);
  k2a_select<<<M_TOTAL / QT, 256, 0, stream>>>(pos, sq, list, cnt_ws, nbr);
  k2b_mlp<<<M_TOTAL / 4, 256, 0, stream>>>(a, g, w2sw, b2, nbr, out);
}

// Round 8
// 228.476 us; speedup vs baseline: 1.5856x; 1.1440x over previous
//
#include <hip/hip_runtime.h>
#include <cfloat>
#include <cstdint>

// Problem constants (B=4, N=2048, C=64, O=64, K=20)
#define M_TOTAL 8192
#define KNN 20
#define PPART 16                 // candidate partitions
#define CPB (M_TOTAL / PPART)    // 512 candidates per K1b block
#define QT 64                    // queries per K1a/K1b block
#define SAMPLE 1024              // tau sample = candidates [0, 1024)
#define CAP 32                   // collect capacity per (query,partition); E~10.2, 6.8 sigma
#define SLOTS (PPART * CAP)      // 512
#define QT2 32                   // queries per K2a block
#define NSLICE 8                 // slices per K2a block (2 partitions each)
#define GCAP 40                  // guard-collect cap in k2a

typedef __attribute__((ext_vector_type(8))) short bf16x8;  // 8 bf16 (4 VGPRs)
typedef __attribute__((ext_vector_type(4))) float f32x4;

__device__ __forceinline__ unsigned short bf16rne(float x) {
  unsigned u = __float_as_uint(x);
  return (unsigned short)((u + 0x7FFFu + ((u >> 16) & 1u)) >> 16);
}

// ---------------------------------------------------------------------------
// K0: per-point precompute. sq, bf16-split pos, factored layer-1 (a, g).
// ---------------------------------------------------------------------------
__global__ __launch_bounds__(256) void k0_pre(
    const float* __restrict__ pos, const float* __restrict__ feat,
    const float* __restrict__ W1, const float* __restrict__ b1,
    float* __restrict__ sq, float* __restrict__ a_out, float* __restrict__ g_out,
    unsigned short* __restrict__ poshi, unsigned short* __restrict__ poslo) {
  __shared__ float fLds[4][64];
  const int lane = threadIdx.x & 63;
  const int rl = threadIdx.x >> 6;
  const int r = blockIdx.x * 4 + rl;

  float p = pos[r * 64 + lane];
  float f = feat[r * 64 + lane];
  fLds[rl][lane] = f;  // wave-private row; wave lockstep

  unsigned hib = bf16rne(p);
  float lof = p - __uint_as_float((unsigned)hib << 16);
  poshi[r * 64 + lane] = (unsigned short)hib;
  poslo[r * 64 + lane] = bf16rne(lof);

  float s = p * p;
#pragma unroll
  for (int off = 1; off < 64; off <<= 1) s += __shfl_xor(s, off, 64);
  if (lane == 0) sq[r] = s;

  float acc_a = b1[lane];
  float acc_g = 0.f;
  const float4* f4 = reinterpret_cast<const float4*>(fLds[rl]);
#pragma unroll
  for (int i = 0; i < 16; ++i) {
    float4 fv = f4[i];
    float fd[4] = {fv.x, fv.y, fv.z, fv.w};
#pragma unroll
    for (int j = 0; j < 4; ++j) {
      int d = 4 * i + j;
      float wt = W1[d * 64 + lane];
      float wb = W1[(64 + d) * 64 + lane];
      acc_a = fmaf(fd[j], wt - wb, acc_a);
      acc_g = fmaf(fd[j], wb, acc_g);
    }
  }
  a_out[r * 64 + lane] = acc_a;
  g_out[r * 64 + lane] = acc_g;
}

// ---------------------------------------------------------------------------
// K0b: swizzle W2 into bf16 B-fragment layout for 16x16x32 MFMA.
// ---------------------------------------------------------------------------
__global__ __launch_bounds__(256) void k0b_w2sw(
    const float* __restrict__ W2, unsigned short* __restrict__ w2sw) {
  const int u = blockIdx.x * 256 + threadIdx.x;  // [0, 512)
  const int f = u >> 6, lane = u & 63;
  const int seg = f >> 2, t = f & 3;
  const int quad = lane >> 4, col = lane & 15;
#pragma unroll
  for (int j = 0; j < 8; ++j) {
    int d = seg * 32 + quad * 8 + j;
    w2sw[u * 8 + j] = bf16rne(W2[d * 64 + t * 16 + col]);
  }
}

// ---------------------------------------------------------------------------
// MFMA stripe: 64 queries x 16 candidates, K=64, bf16-split 3-product.
// A[m=lane&15][k=quad*8+j]; D: col=lane&15, row=quad*4+reg (m89-verified).
// ---------------------------------------------------------------------------
__device__ __forceinline__ void mfma_stripe(
    const unsigned short* __restrict__ poshi,
    const unsigned short* __restrict__ poslo,
    const bf16x8 (&Ahi)[4][2], const bf16x8 (&Alo)[4][2],
    int candRow, int dimOff, f32x4 (&acc)[4]) {
  const bf16x8 Bhi0 = *(const bf16x8*)(poshi + (size_t)candRow * 64 + dimOff);
  const bf16x8 Bhi1 = *(const bf16x8*)(poshi + (size_t)candRow * 64 + dimOff + 32);
  const bf16x8 Blo0 = *(const bf16x8*)(poslo + (size_t)candRow * 64 + dimOff);
  const bf16x8 Blo1 = *(const bf16x8*)(poslo + (size_t)candRow * 64 + dimOff + 32);
#pragma unroll
  for (int s = 0; s < 4; ++s) {
    f32x4 a = acc[s];
    a = __builtin_amdgcn_mfma_f32_16x16x32_bf16(Ahi[s][0], Bhi0, a, 0, 0, 0);
    a = __builtin_amdgcn_mfma_f32_16x16x32_bf16(Ahi[s][1], Bhi1, a, 0, 0, 0);
    a = __builtin_amdgcn_mfma_f32_16x16x32_bf16(Ahi[s][0], Blo0, a, 0, 0, 0);
    a = __builtin_amdgcn_mfma_f32_16x16x32_bf16(Ahi[s][1], Blo1, a, 0, 0, 0);
    a = __builtin_amdgcn_mfma_f32_16x16x32_bf16(Alo[s][0], Bhi0, a, 0, 0, 0);
    a = __builtin_amdgcn_mfma_f32_16x16x32_bf16(Alo[s][1], Bhi1, a, 0, 0, 0);
    acc[s] = a;
  }
}

// ---------------------------------------------------------------------------
// K1a: tau_q >= sample-20th d-hat (overestimate is SAFE: only widens the
// collect superset). Each wave keeps only top-8 of its 256-cand substream
// (8-level cascade, 2.5x less VALU than top-20); final 4-way merge of the
// 32 kept values takes the 20th -> tau. When a substream held >8 of the true
// top-20, tau shifts UP (safe direction, ~+5% collect volume).
// ---------------------------------------------------------------------------
__global__ __launch_bounds__(256) void k1a_tau(
    const unsigned short* __restrict__ poshi,
    const unsigned short* __restrict__ poslo,
    const float* __restrict__ sq, float* __restrict__ tau_g) {
  __shared__ float vw[4][16][68];       // wave-private transpose
  __shared__ float sqcLds[SAMPLE];
  __shared__ float topLds[64][4][8];
  const int lane = threadIdx.x & 63;
  const int w = threadIdx.x >> 6;
  const int qbase = blockIdx.x * QT;
  const int col = lane & 15;
  const int quad = lane >> 4;
  const int dimOff = quad * 8;

  for (int i = threadIdx.x; i < SAMPLE; i += 256) sqcLds[i] = sq[i];

  bf16x8 Ahi[4][2], Alo[4][2];
#pragma unroll
  for (int s = 0; s < 4; ++s) {
    int row = qbase + s * 16 + col;
    Ahi[s][0] = *(const bf16x8*)(poshi + (size_t)row * 64 + dimOff);
    Ahi[s][1] = *(const bf16x8*)(poshi + (size_t)row * 64 + dimOff + 32);
    Alo[s][0] = *(const bf16x8*)(poslo + (size_t)row * 64 + dimOff);
    Alo[s][1] = *(const bf16x8*)(poslo + (size_t)row * 64 + dimOff + 32);
  }
  __syncthreads();

  const f32x4 zf = {0.f, 0.f, 0.f, 0.f};
  float bd[8];
#pragma unroll
  for (int k = 0; k < 8; ++k) bd[k] = FLT_MAX;

  for (int c0 = 0; c0 < SAMPLE; c0 += 64) {
    const int candRow = c0 + w * 16 + col;
    f32x4 acc[4] = {zf, zf, zf, zf};
    mfma_stripe(poshi, poslo, Ahi, Alo, candRow, dimOff, acc);
    const float sqcv = sqcLds[candRow] + 256.0f;
#pragma unroll
    for (int s = 0; s < 4; ++s) {
      float4 v4;
      v4.x = fmaf(-2.f, acc[s][0], sqcv);
      v4.y = fmaf(-2.f, acc[s][1], sqcv);
      v4.z = fmaf(-2.f, acc[s][2], sqcv);
      v4.w = fmaf(-2.f, acc[s][3], sqcv);
      *reinterpret_cast<float4*>(&vw[w][col][s * 16 + quad * 4]) = v4;
    }
    __builtin_amdgcn_wave_barrier();
#pragma unroll
    for (int i = 0; i < 16; ++i) {
      float cd = vw[w][i][lane];
#pragma unroll
      for (int k = 0; k < 8; ++k) {  // branch-free sorted insert (top-8)
        float lo = fminf(cd, bd[k]);
        cd = fmaxf(cd, bd[k]);
        bd[k] = lo;
      }
    }
    __builtin_amdgcn_wave_barrier();
  }

#pragma unroll
  for (int k = 0; k < 8; ++k) topLds[lane][w][k] = bd[k];
  __syncthreads();

  if (threadIdx.x < QT) {
    const int q = threadIdx.x;
    int p0 = 0, p1 = 0, p2 = 0, p3 = 0;
    float tau = FLT_MAX;
    for (int k = 0; k < KNN; ++k) {
      float v0 = (p0 < 8) ? topLds[q][0][p0] : FLT_MAX;
      float v1 = (p1 < 8) ? topLds[q][1][p1] : FLT_MAX;
      float v2 = (p2 < 8) ? topLds[q][2][p2] : FLT_MAX;
      float v3 = (p3 < 8) ? topLds[q][3][p3] : FLT_MAX;
      float m = fminf(fminf(v0, v1), fminf(v2, v3));
      if (m == v0) p0++;
      else if (m == v1) p1++;
      else if (m == v2) p2++;
      else p3++;
      tau = m;
    }
    tau_g[qbase + q] = tau;  // 20th of 32 kept >= sample 20th
  }
}

// ---------------------------------------------------------------------------
// K1b: MFMA pass over a 512-candidate partition; collect val <= tau_q as
// packed u32 key (19-bit truncated val-float-bits | 13-bit idx), transposed
// layout (list[(p*CAP+slot)*M + q]) for K2a coalescing.
// v3: PPART 16 -> 2048 blocks (8 blocks/CU) + unroll-2 stripe loop for
// deeper load pipelining.
// ---------------------------------------------------------------------------
__global__ __launch_bounds__(256) void k1b_collect(
    const unsigned short* __restrict__ poshi,
    const unsigned short* __restrict__ poslo,
    const float* __restrict__ sq, const float* __restrict__ tau_g,
    unsigned* __restrict__ list, unsigned* __restrict__ cnt_ws) {
  __shared__ float sqcLds[CPB];
  __shared__ float tauLds[QT];
  __shared__ unsigned cntLds[QT];

  const int lane = threadIdx.x & 63;
  const int w = threadIdx.x >> 6;
  const int qbase = blockIdx.x * QT;
  const int cbase = blockIdx.y * CPB;
  const int col = lane & 15;
  const int quad = lane >> 4;
  const int dimOff = quad * 8;

  for (int i = threadIdx.x; i < CPB; i += 256) sqcLds[i] = sq[cbase + i];
  if (threadIdx.x < QT) {
    tauLds[threadIdx.x] = tau_g[qbase + threadIdx.x];
    cntLds[threadIdx.x] = 0;
  }

  bf16x8 Ahi[4][2], Alo[4][2];
#pragma unroll
  for (int s = 0; s < 4; ++s) {
    int row = qbase + s * 16 + col;
    Ahi[s][0] = *(const bf16x8*)(poshi + (size_t)row * 64 + dimOff);
    Ahi[s][1] = *(const bf16x8*)(poshi + (size_t)row * 64 + dimOff + 32);
    Alo[s][0] = *(const bf16x8*)(poslo + (size_t)row * 64 + dimOff);
    Alo[s][1] = *(const bf16x8*)(poslo + (size_t)row * 64 + dimOff + 32);
  }
  __syncthreads();

  float tau_l[4][4];
#pragma unroll
  for (int s = 0; s < 4; ++s)
#pragma unroll
    for (int r = 0; r < 4; ++r) tau_l[s][r] = tauLds[s * 16 + quad * 4 + r];

  const f32x4 zf = {0.f, 0.f, 0.f, 0.f};
#pragma unroll 2
  for (int c0 = 0; c0 < CPB; c0 += 64) {
    const int candRow = cbase + c0 + w * 16 + col;
    f32x4 acc[4] = {zf, zf, zf, zf};
    mfma_stripe(poshi, poslo, Ahi, Alo, candRow, dimOff, acc);
    const float sqcv = sqcLds[c0 + w * 16 + col] + 256.0f;
#pragma unroll
    for (int s = 0; s < 4; ++s) {
#pragma unroll
      for (int r = 0; r < 4; ++r) {
        float val = fmaf(-2.f, acc[s][r], sqcv);
        const int qrow = s * 16 + quad * 4 + r;
        if (val <= tau_l[s][r]) {  // ~2% of lanes
          unsigned slot = atomicAdd(&cntLds[qrow], 1u);
          if (slot < CAP)
            list[(size_t)(blockIdx.y * CAP + slot) * M_TOTAL + qbase + qrow] =
                (__float_as_uint(val) & 0xFFFFE000u) | (unsigned)candRow;
        }
      }
    }
  }
  __syncthreads();
  if (threadIdx.x < QT) {
    unsigned c = cntLds[threadIdx.x];
    cnt_ws[blockIdx.y * M_TOTAL + qbase + threadIdx.x] = c > CAP ? CAP : c;
  }
}

// ---------------------------------------------------------------------------
// K2a v3: 32 queries x 8 slices (2 partitions each), grid 256 -> full GPU.
// Ph1: per-slice top-8 (coalesced list reads; overestimated q20 is safe).
// Ph2: 8-way merge -> 20th of kept -> guard T.
// Ph3: rescan + collect quant <= T (~21-24 per query).
// Ph4: 8 thr/query exact fp32 d2, sorted-5 each; 8-way merge -> top-20 -> nbr.
// ---------------------------------------------------------------------------
__global__ __launch_bounds__(256) void k2a_select(
    const float* __restrict__ pos, const float* __restrict__ sq,
    const unsigned* __restrict__ list, const unsigned* __restrict__ cnt_ws,
    int* __restrict__ nbr) {
  __shared__ unsigned topLds[NSLICE][QT2][9];           // 9.2 KiB (pad 9)
  __shared__ unsigned TLds[QT2];
  __shared__ unsigned ccnt[QT2];
  __shared__ unsigned candLds[QT2][GCAP];               // 5.1 KiB
  __shared__ unsigned long long rrLds[NSLICE][QT2][6];  // 12.3 KiB (pad 6)

  const int l = threadIdx.x & 31;   // query lane
  const int s = threadIdx.x >> 5;   // slice: partitions 2s, 2s+1
  const int q = blockIdx.x * QT2 + l;

  // ---- phase 1: per-slice top-8 over collected keys ----
  unsigned bd[8];
#pragma unroll
  for (int k = 0; k < 8; ++k) bd[k] = 0xFFFFFFFFu;
#pragma unroll
  for (int pp = 0; pp < 2; ++pp) {
    const int p = s * 2 + pp;
    const unsigned c = cnt_ws[p * M_TOTAL + q];
    const unsigned* base = list + (size_t)(p * CAP) * M_TOTAL + q;
    for (unsigned sl = 0; sl < c; ++sl) {
      unsigned cd = base[(size_t)sl * M_TOTAL];  // coalesced across lanes
#pragma unroll
      for (int k = 0; k < 8; ++k) {
        unsigned lo = cd < bd[k] ? cd : bd[k];
        cd = cd < bd[k] ? bd[k] : cd;
        bd[k] = lo;
      }
    }
  }
#pragma unroll
  for (int k = 0; k < 8; ++k) topLds[s][l][k] = bd[k];
  __syncthreads();

  // ---- phase 2: 8-way merge -> 20th of kept -> guard T ----
  if (threadIdx.x < QT2) {
    int i0 = 0, i1 = 0, i2 = 0, i3 = 0, i4 = 0, i5 = 0, i6 = 0, i7 = 0;
    unsigned m = 0;
    for (int k = 0; k < KNN; ++k) {
      unsigned v0 = (i0 < 8) ? topLds[0][l][i0] : 0xFFFFFFFFu;
      unsigned v1 = (i1 < 8) ? topLds[1][l][i1] : 0xFFFFFFFFu;
      unsigned v2 = (i2 < 8) ? topLds[2][l][i2] : 0xFFFFFFFFu;
      unsigned v3 = (i3 < 8) ? topLds[3][l][i3] : 0xFFFFFFFFu;
      unsigned v4 = (i4 < 8) ? topLds[4][l][i4] : 0xFFFFFFFFu;
      unsigned v5 = (i5 < 8) ? topLds[5][l][i5] : 0xFFFFFFFFu;
      unsigned v6 = (i6 < 8) ? topLds[6][l][i6] : 0xFFFFFFFFu;
      unsigned v7 = (i7 < 8) ? topLds[7][l][i7] : 0xFFFFFFFFu;
      unsigned a01 = v0 < v1 ? v0 : v1;
      unsigned a23 = v2 < v3 ? v2 : v3;
      unsigned a45 = v4 < v5 ? v4 : v5;
      unsigned a67 = v6 < v7 ? v6 : v7;
      unsigned a03 = a01 < a23 ? a01 : a23;
      unsigned a47 = a45 < a67 ? a45 : a67;
      m = a03 < a47 ? a03 : a47;
      if (m == v0) i0++;
      else if (m == v1) i1++;
      else if (m == v2) i2++;
      else if (m == v3) i3++;
      else if (m == v4) i4++;
      else if (m == v5) i5++;
      else if (m == v6) i6++;
      else i7++;
    }
    TLds[l] = (m >> 13) + 2;
    ccnt[l] = 0;
  }
  __syncthreads();

  // ---- phase 3: rescan, collect guard set ----
  const unsigned T = TLds[l];
#pragma unroll
  for (int pp = 0; pp < 2; ++pp) {
    const int p = s * 2 + pp;
    const unsigned c = cnt_ws[p * M_TOTAL + q];
    const unsigned* base = list + (size_t)(p * CAP) * M_TOTAL + q;
    for (unsigned sl = 0; sl < c; ++sl) {
      unsigned kk = base[(size_t)sl * M_TOTAL];
      if ((kk >> 13) <= T) {
        unsigned pos_ = atomicAdd(&ccnt[l], 1u);
        if (pos_ < GCAP) candLds[l][pos_] = kk & 0x1FFFu;
      }
    }
  }
  __syncthreads();

  // ---- phase 4: exact fp32 d2 re-rank of the guard set ----
  const int cc = min(ccnt[l], (unsigned)GCAP);
  const float sqq = sq[q];
  const float4* qp4 = reinterpret_cast<const float4*>(pos + (size_t)q * 64);
  unsigned long long kb[5];
#pragma unroll
  for (int j = 0; j < 5; ++j) kb[j] = ~0ull;
  for (int j = s; j < cc; j += NSLICE) {
    const unsigned idx = candLds[l][j];
    const float4* cp4 = reinterpret_cast<const float4*>(pos + (size_t)idx * 64);
    float d0 = 0.f, d1 = 0.f, d2 = 0.f, d3 = 0.f;
#pragma unroll
    for (int t = 0; t < 16; ++t) {
      float4 cv = cp4[t];
      float4 qv = qp4[t];  // L1/L2-hot
      d0 = fmaf(cv.x, qv.x, d0);
      d1 = fmaf(cv.y, qv.y, d1);
      d2 = fmaf(cv.z, qv.z, d2);
      d3 = fmaf(cv.w, qv.w, d3);
    }
    float dot = (d0 + d1) + (d2 + d3);
    float dd = fmaxf(fmaf(-2.f, dot, sqq + sq[idx]), 0.f);
    unsigned long long cd = ((unsigned long long)__float_as_uint(dd) << 32) | idx;
#pragma unroll
    for (int k = 0; k < 5; ++k) {  // sorted-5 insert (tie -> smaller idx)
      unsigned long long lo = cd < kb[k] ? cd : kb[k];
      cd = cd < kb[k] ? kb[k] : cd;
      kb[k] = lo;
    }
  }
#pragma unroll
  for (int j = 0; j < 5; ++j) rrLds[s][l][j] = kb[j];
  __syncthreads();

  if (threadIdx.x < QT2) {
    int i0 = 0, i1 = 0, i2 = 0, i3 = 0, i4 = 0, i5 = 0, i6 = 0, i7 = 0;
    for (int k = 0; k < KNN; ++k) {
      unsigned long long v0 = (i0 < 5) ? rrLds[0][l][i0] : ~0ull;
      unsigned long long v1 = (i1 < 5) ? rrLds[1][l][i1] : ~0ull;
      unsigned long long v2 = (i2 < 5) ? rrLds[2][l][i2] : ~0ull;
      unsigned long long v3 = (i3 < 5) ? rrLds[3][l][i3] : ~0ull;
      unsigned long long v4 = (i4 < 5) ? rrLds[4][l][i4] : ~0ull;
      unsigned long long v5 = (i5 < 5) ? rrLds[5][l][i5] : ~0ull;
      unsigned long long v6 = (i6 < 5) ? rrLds[6][l][i6] : ~0ull;
      unsigned long long v7 = (i7 < 5) ? rrLds[7][l][i7] : ~0ull;
      unsigned long long a01 = v0 < v1 ? v0 : v1;
      unsigned long long a23 = v2 < v3 ? v2 : v3;
      unsigned long long a45 = v4 < v5 ? v4 : v5;
      unsigned long long a67 = v6 < v7 ? v6 : v7;
      unsigned long long a03 = a01 < a23 ? a01 : a23;
      unsigned long long a47 = a45 < a67 ? a45 : a67;
      unsigned long long m = a03 < a47 ? a03 : a47;
      if (m == v0) i0++;
      else if (m == v1) i1++;
      else if (m == v2) i2++;
      else if (m == v3) i3++;
      else if (m == v4) i4++;
      else if (m == v5) i5++;
      else if (m == v6) i6++;
      else i7++;
      nbr[q * KNN + k] = (int)(unsigned)(m & 0xFFFFFFFFu);
    }
  }
}

// ---------------------------------------------------------------------------
// K2b: MLP + max-aggregation via MFMA. One wave per query. (unchanged)
// ---------------------------------------------------------------------------
__global__ __launch_bounds__(256) void k2b_mlp(
    const float* __restrict__ a_in, const float* __restrict__ g_in,
    const unsigned short* __restrict__ w2sw, const float* __restrict__ b2,
    const int* __restrict__ nbr, float* __restrict__ out) {
  const int lane = threadIdx.x & 63;
  const int wv = threadIdx.x >> 6;
  const int q = blockIdx.x * 4 + wv;
  const int col = lane & 15;
  const int quad = lane >> 4;

  const int n0 = nbr[q * KNN + col];
  const int n1 = nbr[q * KNN + ((16 + col) % KNN)];

  bf16x8 Bf[8];
#pragma unroll
  for (int f = 0; f < 8; ++f)
    Bf[f] = *(const bf16x8*)(w2sw + ((size_t)f * 64 + lane) * 8);

  const f32x4 zf = {0.f, 0.f, 0.f, 0.f};
  f32x4 acc0[4] = {zf, zf, zf, zf};
  f32x4 acc1[4] = {zf, zf, zf, zf};

#pragma unroll
  for (int seg = 0; seg < 2; ++seg) {
    const int dOff = seg * 32 + quad * 8;
    const float4* ap = reinterpret_cast<const float4*>(a_in + (size_t)q * 64 + dOff);
    const float4* g0p = reinterpret_cast<const float4*>(g_in + (size_t)n0 * 64 + dOff);
    const float4* g1p = reinterpret_cast<const float4*>(g_in + (size_t)n1 * 64 + dOff);
    float4 aa0 = ap[0], aa1 = ap[1];
    float4 gg0 = g0p[0], gg1 = g0p[1];
    float4 hh0 = g1p[0], hh1 = g1p[1];
    float av[8] = {aa0.x, aa0.y, aa0.z, aa0.w, aa1.x, aa1.y, aa1.z, aa1.w};
    float g0v[8] = {gg0.x, gg0.y, gg0.z, gg0.w, gg1.x, gg1.y, gg1.z, gg1.w};
    float g1v[8] = {hh0.x, hh0.y, hh0.z, hh0.w, hh1.x, hh1.y, hh1.z, hh1.w};
    bf16x8 A0, A1;
#pragma unroll
    for (int j = 0; j < 8; ++j) {
      A0[j] = (short)bf16rne(fmaxf(av[j] + g0v[j], 0.f));
      A1[j] = (short)bf16rne(fmaxf(av[j] + g1v[j], 0.f));
    }
#pragma unroll
    for (int t = 0; t < 4; ++t) {
      acc0[t] = __builtin_amdgcn_mfma_f32_16x16x32_bf16(A0, Bf[seg * 4 + t], acc0[t], 0, 0, 0);
      acc1[t] = __builtin_amdgcn_mfma_f32_16x16x32_bf16(A1, Bf[seg * 4 + t], acc1[t], 0, 0, 0);
    }
  }

  float res = 0.f;
#pragma unroll
  for (int t = 0; t < 4; ++t) {
    float m = fmaxf(fmaxf(fmaxf(acc0[t][0], acc1[t][0]), fmaxf(acc0[t][1], acc1[t][1])),
                    fmaxf(fmaxf(acc0[t][2], acc1[t][2]), fmaxf(acc0[t][3], acc1[t][3])));
    m = fmaxf(m, __shfl_xor(m, 16, 64));
    m = fmaxf(m, __shfl_xor(m, 32, 64));
    res = (quad == t) ? m : res;
  }
  out[(size_t)q * 64 + lane] = res + b2[lane];
}

// ---------------------------------------------------------------------------
extern "C" void kernel_launch(void* const* d_in, const int* in_sizes, int n_in,
                              void* d_out, int out_size, void* d_ws, size_t ws_size,
                              hipStream_t stream) {
  const float* pos = (const float*)d_in[0];
  const float* feat = (const float*)d_in[1];
  const float* W1 = (const float*)d_in[2];
  const float* b1 = (const float*)d_in[3];
  const float* W2 = (const float*)d_in[4];
  const float* b2 = (const float*)d_in[5];
  float* out = (float*)d_out;

  // ws layout (bytes), total ~24.3 MiB:
  //   sq    @ 0         32 KiB
  //   a     @ 32768     2 MiB
  //   g     @ 2129920   2 MiB
  //   poshi @ 4227072   1 MiB
  //   poslo @ 5275648   1 MiB
  //   w2sw  @ 6324224   8 KiB
  //   list  @ 6332416   16 MiB  (512 slots x 8192 queries, transposed u32 keys)
  //   cnt   @ 23109632  512 KiB (16 x 8192, transposed)
  //   tau   @ 23633920  32 KiB
  //   nbr   @ 23666688  640 KiB (8192 * 20 * 4)
  char* ws = (char*)d_ws;
  float* sq = (float*)ws;
  float* a = (float*)(ws + 32768);
  float* g = (float*)(ws + 2129920);
  unsigned short* poshi = (unsigned short*)(ws + 4227072);
  unsigned short* poslo = (unsigned short*)(ws + 5275648);
  unsigned short* w2sw = (unsigned short*)(ws + 6324224);
  unsigned* list = (unsigned*)(ws + 6332416);
  unsigned* cnt_ws = (unsigned*)(ws + 23109632);
  float* tau_g = (float*)(ws + 23633920);
  int* nbr = (int*)(ws + 23666688);

  k0_pre<<<M_TOTAL / 4, 256, 0, stream>>>(pos, feat, W1, b1, sq, a, g, poshi, poslo);
  k0b_w2sw<<<2, 256, 0, stream>>>(W2, w2sw);
  k1a_tau<<<M_TOTAL / QT, 256, 0, stream>>>(poshi, poslo, sq, tau_g);
  k1b_collect<<<dim3(M_TOTAL / QT, PPART), 256, 0, stream>>>(poshi, poslo, sq, tau_g, list, cnt_ws);
  k2a_select<<<M_TOTAL / QT2, 256, 0, stream>>>(pos, sq, list, cnt_ws, nbr);
  k2b_mlp<<<M_TOTAL / 4, 256, 0, stream>>>(a, g, w2sw, b2, nbr, out);
}

// Round 9
// 204.495 us; speedup vs baseline: 1.7715x; 1.1173x over previous
//
#include <hip/hip_runtime.h>
#include <cfloat>
#include <cstdint>

// Problem constants (B=4, N=2048, C=64, O=64, K=20)
#define M_TOTAL 8192
#define KNN 20
#define PPART 16                 // candidate partitions
#define CPB (M_TOTAL / PPART)    // 512 candidates per K1b block
#define QT 64                    // queries per K1b block
#define QT1A 32                  // queries per K1a block
#define SAMPLE 1024              // tau sample = candidates [0, 1024)
#define CAP 32                   // collect capacity per (query,partition); E~10.2, 6.8 sigma
#define SLOTS (PPART * CAP)      // 512
#define QT2 32                   // queries per K2a block
#define NSLICE 8                 // slices per K2a block (2 partitions each)
#define GCAP 40                  // guard-collect cap in k2a

typedef __attribute__((ext_vector_type(8))) short bf16x8;  // 8 bf16 (4 VGPRs)
typedef __attribute__((ext_vector_type(4))) float f32x4;

__device__ __forceinline__ unsigned short bf16rne(float x) {
  unsigned u = __float_as_uint(x);
  return (unsigned short)((u + 0x7FFFu + ((u >> 16) & 1u)) >> 16);
}

// ---------------------------------------------------------------------------
// K0: per-point precompute. sq, bf16-split pos, factored layer-1 (a, g).
// ---------------------------------------------------------------------------
__global__ __launch_bounds__(256) void k0_pre(
    const float* __restrict__ pos, const float* __restrict__ feat,
    const float* __restrict__ W1, const float* __restrict__ b1,
    float* __restrict__ sq, float* __restrict__ a_out, float* __restrict__ g_out,
    unsigned short* __restrict__ poshi, unsigned short* __restrict__ poslo) {
  __shared__ float fLds[4][64];
  const int lane = threadIdx.x & 63;
  const int rl = threadIdx.x >> 6;
  const int r = blockIdx.x * 4 + rl;

  float p = pos[r * 64 + lane];
  float f = feat[r * 64 + lane];
  fLds[rl][lane] = f;  // wave-private row; wave lockstep

  unsigned hib = bf16rne(p);
  float lof = p - __uint_as_float((unsigned)hib << 16);
  poshi[r * 64 + lane] = (unsigned short)hib;
  poslo[r * 64 + lane] = bf16rne(lof);

  float s = p * p;
#pragma unroll
  for (int off = 1; off < 64; off <<= 1) s += __shfl_xor(s, off, 64);
  if (lane == 0) sq[r] = s;

  float acc_a = b1[lane];
  float acc_g = 0.f;
  const float4* f4 = reinterpret_cast<const float4*>(fLds[rl]);
#pragma unroll
  for (int i = 0; i < 16; ++i) {
    float4 fv = f4[i];
    float fd[4] = {fv.x, fv.y, fv.z, fv.w};
#pragma unroll
    for (int j = 0; j < 4; ++j) {
      int d = 4 * i + j;
      float wt = W1[d * 64 + lane];
      float wb = W1[(64 + d) * 64 + lane];
      acc_a = fmaf(fd[j], wt - wb, acc_a);
      acc_g = fmaf(fd[j], wb, acc_g);
    }
  }
  a_out[r * 64 + lane] = acc_a;
  g_out[r * 64 + lane] = acc_g;
}

// ---------------------------------------------------------------------------
// K0b: swizzle W2 into bf16 B-fragment layout for 16x16x32 MFMA.
// ---------------------------------------------------------------------------
__global__ __launch_bounds__(256) void k0b_w2sw(
    const float* __restrict__ W2, unsigned short* __restrict__ w2sw) {
  const int u = blockIdx.x * 256 + threadIdx.x;  // [0, 512)
  const int f = u >> 6, lane = u & 63;
  const int seg = f >> 2, t = f & 3;
  const int quad = lane >> 4, col = lane & 15;
#pragma unroll
  for (int j = 0; j < 8; ++j) {
    int d = seg * 32 + quad * 8 + j;
    w2sw[u * 8 + j] = bf16rne(W2[d * 64 + t * 16 + col]);
  }
}

// ---------------------------------------------------------------------------
// B-tile register load + MFMA compute (split so the caller can software-
// pipeline: load stripe n+1 before computing stripe n).
// A[m=lane&15][k=quad*8+j]; D: col=lane&15, row=quad*4+reg (m89-verified).
// ---------------------------------------------------------------------------
__device__ __forceinline__ void ldB(
    const unsigned short* __restrict__ poshi,
    const unsigned short* __restrict__ poslo, int candRow, int dimOff,
    bf16x8& h0, bf16x8& h1, bf16x8& l0, bf16x8& l1) {
  h0 = *(const bf16x8*)(poshi + (size_t)candRow * 64 + dimOff);
  h1 = *(const bf16x8*)(poshi + (size_t)candRow * 64 + dimOff + 32);
  l0 = *(const bf16x8*)(poslo + (size_t)candRow * 64 + dimOff);
  l1 = *(const bf16x8*)(poslo + (size_t)candRow * 64 + dimOff + 32);
}

template <int NG>
__device__ __forceinline__ void mfma_groups(
    const bf16x8 (&Ahi)[NG][2], const bf16x8 (&Alo)[NG][2],
    const bf16x8& Bh0, const bf16x8& Bh1, const bf16x8& Bl0, const bf16x8& Bl1,
    f32x4 (&acc)[NG]) {
#pragma unroll
  for (int s = 0; s < NG; ++s) {
    f32x4 a = acc[s];
    a = __builtin_amdgcn_mfma_f32_16x16x32_bf16(Ahi[s][0], Bh0, a, 0, 0, 0);
    a = __builtin_amdgcn_mfma_f32_16x16x32_bf16(Ahi[s][1], Bh1, a, 0, 0, 0);
    a = __builtin_amdgcn_mfma_f32_16x16x32_bf16(Ahi[s][0], Bl0, a, 0, 0, 0);
    a = __builtin_amdgcn_mfma_f32_16x16x32_bf16(Ahi[s][1], Bl1, a, 0, 0, 0);
    a = __builtin_amdgcn_mfma_f32_16x16x32_bf16(Alo[s][0], Bh0, a, 0, 0, 0);
    a = __builtin_amdgcn_mfma_f32_16x16x32_bf16(Alo[s][1], Bh1, a, 0, 0, 0);
    acc[s] = a;
  }
}

// ---------------------------------------------------------------------------
// K1a v4: tau_q >= sample-20th d-hat (overestimate widens superset: safe).
// QT1A=32 queries/block -> 256 blocks (full GPU). Wave w covers cand cols
// 16w..16w+15; lane = (query l&31, cand-half l>>5); top-8 per 128-cand
// stream; 8 streams/query; tau = 20th of 64 kept. B-regs double-buffered.
// ---------------------------------------------------------------------------
__global__ __launch_bounds__(256) void k1a_tau(
    const unsigned short* __restrict__ poshi,
    const unsigned short* __restrict__ poslo,
    const float* __restrict__ sq, float* __restrict__ tau_g) {
  __shared__ float vw[4][16][36];        // wave-private transpose, 9 KiB
  __shared__ float sqcLds[SAMPLE];       // 4 KiB
  __shared__ float topLds[8][8][33];     // [stream][k][q], 8.25 KiB
  const int lane = threadIdx.x & 63;
  const int w = threadIdx.x >> 6;
  const int qbase = blockIdx.x * QT1A;
  const int col = lane & 15;
  const int quad = lane >> 4;
  const int dimOff = quad * 8;
  const int qq = lane & 31;     // query owned in cascade phase
  const int h = lane >> 5;      // candidate half owned

  for (int i = threadIdx.x; i < SAMPLE; i += 256) sqcLds[i] = sq[i];

  bf16x8 Ahi[2][2], Alo[2][2];
#pragma unroll
  for (int s = 0; s < 2; ++s) {
    int row = qbase + s * 16 + col;
    Ahi[s][0] = *(const bf16x8*)(poshi + (size_t)row * 64 + dimOff);
    Ahi[s][1] = *(const bf16x8*)(poshi + (size_t)row * 64 + dimOff + 32);
    Alo[s][0] = *(const bf16x8*)(poslo + (size_t)row * 64 + dimOff);
    Alo[s][1] = *(const bf16x8*)(poslo + (size_t)row * 64 + dimOff + 32);
  }
  __syncthreads();  // sqcLds ready

  const f32x4 zf = {0.f, 0.f, 0.f, 0.f};
  float bd[8];
#pragma unroll
  for (int k = 0; k < 8; ++k) bd[k] = FLT_MAX;

  bf16x8 Bh0, Bh1, Bl0, Bl1;
  ldB(poshi, poslo, w * 16 + col, dimOff, Bh0, Bh1, Bl0, Bl1);
  for (int c0 = 0; c0 < SAMPLE; c0 += 64) {
    // prefetch next stripe's B (overlaps this stripe's MFMA + cascade)
    const int nc0 = (c0 + 64 < SAMPLE) ? c0 + 64 : c0;
    bf16x8 Nh0, Nh1, Nl0, Nl1;
    ldB(poshi, poslo, nc0 + w * 16 + col, dimOff, Nh0, Nh1, Nl0, Nl1);

    f32x4 acc[2] = {zf, zf};
    mfma_groups<2>(Ahi, Alo, Bh0, Bh1, Bl0, Bl1, acc);
    const float sqcv = sqcLds[c0 + w * 16 + col] + 256.0f;
#pragma unroll
    for (int s = 0; s < 2; ++s) {
      float4 v4;
      v4.x = fmaf(-2.f, acc[s][0], sqcv);
      v4.y = fmaf(-2.f, acc[s][1], sqcv);
      v4.z = fmaf(-2.f, acc[s][2], sqcv);
      v4.w = fmaf(-2.f, acc[s][3], sqcv);
      *reinterpret_cast<float4*>(&vw[w][col][s * 16 + quad * 4]) = v4;
    }
    __builtin_amdgcn_wave_barrier();  // wave-private region, lockstep
#pragma unroll
    for (int i = 0; i < 8; ++i) {
      float cd = vw[w][h * 8 + i][qq];
#pragma unroll
      for (int k = 0; k < 8; ++k) {  // branch-free sorted insert (top-8)
        float lo = fminf(cd, bd[k]);
        cd = fmaxf(cd, bd[k]);
        bd[k] = lo;
      }
    }
    __builtin_amdgcn_wave_barrier();
    Bh0 = Nh0; Bh1 = Nh1; Bl0 = Nl0; Bl1 = Nl1;
  }

#pragma unroll
  for (int k = 0; k < 8; ++k) topLds[w * 2 + h][k][qq] = bd[k];
  __syncthreads();

  if (threadIdx.x < QT1A) {
    const int l = threadIdx.x;
    int ix[8] = {0, 0, 0, 0, 0, 0, 0, 0};
    float tau = FLT_MAX;
    for (int k = 0; k < KNN; ++k) {
      float best = FLT_MAX;
      int bs = 0;
#pragma unroll
      for (int st = 0; st < 8; ++st) {
        float v = (ix[st] < 8) ? topLds[st][ix[st]][l] : FLT_MAX;
        if (v < best) { best = v; bs = st; }
      }
      ix[bs]++;
      tau = best;
    }
    tau_g[qbase + l] = tau;  // 20th of 64 kept >= sample 20th
  }
}

// ---------------------------------------------------------------------------
// K1b v4: MFMA pass over a 512-candidate partition with register double-
// buffered B (stripe n+1 loads issued before stripe n compute); collect
// val <= tau_q as packed u32 key (19-bit val-bits | 13-bit idx), transposed
// layout for K2a coalescing.
// ---------------------------------------------------------------------------
__global__ __launch_bounds__(256) void k1b_collect(
    const unsigned short* __restrict__ poshi,
    const unsigned short* __restrict__ poslo,
    const float* __restrict__ sq, const float* __restrict__ tau_g,
    unsigned* __restrict__ list, unsigned* __restrict__ cnt_ws) {
  __shared__ float sqcLds[CPB];
  __shared__ float tauLds[QT];
  __shared__ unsigned cntLds[QT];

  const int lane = threadIdx.x & 63;
  const int w = threadIdx.x >> 6;
  const int qbase = blockIdx.x * QT;
  const int cbase = blockIdx.y * CPB;
  const int col = lane & 15;
  const int quad = lane >> 4;
  const int dimOff = quad * 8;

  for (int i = threadIdx.x; i < CPB; i += 256) sqcLds[i] = sq[cbase + i];
  if (threadIdx.x < QT) {
    tauLds[threadIdx.x] = tau_g[qbase + threadIdx.x];
    cntLds[threadIdx.x] = 0;
  }

  bf16x8 Ahi[4][2], Alo[4][2];
#pragma unroll
  for (int s = 0; s < 4; ++s) {
    int row = qbase + s * 16 + col;
    Ahi[s][0] = *(const bf16x8*)(poshi + (size_t)row * 64 + dimOff);
    Ahi[s][1] = *(const bf16x8*)(poshi + (size_t)row * 64 + dimOff + 32);
    Alo[s][0] = *(const bf16x8*)(poslo + (size_t)row * 64 + dimOff);
    Alo[s][1] = *(const bf16x8*)(poslo + (size_t)row * 64 + dimOff + 32);
  }
  __syncthreads();

  float tau_l[4][4];
#pragma unroll
  for (int s = 0; s < 4; ++s)
#pragma unroll
    for (int r = 0; r < 4; ++r) tau_l[s][r] = tauLds[s * 16 + quad * 4 + r];

  const f32x4 zf = {0.f, 0.f, 0.f, 0.f};
  bf16x8 Bh0, Bh1, Bl0, Bl1;
  ldB(poshi, poslo, cbase + w * 16 + col, dimOff, Bh0, Bh1, Bl0, Bl1);
  for (int c0 = 0; c0 < CPB; c0 += 64) {
    const int nc0 = (c0 + 64 < CPB) ? c0 + 64 : c0;
    bf16x8 Nh0, Nh1, Nl0, Nl1;
    ldB(poshi, poslo, cbase + nc0 + w * 16 + col, dimOff, Nh0, Nh1, Nl0, Nl1);

    f32x4 acc[4] = {zf, zf, zf, zf};
    mfma_groups<4>(Ahi, Alo, Bh0, Bh1, Bl0, Bl1, acc);
    const int candRow = cbase + c0 + w * 16 + col;
    const float sqcv = sqcLds[c0 + w * 16 + col] + 256.0f;
#pragma unroll
    for (int s = 0; s < 4; ++s) {
#pragma unroll
      for (int r = 0; r < 4; ++r) {
        float val = fmaf(-2.f, acc[s][r], sqcv);
        const int qrow = s * 16 + quad * 4 + r;
        if (val <= tau_l[s][r]) {  // ~2% of lanes
          unsigned slot = atomicAdd(&cntLds[qrow], 1u);
          if (slot < CAP)
            list[(size_t)(blockIdx.y * CAP + slot) * M_TOTAL + qbase + qrow] =
                (__float_as_uint(val) & 0xFFFFE000u) | (unsigned)candRow;
        }
      }
    }
    Bh0 = Nh0; Bh1 = Nh1; Bl0 = Nl0; Bl1 = Nl1;
  }
  __syncthreads();
  if (threadIdx.x < QT) {
    unsigned c = cntLds[threadIdx.x];
    cnt_ws[blockIdx.y * M_TOTAL + qbase + threadIdx.x] = c > CAP ? CAP : c;
  }
}

// ---------------------------------------------------------------------------
// K2a v4: 32 queries x 8 slices; chunk-8 batched key loads (8 independent
// loads in flight per chunk instead of load->cascade->load serial chains).
// ---------------------------------------------------------------------------
__global__ __launch_bounds__(256) void k2a_select(
    const float* __restrict__ pos, const float* __restrict__ sq,
    const unsigned* __restrict__ list, const unsigned* __restrict__ cnt_ws,
    int* __restrict__ nbr) {
  __shared__ unsigned topLds[NSLICE][QT2][9];           // 9.2 KiB (pad 9)
  __shared__ unsigned TLds[QT2];
  __shared__ unsigned ccnt[QT2];
  __shared__ unsigned candLds[QT2][GCAP];               // 5.1 KiB
  __shared__ unsigned long long rrLds[NSLICE][QT2][6];  // 12.3 KiB (pad 6)

  const int l = threadIdx.x & 31;   // query lane
  const int s = threadIdx.x >> 5;   // slice: partitions 2s, 2s+1
  const int q = blockIdx.x * QT2 + l;

  // ---- phase 1: per-slice top-8 over collected keys (chunked loads) ----
  unsigned bd[8];
#pragma unroll
  for (int k = 0; k < 8; ++k) bd[k] = 0xFFFFFFFFu;
#pragma unroll
  for (int pp = 0; pp < 2; ++pp) {
    const int p = s * 2 + pp;
    const unsigned c = cnt_ws[p * M_TOTAL + q];
    const unsigned* base = list + (size_t)(p * CAP) * M_TOTAL + q;
    for (unsigned sl0 = 0; sl0 < c; sl0 += 8) {
      unsigned kk[8];
#pragma unroll
      for (int j = 0; j < 8; ++j) {
        unsigned slj = sl0 + j;
        kk[j] = base[(size_t)(slj < c ? slj : 0) * M_TOTAL];  // 8 loads in flight
      }
#pragma unroll
      for (int j = 0; j < 8; ++j) {
        unsigned cd = (sl0 + j < c) ? kk[j] : 0xFFFFFFFFu;
#pragma unroll
        for (int k = 0; k < 8; ++k) {
          unsigned lo = cd < bd[k] ? cd : bd[k];
          cd = cd < bd[k] ? bd[k] : cd;
          bd[k] = lo;
        }
      }
    }
  }
#pragma unroll
  for (int k = 0; k < 8; ++k) topLds[s][l][k] = bd[k];
  __syncthreads();

  // ---- phase 2: 8-way merge -> 20th of kept -> guard T ----
  if (threadIdx.x < QT2) {
    int i0 = 0, i1 = 0, i2 = 0, i3 = 0, i4 = 0, i5 = 0, i6 = 0, i7 = 0;
    unsigned m = 0;
    for (int k = 0; k < KNN; ++k) {
      unsigned v0 = (i0 < 8) ? topLds[0][l][i0] : 0xFFFFFFFFu;
      unsigned v1 = (i1 < 8) ? topLds[1][l][i1] : 0xFFFFFFFFu;
      unsigned v2 = (i2 < 8) ? topLds[2][l][i2] : 0xFFFFFFFFu;
      unsigned v3 = (i3 < 8) ? topLds[3][l][i3] : 0xFFFFFFFFu;
      unsigned v4 = (i4 < 8) ? topLds[4][l][i4] : 0xFFFFFFFFu;
      unsigned v5 = (i5 < 8) ? topLds[5][l][i5] : 0xFFFFFFFFu;
      unsigned v6 = (i6 < 8) ? topLds[6][l][i6] : 0xFFFFFFFFu;
      unsigned v7 = (i7 < 8) ? topLds[7][l][i7] : 0xFFFFFFFFu;
      unsigned a01 = v0 < v1 ? v0 : v1;
      unsigned a23 = v2 < v3 ? v2 : v3;
      unsigned a45 = v4 < v5 ? v4 : v5;
      unsigned a67 = v6 < v7 ? v6 : v7;
      unsigned a03 = a01 < a23 ? a01 : a23;
      unsigned a47 = a45 < a67 ? a45 : a67;
      m = a03 < a47 ? a03 : a47;
      if (m == v0) i0++;
      else if (m == v1) i1++;
      else if (m == v2) i2++;
      else if (m == v3) i3++;
      else if (m == v4) i4++;
      else if (m == v5) i5++;
      else if (m == v6) i6++;
      else i7++;
    }
    TLds[l] = (m >> 13) + 2;
    ccnt[l] = 0;
  }
  __syncthreads();

  // ---- phase 3: rescan, collect guard set (chunked loads) ----
  const unsigned T = TLds[l];
#pragma unroll
  for (int pp = 0; pp < 2; ++pp) {
    const int p = s * 2 + pp;
    const unsigned c = cnt_ws[p * M_TOTAL + q];
    const unsigned* base = list + (size_t)(p * CAP) * M_TOTAL + q;
    for (unsigned sl0 = 0; sl0 < c; sl0 += 8) {
      unsigned kk[8];
#pragma unroll
      for (int j = 0; j < 8; ++j) {
        unsigned slj = sl0 + j;
        kk[j] = base[(size_t)(slj < c ? slj : 0) * M_TOTAL];
      }
#pragma unroll
      for (int j = 0; j < 8; ++j) {
        if (sl0 + j < c && (kk[j] >> 13) <= T) {
          unsigned pos_ = atomicAdd(&ccnt[l], 1u);
          if (pos_ < GCAP) candLds[l][pos_] = kk[j] & 0x1FFFu;
        }
      }
    }
  }
  __syncthreads();

  // ---- phase 4: exact fp32 d2 re-rank of the guard set ----
  const int cc = min(ccnt[l], (unsigned)GCAP);
  const float sqq = sq[q];
  const float4* qp4 = reinterpret_cast<const float4*>(pos + (size_t)q * 64);
  unsigned long long kb[5];
#pragma unroll
  for (int j = 0; j < 5; ++j) kb[j] = ~0ull;
  for (int j = s; j < cc; j += NSLICE) {
    const unsigned idx = candLds[l][j];
    const float4* cp4 = reinterpret_cast<const float4*>(pos + (size_t)idx * 64);
    float d0 = 0.f, d1 = 0.f, d2 = 0.f, d3 = 0.f;
#pragma unroll
    for (int t = 0; t < 16; ++t) {
      float4 cv = cp4[t];
      float4 qv = qp4[t];  // L1/L2-hot
      d0 = fmaf(cv.x, qv.x, d0);
      d1 = fmaf(cv.y, qv.y, d1);
      d2 = fmaf(cv.z, qv.z, d2);
      d3 = fmaf(cv.w, qv.w, d3);
    }
    float dot = (d0 + d1) + (d2 + d3);
    float dd = fmaxf(fmaf(-2.f, dot, sqq + sq[idx]), 0.f);
    unsigned long long cd = ((unsigned long long)__float_as_uint(dd) << 32) | idx;
#pragma unroll
    for (int k = 0; k < 5; ++k) {  // sorted-5 insert (tie -> smaller idx)
      unsigned long long lo = cd < kb[k] ? cd : kb[k];
      cd = cd < kb[k] ? kb[k] : cd;
      kb[k] = lo;
    }
  }
#pragma unroll
  for (int j = 0; j < 5; ++j) rrLds[s][l][j] = kb[j];
  __syncthreads();

  if (threadIdx.x < QT2) {
    int i0 = 0, i1 = 0, i2 = 0, i3 = 0, i4 = 0, i5 = 0, i6 = 0, i7 = 0;
    for (int k = 0; k < KNN; ++k) {
      unsigned long long v0 = (i0 < 5) ? rrLds[0][l][i0] : ~0ull;
      unsigned long long v1 = (i1 < 5) ? rrLds[1][l][i1] : ~0ull;
      unsigned long long v2 = (i2 < 5) ? rrLds[2][l][i2] : ~0ull;
      unsigned long long v3 = (i3 < 5) ? rrLds[3][l][i3] : ~0ull;
      unsigned long long v4 = (i4 < 5) ? rrLds[4][l][i4] : ~0ull;
      unsigned long long v5 = (i5 < 5) ? rrLds[5][l][i5] : ~0ull;
      unsigned long long v6 = (i6 < 5) ? rrLds[6][l][i6] : ~0ull;
      unsigned long long v7 = (i7 < 5) ? rrLds[7][l][i7] : ~0ull;
      unsigned long long a01 = v0 < v1 ? v0 : v1;
      unsigned long long a23 = v2 < v3 ? v2 : v3;
      unsigned long long a45 = v4 < v5 ? v4 : v5;
      unsigned long long a67 = v6 < v7 ? v6 : v7;
      unsigned long long a03 = a01 < a23 ? a01 : a23;
      unsigned long long a47 = a45 < a67 ? a45 : a67;
      unsigned long long m = a03 < a47 ? a03 : a47;
      if (m == v0) i0++;
      else if (m == v1) i1++;
      else if (m == v2) i2++;
      else if (m == v3) i3++;
      else if (m == v4) i4++;
      else if (m == v5) i5++;
      else if (m == v6) i6++;
      else i7++;
      nbr[q * KNN + k] = (int)(unsigned)(m & 0xFFFFFFFFu);
    }
  }
}

// ---------------------------------------------------------------------------
// K2b: MLP + max-aggregation via MFMA. One wave per query. (unchanged)
// ---------------------------------------------------------------------------
__global__ __launch_bounds__(256) void k2b_mlp(
    const float* __restrict__ a_in, const float* __restrict__ g_in,
    const unsigned short* __restrict__ w2sw, const float* __restrict__ b2,
    const int* __restrict__ nbr, float* __restrict__ out) {
  const int lane = threadIdx.x & 63;
  const int wv = threadIdx.x >> 6;
  const int q = blockIdx.x * 4 + wv;
  const int col = lane & 15;
  const int quad = lane >> 4;

  const int n0 = nbr[q * KNN + col];
  const int n1 = nbr[q * KNN + ((16 + col) % KNN)];

  bf16x8 Bf[8];
#pragma unroll
  for (int f = 0; f < 8; ++f)
    Bf[f] = *(const bf16x8*)(w2sw + ((size_t)f * 64 + lane) * 8);

  const f32x4 zf = {0.f, 0.f, 0.f, 0.f};
  f32x4 acc0[4] = {zf, zf, zf, zf};
  f32x4 acc1[4] = {zf, zf, zf, zf};

#pragma unroll
  for (int seg = 0; seg < 2; ++seg) {
    const int dOff = seg * 32 + quad * 8;
    const float4* ap = reinterpret_cast<const float4*>(a_in + (size_t)q * 64 + dOff);
    const float4* g0p = reinterpret_cast<const float4*>(g_in + (size_t)n0 * 64 + dOff);
    const float4* g1p = reinterpret_cast<const float4*>(g_in + (size_t)n1 * 64 + dOff);
    float4 aa0 = ap[0], aa1 = ap[1];
    float4 gg0 = g0p[0], gg1 = g0p[1];
    float4 hh0 = g1p[0], hh1 = g1p[1];
    float av[8] = {aa0.x, aa0.y, aa0.z, aa0.w, aa1.x, aa1.y, aa1.z, aa1.w};
    float g0v[8] = {gg0.x, gg0.y, gg0.z, gg0.w, gg1.x, gg1.y, gg1.z, gg1.w};
    float g1v[8] = {hh0.x, hh0.y, hh0.z, hh0.w, hh1.x, hh1.y, hh1.z, hh1.w};
    bf16x8 A0, A1;
#pragma unroll
    for (int j = 0; j < 8; ++j) {
      A0[j] = (short)bf16rne(fmaxf(av[j] + g0v[j], 0.f));
      A1[j] = (short)bf16rne(fmaxf(av[j] + g1v[j], 0.f));
    }
#pragma unroll
    for (int t = 0; t < 4; ++t) {
      acc0[t] = __builtin_amdgcn_mfma_f32_16x16x32_bf16(A0, Bf[seg * 4 + t], acc0[t], 0, 0, 0);
      acc1[t] = __builtin_amdgcn_mfma_f32_16x16x32_bf16(A1, Bf[seg * 4 + t], acc1[t], 0, 0, 0);
    }
  }

  float res = 0.f;
#pragma unroll
  for (int t = 0; t < 4; ++t) {
    float m = fmaxf(fmaxf(fmaxf(acc0[t][0], acc1[t][0]), fmaxf(acc0[t][1], acc1[t][1])),
                    fmaxf(fmaxf(acc0[t][2], acc1[t][2]), fmaxf(acc0[t][3], acc1[t][3])));
    m = fmaxf(m, __shfl_xor(m, 16, 64));
    m = fmaxf(m, __shfl_xor(m, 32, 64));
    res = (quad == t) ? m : res;
  }
  out[(size_t)q * 64 + lane] = res + b2[lane];
}

// ---------------------------------------------------------------------------
extern "C" void kernel_launch(void* const* d_in, const int* in_sizes, int n_in,
                              void* d_out, int out_size, void* d_ws, size_t ws_size,
                              hipStream_t stream) {
  const float* pos = (const float*)d_in[0];
  const float* feat = (const float*)d_in[1];
  const float* W1 = (const float*)d_in[2];
  const float* b1 = (const float*)d_in[3];
  const float* W2 = (const float*)d_in[4];
  const float* b2 = (const float*)d_in[5];
  float* out = (float*)d_out;

  // ws layout (bytes), total ~24.3 MiB:
  //   sq    @ 0         32 KiB
  //   a     @ 32768     2 MiB
  //   g     @ 2129920   2 MiB
  //   poshi @ 4227072   1 MiB
  //   poslo @ 5275648   1 MiB
  //   w2sw  @ 6324224   8 KiB
  //   list  @ 6332416   16 MiB  (512 slots x 8192 queries, transposed u32 keys)
  //   cnt   @ 23109632  512 KiB (16 x 8192, transposed)
  //   tau   @ 23633920  32 KiB
  //   nbr   @ 23666688  640 KiB (8192 * 20 * 4)
  char* ws = (char*)d_ws;
  float* sq = (float*)ws;
  float* a = (float*)(ws + 32768);
  float* g = (float*)(ws + 2129920);
  unsigned short* poshi = (unsigned short*)(ws + 4227072);
  unsigned short* poslo = (unsigned short*)(ws + 5275648);
  unsigned short* w2sw = (unsigned short*)(ws + 6324224);
  unsigned* list = (unsigned*)(ws + 6332416);
  unsigned* cnt_ws = (unsigned*)(ws + 23109632);
  float* tau_g = (float*)(ws + 23633920);
  int* nbr = (int*)(ws + 23666688);

  k0_pre<<<M_TOTAL / 4, 256, 0, stream>>>(pos, feat, W1, b1, sq, a, g, poshi, poslo);
  k0b_w2sw<<<2, 256, 0, stream>>>(W2, w2sw);
  k1a_tau<<<M_TOTAL / QT1A, 256, 0, stream>>>(poshi, poslo, sq, tau_g);
  k1b_collect<<<dim3(M_TOTAL / QT, PPART), 256, 0, stream>>>(poshi, poslo, sq, tau_g, list, cnt_ws);
  k2a_select<<<M_TOTAL / QT2, 256, 0, stream>>>(pos, sq, list, cnt_ws, nbr);
  k2b_mlp<<<M_TOTAL / 4, 256, 0, stream>>>(a, g, w2sw, b2, nbr, out);
}

// Round 10
// 192.001 us; speedup vs baseline: 1.8868x; 1.0651x over previous
//
#include <hip/hip_runtime.h>
#include <cfloat>
#include <cstdint>

// Problem constants (B=4, N=2048, C=64, O=64, K=20)
#define M_TOTAL 8192
#define KNN 20
#define PPART 16                 // candidate partitions
#define CPB (M_TOTAL / PPART)    // 512 candidates per K1b block
#define QT 64                    // queries per K1b block
#define QT1A 32                  // queries per K1a block
#define SAMPLE 1024              // tau sample = candidates [0, 1024)
#define CAP 32                   // collect capacity per (query,partition)
#define SLOTS (PPART * CAP)      // 512
#define QT2 32                   // queries per K2a block
#define NSLICE 8                 // slices per K2a block (2 partitions each)
#define GCAP 40                  // guard-collect cap in k2a

typedef __attribute__((ext_vector_type(8))) short bf16x8;  // 8 bf16 (4 VGPRs)
typedef __attribute__((ext_vector_type(4))) float f32x4;

__device__ __forceinline__ unsigned short bf16rne(float x) {
  unsigned u = __float_as_uint(x);
  return (unsigned short)((u + 0x7FFFu + ((u >> 16) & 1u)) >> 16);
}

// ---------------------------------------------------------------------------
// K0: per-point precompute. sq, bf16 pos (hi only -- k1 distances are hi*hi;
// error ~0.2 val-units vs ~10.6-unit selection margin, and k2a re-ranks in
// exact fp32), factored layer-1 (a, g).
// ---------------------------------------------------------------------------
__global__ __launch_bounds__(256) void k0_pre(
    const float* __restrict__ pos, const float* __restrict__ feat,
    const float* __restrict__ W1, const float* __restrict__ b1,
    float* __restrict__ sq, float* __restrict__ a_out, float* __restrict__ g_out,
    unsigned short* __restrict__ poshi) {
  __shared__ float fLds[4][64];
  const int lane = threadIdx.x & 63;
  const int rl = threadIdx.x >> 6;
  const int r = blockIdx.x * 4 + rl;

  float p = pos[r * 64 + lane];
  float f = feat[r * 64 + lane];
  fLds[rl][lane] = f;  // wave-private row; wave lockstep

  poshi[r * 64 + lane] = bf16rne(p);

  float s = p * p;
#pragma unroll
  for (int off = 1; off < 64; off <<= 1) s += __shfl_xor(s, off, 64);
  if (lane == 0) sq[r] = s;

  float acc_a = b1[lane];
  float acc_g = 0.f;
  const float4* f4 = reinterpret_cast<const float4*>(fLds[rl]);
#pragma unroll
  for (int i = 0; i < 16; ++i) {
    float4 fv = f4[i];
    float fd[4] = {fv.x, fv.y, fv.z, fv.w};
#pragma unroll
    for (int j = 0; j < 4; ++j) {
      int d = 4 * i + j;
      float wt = W1[d * 64 + lane];
      float wb = W1[(64 + d) * 64 + lane];
      acc_a = fmaf(fd[j], wt - wb, acc_a);
      acc_g = fmaf(fd[j], wb, acc_g);
    }
  }
  a_out[r * 64 + lane] = acc_a;
  g_out[r * 64 + lane] = acc_g;
}

// ---------------------------------------------------------------------------
// K0b: swizzle W2 into bf16 B-fragment layout for 16x16x32 MFMA.
// ---------------------------------------------------------------------------
__global__ __launch_bounds__(256) void k0b_w2sw(
    const float* __restrict__ W2, unsigned short* __restrict__ w2sw) {
  const int u = blockIdx.x * 256 + threadIdx.x;  // [0, 512)
  const int f = u >> 6, lane = u & 63;
  const int seg = f >> 2, t = f & 3;
  const int quad = lane >> 4, col = lane & 15;
#pragma unroll
  for (int j = 0; j < 8; ++j) {
    int d = seg * 32 + quad * 8 + j;
    w2sw[u * 8 + j] = bf16rne(W2[d * 64 + t * 16 + col]);
  }
}

// ---------------------------------------------------------------------------
// K1a: tau_q >= sample-20th d-hat (overestimate widens superset: safe).
// 256 blocks; wave w covers cand cols 16w..16w+15; lane = (query l&31,
// cand-half l>>5); top-8 per 128-cand stream; tau = 20th of 64 kept, +0.5
// margin for hi-only d-hat error. Hi-only: 4 MFMAs/stripe, 2 loads/stripe.
// A[m=lane&15][k=quad*8+j]; D: col=lane&15, row=quad*4+reg (m89-verified).
// ---------------------------------------------------------------------------
__global__ __launch_bounds__(256) void k1a_tau(
    const unsigned short* __restrict__ poshi,
    const float* __restrict__ sq, float* __restrict__ tau_g) {
  __shared__ float vw[4][16][36];        // wave-private transpose, 9 KiB
  __shared__ float sqcLds[SAMPLE];       // 4 KiB
  __shared__ float topLds[8][8][33];     // [stream][k][q], 8.25 KiB
  const int lane = threadIdx.x & 63;
  const int w = threadIdx.x >> 6;
  const int qbase = blockIdx.x * QT1A;
  const int col = lane & 15;
  const int quad = lane >> 4;
  const int dimOff = quad * 8;
  const int qq = lane & 31;     // query owned in cascade phase
  const int h = lane >> 5;      // candidate half owned

  for (int i = threadIdx.x; i < SAMPLE; i += 256) sqcLds[i] = sq[i];

  bf16x8 Ahi[2][2];
#pragma unroll
  for (int s = 0; s < 2; ++s) {
    int row = qbase + s * 16 + col;
    Ahi[s][0] = *(const bf16x8*)(poshi + (size_t)row * 64 + dimOff);
    Ahi[s][1] = *(const bf16x8*)(poshi + (size_t)row * 64 + dimOff + 32);
  }
  __syncthreads();  // sqcLds ready

  const f32x4 zf = {0.f, 0.f, 0.f, 0.f};
  float bd[8];
#pragma unroll
  for (int k = 0; k < 8; ++k) bd[k] = FLT_MAX;

  bf16x8 Bh0 = *(const bf16x8*)(poshi + (size_t)(w * 16 + col) * 64 + dimOff);
  bf16x8 Bh1 = *(const bf16x8*)(poshi + (size_t)(w * 16 + col) * 64 + dimOff + 32);
  for (int c0 = 0; c0 < SAMPLE; c0 += 64) {
    const int nc0 = (c0 + 64 < SAMPLE) ? c0 + 64 : c0;
    bf16x8 Nh0 = *(const bf16x8*)(poshi + (size_t)(nc0 + w * 16 + col) * 64 + dimOff);
    bf16x8 Nh1 = *(const bf16x8*)(poshi + (size_t)(nc0 + w * 16 + col) * 64 + dimOff + 32);

    f32x4 acc[2] = {zf, zf};
#pragma unroll
    for (int s = 0; s < 2; ++s) {
      acc[s] = __builtin_amdgcn_mfma_f32_16x16x32_bf16(Ahi[s][0], Bh0, acc[s], 0, 0, 0);
      acc[s] = __builtin_amdgcn_mfma_f32_16x16x32_bf16(Ahi[s][1], Bh1, acc[s], 0, 0, 0);
    }
    const float sqcv = sqcLds[c0 + w * 16 + col] + 256.0f;
#pragma unroll
    for (int s = 0; s < 2; ++s) {
      float4 v4;
      v4.x = fmaf(-2.f, acc[s][0], sqcv);
      v4.y = fmaf(-2.f, acc[s][1], sqcv);
      v4.z = fmaf(-2.f, acc[s][2], sqcv);
      v4.w = fmaf(-2.f, acc[s][3], sqcv);
      *reinterpret_cast<float4*>(&vw[w][col][s * 16 + quad * 4]) = v4;
    }
    __builtin_amdgcn_wave_barrier();  // wave-private region, lockstep
#pragma unroll
    for (int i = 0; i < 8; ++i) {
      float cd = vw[w][h * 8 + i][qq];
#pragma unroll
      for (int k = 0; k < 8; ++k) {  // branch-free sorted insert (top-8)
        float lo = fminf(cd, bd[k]);
        cd = fmaxf(cd, bd[k]);
        bd[k] = lo;
      }
    }
    __builtin_amdgcn_wave_barrier();
    Bh0 = Nh0; Bh1 = Nh1;
  }

#pragma unroll
  for (int k = 0; k < 8; ++k) topLds[w * 2 + h][k][qq] = bd[k];
  __syncthreads();

  if (threadIdx.x < QT1A) {
    const int l = threadIdx.x;
    int ix[8] = {0, 0, 0, 0, 0, 0, 0, 0};
    float tau = FLT_MAX;
    for (int k = 0; k < KNN; ++k) {
      float best = FLT_MAX;
      int bs = 0;
#pragma unroll
      for (int st = 0; st < 8; ++st) {
        float v = (ix[st] < 8) ? topLds[st][ix[st]][l] : FLT_MAX;
        if (v < best) { best = v; bs = st; }
      }
      ix[bs]++;
      tau = best;
    }
    tau_g[qbase + l] = tau + 0.5f;  // margin covers hi-only d-hat error
  }
}

// ---------------------------------------------------------------------------
// K1b v5: hi-only distances; ALL 8 stripes' B preloaded into registers
// before the loop (16 loads in flight during setup) -> the stripe loop has
// ZERO global loads, no vmcnt stalls for the scheduler to mis-place.
// Collect val <= tau_q as packed u32 key (19-bit val-bits | 13-bit idx),
// transposed layout for K2a coalescing.
// ---------------------------------------------------------------------------
__global__ __launch_bounds__(256) void k1b_collect(
    const unsigned short* __restrict__ poshi,
    const float* __restrict__ sq, const float* __restrict__ tau_g,
    unsigned* __restrict__ list, unsigned* __restrict__ cnt_ws) {
  __shared__ float sqcLds[CPB];
  __shared__ float tauLds[QT];
  __shared__ unsigned cntLds[QT];

  const int lane = threadIdx.x & 63;
  const int w = threadIdx.x >> 6;
  const int qbase = blockIdx.x * QT;
  const int cbase = blockIdx.y * CPB;
  const int col = lane & 15;
  const int quad = lane >> 4;
  const int dimOff = quad * 8;

  // B preload first: 16 loads in flight while the rest of setup runs
  bf16x8 B[8][2];
#pragma unroll
  for (int st = 0; st < 8; ++st) {
    const size_t row = (size_t)(cbase + st * 64 + w * 16 + col) * 64;
    B[st][0] = *(const bf16x8*)(poshi + row + dimOff);
    B[st][1] = *(const bf16x8*)(poshi + row + dimOff + 32);
  }

  for (int i = threadIdx.x; i < CPB; i += 256) sqcLds[i] = sq[cbase + i];
  if (threadIdx.x < QT) {
    tauLds[threadIdx.x] = tau_g[qbase + threadIdx.x];
    cntLds[threadIdx.x] = 0;
  }

  bf16x8 Ahi[4][2];
#pragma unroll
  for (int s = 0; s < 4; ++s) {
    int row = qbase + s * 16 + col;
    Ahi[s][0] = *(const bf16x8*)(poshi + (size_t)row * 64 + dimOff);
    Ahi[s][1] = *(const bf16x8*)(poshi + (size_t)row * 64 + dimOff + 32);
  }
  __syncthreads();

  float tau_l[4][4];
#pragma unroll
  for (int s = 0; s < 4; ++s)
#pragma unroll
    for (int r = 0; r < 4; ++r) tau_l[s][r] = tauLds[s * 16 + quad * 4 + r];

  const f32x4 zf = {0.f, 0.f, 0.f, 0.f};
#pragma unroll
  for (int st = 0; st < 8; ++st) {
    f32x4 acc[4] = {zf, zf, zf, zf};
#pragma unroll
    for (int s = 0; s < 4; ++s) {
      acc[s] = __builtin_amdgcn_mfma_f32_16x16x32_bf16(Ahi[s][0], B[st][0], acc[s], 0, 0, 0);
      acc[s] = __builtin_amdgcn_mfma_f32_16x16x32_bf16(Ahi[s][1], B[st][1], acc[s], 0, 0, 0);
    }
    const int candRow = cbase + st * 64 + w * 16 + col;
    const float sqcv = sqcLds[st * 64 + w * 16 + col] + 256.0f;
#pragma unroll
    for (int s = 0; s < 4; ++s) {
#pragma unroll
      for (int r = 0; r < 4; ++r) {
        float val = fmaf(-2.f, acc[s][r], sqcv);
        const int qrow = s * 16 + quad * 4 + r;
        if (val <= tau_l[s][r]) {  // ~2% of lanes
          unsigned slot = atomicAdd(&cntLds[qrow], 1u);
          if (slot < CAP)
            list[(size_t)(blockIdx.y * CAP + slot) * M_TOTAL + qbase + qrow] =
                (__float_as_uint(val) & 0xFFFFE000u) | (unsigned)candRow;
        }
      }
    }
  }
  __syncthreads();
  if (threadIdx.x < QT) {
    unsigned c = cntLds[threadIdx.x];
    cnt_ws[blockIdx.y * M_TOTAL + qbase + threadIdx.x] = c > CAP ? CAP : c;
  }
}

// ---------------------------------------------------------------------------
// K2a: 32 queries x 8 slices; chunk-8 batched key loads; guard +3 quanta
// (0.75 val) covers hi-only d-hat error in the quantized keys.
// ---------------------------------------------------------------------------
__global__ __launch_bounds__(256) void k2a_select(
    const float* __restrict__ pos, const float* __restrict__ sq,
    const unsigned* __restrict__ list, const unsigned* __restrict__ cnt_ws,
    int* __restrict__ nbr) {
  __shared__ unsigned topLds[NSLICE][QT2][9];           // 9.2 KiB (pad 9)
  __shared__ unsigned TLds[QT2];
  __shared__ unsigned ccnt[QT2];
  __shared__ unsigned candLds[QT2][GCAP];               // 5.1 KiB
  __shared__ unsigned long long rrLds[NSLICE][QT2][6];  // 12.3 KiB (pad 6)

  const int l = threadIdx.x & 31;   // query lane
  const int s = threadIdx.x >> 5;   // slice: partitions 2s, 2s+1
  const int q = blockIdx.x * QT2 + l;

  // ---- phase 1: per-slice top-8 over collected keys (chunked loads) ----
  unsigned bd[8];
#pragma unroll
  for (int k = 0; k < 8; ++k) bd[k] = 0xFFFFFFFFu;
#pragma unroll
  for (int pp = 0; pp < 2; ++pp) {
    const int p = s * 2 + pp;
    const unsigned c = cnt_ws[p * M_TOTAL + q];
    const unsigned* base = list + (size_t)(p * CAP) * M_TOTAL + q;
    for (unsigned sl0 = 0; sl0 < c; sl0 += 8) {
      unsigned kk[8];
#pragma unroll
      for (int j = 0; j < 8; ++j) {
        unsigned slj = sl0 + j;
        kk[j] = base[(size_t)(slj < c ? slj : 0) * M_TOTAL];  // 8 loads in flight
      }
#pragma unroll
      for (int j = 0; j < 8; ++j) {
        unsigned cd = (sl0 + j < c) ? kk[j] : 0xFFFFFFFFu;
#pragma unroll
        for (int k = 0; k < 8; ++k) {
          unsigned lo = cd < bd[k] ? cd : bd[k];
          cd = cd < bd[k] ? bd[k] : cd;
          bd[k] = lo;
        }
      }
    }
  }
#pragma unroll
  for (int k = 0; k < 8; ++k) topLds[s][l][k] = bd[k];
  __syncthreads();

  // ---- phase 2: 8-way merge -> 20th of kept -> guard T ----
  if (threadIdx.x < QT2) {
    int i0 = 0, i1 = 0, i2 = 0, i3 = 0, i4 = 0, i5 = 0, i6 = 0, i7 = 0;
    unsigned m = 0;
    for (int k = 0; k < KNN; ++k) {
      unsigned v0 = (i0 < 8) ? topLds[0][l][i0] : 0xFFFFFFFFu;
      unsigned v1 = (i1 < 8) ? topLds[1][l][i1] : 0xFFFFFFFFu;
      unsigned v2 = (i2 < 8) ? topLds[2][l][i2] : 0xFFFFFFFFu;
      unsigned v3 = (i3 < 8) ? topLds[3][l][i3] : 0xFFFFFFFFu;
      unsigned v4 = (i4 < 8) ? topLds[4][l][i4] : 0xFFFFFFFFu;
      unsigned v5 = (i5 < 8) ? topLds[5][l][i5] : 0xFFFFFFFFu;
      unsigned v6 = (i6 < 8) ? topLds[6][l][i6] : 0xFFFFFFFFu;
      unsigned v7 = (i7 < 8) ? topLds[7][l][i7] : 0xFFFFFFFFu;
      unsigned a01 = v0 < v1 ? v0 : v1;
      unsigned a23 = v2 < v3 ? v2 : v3;
      unsigned a45 = v4 < v5 ? v4 : v5;
      unsigned a67 = v6 < v7 ? v6 : v7;
      unsigned a03 = a01 < a23 ? a01 : a23;
      unsigned a47 = a45 < a67 ? a45 : a67;
      m = a03 < a47 ? a03 : a47;
      if (m == v0) i0++;
      else if (m == v1) i1++;
      else if (m == v2) i2++;
      else if (m == v3) i3++;
      else if (m == v4) i4++;
      else if (m == v5) i5++;
      else if (m == v6) i6++;
      else i7++;
    }
    TLds[l] = (m >> 13) + 3;
    ccnt[l] = 0;
  }
  __syncthreads();

  // ---- phase 3: rescan, collect guard set (chunked loads) ----
  const unsigned T = TLds[l];
#pragma unroll
  for (int pp = 0; pp < 2; ++pp) {
    const int p = s * 2 + pp;
    const unsigned c = cnt_ws[p * M_TOTAL + q];
    const unsigned* base = list + (size_t)(p * CAP) * M_TOTAL + q;
    for (unsigned sl0 = 0; sl0 < c; sl0 += 8) {
      unsigned kk[8];
#pragma unroll
      for (int j = 0; j < 8; ++j) {
        unsigned slj = sl0 + j;
        kk[j] = base[(size_t)(slj < c ? slj : 0) * M_TOTAL];
      }
#pragma unroll
      for (int j = 0; j < 8; ++j) {
        if (sl0 + j < c && (kk[j] >> 13) <= T) {
          unsigned pos_ = atomicAdd(&ccnt[l], 1u);
          if (pos_ < GCAP) candLds[l][pos_] = kk[j] & 0x1FFFu;
        }
      }
    }
  }
  __syncthreads();

  // ---- phase 4: exact fp32 d2 re-rank of the guard set ----
  const int cc = min(ccnt[l], (unsigned)GCAP);
  const float sqq = sq[q];
  const float4* qp4 = reinterpret_cast<const float4*>(pos + (size_t)q * 64);
  unsigned long long kb[5];
#pragma unroll
  for (int j = 0; j < 5; ++j) kb[j] = ~0ull;
  for (int j = s; j < cc; j += NSLICE) {
    const unsigned idx = candLds[l][j];
    const float4* cp4 = reinterpret_cast<const float4*>(pos + (size_t)idx * 64);
    float d0 = 0.f, d1 = 0.f, d2 = 0.f, d3 = 0.f;
#pragma unroll
    for (int t = 0; t < 16; ++t) {
      float4 cv = cp4[t];
      float4 qv = qp4[t];  // L1/L2-hot
      d0 = fmaf(cv.x, qv.x, d0);
      d1 = fmaf(cv.y, qv.y, d1);
      d2 = fmaf(cv.z, qv.z, d2);
      d3 = fmaf(cv.w, qv.w, d3);
    }
    float dot = (d0 + d1) + (d2 + d3);
    float dd = fmaxf(fmaf(-2.f, dot, sqq + sq[idx]), 0.f);
    unsigned long long cd = ((unsigned long long)__float_as_uint(dd) << 32) | idx;
#pragma unroll
    for (int k = 0; k < 5; ++k) {  // sorted-5 insert (tie -> smaller idx)
      unsigned long long lo = cd < kb[k] ? cd : kb[k];
      cd = cd < kb[k] ? kb[k] : cd;
      kb[k] = lo;
    }
  }
#pragma unroll
  for (int j = 0; j < 5; ++j) rrLds[s][l][j] = kb[j];
  __syncthreads();

  if (threadIdx.x < QT2) {
    int i0 = 0, i1 = 0, i2 = 0, i3 = 0, i4 = 0, i5 = 0, i6 = 0, i7 = 0;
    for (int k = 0; k < KNN; ++k) {
      unsigned long long v0 = (i0 < 5) ? rrLds[0][l][i0] : ~0ull;
      unsigned long long v1 = (i1 < 5) ? rrLds[1][l][i1] : ~0ull;
      unsigned long long v2 = (i2 < 5) ? rrLds[2][l][i2] : ~0ull;
      unsigned long long v3 = (i3 < 5) ? rrLds[3][l][i3] : ~0ull;
      unsigned long long v4 = (i4 < 5) ? rrLds[4][l][i4] : ~0ull;
      unsigned long long v5 = (i5 < 5) ? rrLds[5][l][i5] : ~0ull;
      unsigned long long v6 = (i6 < 5) ? rrLds[6][l][i6] : ~0ull;
      unsigned long long v7 = (i7 < 5) ? rrLds[7][l][i7] : ~0ull;
      unsigned long long a01 = v0 < v1 ? v0 : v1;
      unsigned long long a23 = v2 < v3 ? v2 : v3;
      unsigned long long a45 = v4 < v5 ? v4 : v5;
      unsigned long long a67 = v6 < v7 ? v6 : v7;
      unsigned long long a03 = a01 < a23 ? a01 : a23;
      unsigned long long a47 = a45 < a67 ? a45 : a67;
      unsigned long long m = a03 < a47 ? a03 : a47;
      if (m == v0) i0++;
      else if (m == v1) i1++;
      else if (m == v2) i2++;
      else if (m == v3) i3++;
      else if (m == v4) i4++;
      else if (m == v5) i5++;
      else if (m == v6) i6++;
      else i7++;
      nbr[q * KNN + k] = (int)(unsigned)(m & 0xFFFFFFFFu);
    }
  }
}

// ---------------------------------------------------------------------------
// K2b: MLP + max-aggregation via MFMA. One wave per query. (unchanged)
// ---------------------------------------------------------------------------
__global__ __launch_bounds__(256) void k2b_mlp(
    const float* __restrict__ a_in, const float* __restrict__ g_in,
    const unsigned short* __restrict__ w2sw, const float* __restrict__ b2,
    const int* __restrict__ nbr, float* __restrict__ out) {
  const int lane = threadIdx.x & 63;
  const int wv = threadIdx.x >> 6;
  const int q = blockIdx.x * 4 + wv;
  const int col = lane & 15;
  const int quad = lane >> 4;

  const int n0 = nbr[q * KNN + col];
  const int n1 = nbr[q * KNN + ((16 + col) % KNN)];

  bf16x8 Bf[8];
#pragma unroll
  for (int f = 0; f < 8; ++f)
    Bf[f] = *(const bf16x8*)(w2sw + ((size_t)f * 64 + lane) * 8);

  const f32x4 zf = {0.f, 0.f, 0.f, 0.f};
  f32x4 acc0[4] = {zf, zf, zf, zf};
  f32x4 acc1[4] = {zf, zf, zf, zf};

#pragma unroll
  for (int seg = 0; seg < 2; ++seg) {
    const int dOff = seg * 32 + quad * 8;
    const float4* ap = reinterpret_cast<const float4*>(a_in + (size_t)q * 64 + dOff);
    const float4* g0p = reinterpret_cast<const float4*>(g_in + (size_t)n0 * 64 + dOff);
    const float4* g1p = reinterpret_cast<const float4*>(g_in + (size_t)n1 * 64 + dOff);
    float4 aa0 = ap[0], aa1 = ap[1];
    float4 gg0 = g0p[0], gg1 = g0p[1];
    float4 hh0 = g1p[0], hh1 = g1p[1];
    float av[8] = {aa0.x, aa0.y, aa0.z, aa0.w, aa1.x, aa1.y, aa1.z, aa1.w};
    float g0v[8] = {gg0.x, gg0.y, gg0.z, gg0.w, gg1.x, gg1.y, gg1.z, gg1.w};
    float g1v[8] = {hh0.x, hh0.y, hh0.z, hh0.w, hh1.x, hh1.y, hh1.z, hh1.w};
    bf16x8 A0, A1;
#pragma unroll
    for (int j = 0; j < 8; ++j) {
      A0[j] = (short)bf16rne(fmaxf(av[j] + g0v[j], 0.f));
      A1[j] = (short)bf16rne(fmaxf(av[j] + g1v[j], 0.f));
    }
#pragma unroll
    for (int t = 0; t < 4; ++t) {
      acc0[t] = __builtin_amdgcn_mfma_f32_16x16x32_bf16(A0, Bf[seg * 4 + t], acc0[t], 0, 0, 0);
      acc1[t] = __builtin_amdgcn_mfma_f32_16x16x32_bf16(A1, Bf[seg * 4 + t], acc1[t], 0, 0, 0);
    }
  }

  float res = 0.f;
#pragma unroll
  for (int t = 0; t < 4; ++t) {
    float m = fmaxf(fmaxf(fmaxf(acc0[t][0], acc1[t][0]), fmaxf(acc0[t][1], acc1[t][1])),
                    fmaxf(fmaxf(acc0[t][2], acc1[t][2]), fmaxf(acc0[t][3], acc1[t][3])));
    m = fmaxf(m, __shfl_xor(m, 16, 64));
    m = fmaxf(m, __shfl_xor(m, 32, 64));
    res = (quad == t) ? m : res;
  }
  out[(size_t)q * 64 + lane] = res + b2[lane];
}

// ---------------------------------------------------------------------------
extern "C" void kernel_launch(void* const* d_in, const int* in_sizes, int n_in,
                              void* d_out, int out_size, void* d_ws, size_t ws_size,
                              hipStream_t stream) {
  const float* pos = (const float*)d_in[0];
  const float* feat = (const float*)d_in[1];
  const float* W1 = (const float*)d_in[2];
  const float* b1 = (const float*)d_in[3];
  const float* W2 = (const float*)d_in[4];
  const float* b2 = (const float*)d_in[5];
  float* out = (float*)d_out;

  // ws layout (bytes), total ~23.3 MiB:
  //   sq    @ 0         32 KiB
  //   a     @ 32768     2 MiB
  //   g     @ 2129920   2 MiB
  //   poshi @ 4227072   1 MiB
  //   w2sw  @ 6324224   8 KiB
  //   list  @ 6332416   16 MiB  (512 slots x 8192 queries, transposed u32 keys)
  //   cnt   @ 23109632  512 KiB (16 x 8192, transposed)
  //   tau   @ 23633920  32 KiB
  //   nbr   @ 23666688  640 KiB (8192 * 20 * 4)
  char* ws = (char*)d_ws;
  float* sq = (float*)ws;
  float* a = (float*)(ws + 32768);
  float* g = (float*)(ws + 2129920);
  unsigned short* poshi = (unsigned short*)(ws + 4227072);
  unsigned short* w2sw = (unsigned short*)(ws + 6324224);
  unsigned* list = (unsigned*)(ws + 6332416);
  unsigned* cnt_ws = (unsigned*)(ws + 23109632);
  float* tau_g = (float*)(ws + 23633920);
  int* nbr = (int*)(ws + 23666688);

  k0_pre<<<M_TOTAL / 4, 256, 0, stream>>>(pos, feat, W1, b1, sq, a, g, poshi);
  k0b_w2sw<<<2, 256, 0, stream>>>(W2, w2sw);
  k1a_tau<<<M_TOTAL / QT1A, 256, 0, stream>>>(poshi, sq, tau_g);
  k1b_collect<<<dim3(M_TOTAL / QT, PPART), 256, 0, stream>>>(poshi, sq, tau_g, list, cnt_ws);
  k2a_select<<<M_TOTAL / QT2, 256, 0, stream>>>(pos, sq, list, cnt_ws, nbr);
  k2b_mlp<<<M_TOTAL / 4, 256, 0, stream>>>(a, g, w2sw, b2, nbr, out);
}

// Round 11
// 191.663 us; speedup vs baseline: 1.8901x; 1.0018x over previous
//
#include <hip/hip_runtime.h>
#include <cfloat>
#include <cstdint>

// Problem constants (B=4, N=2048, C=64, O=64, K=20)
#define M_TOTAL 8192
#define KNN 20
#define PPART 16                 // candidate partitions
#define CPB (M_TOTAL / PPART)    // 512 candidates per K1b block
#define QT 64                    // queries per K1b block
#define QT1A 32                  // queries per K1a block
#define SAMPLE 1024              // tau sample = candidates [0, 1024)
#define CAP 32                   // collect capacity per (query,partition)
#define SLOTS (PPART * CAP)      // 512
#define QT2 32                   // queries per K2a block
#define NSLICE 8                 // slices per K2a block (2 partitions each)
#define GCAP 40                  // guard-collect cap in k2a

typedef __attribute__((ext_vector_type(8))) short bf16x8;  // 8 bf16 (4 VGPRs)
typedef __attribute__((ext_vector_type(4))) float f32x4;

__device__ __forceinline__ unsigned short bf16rne(float x) {
  unsigned u = __float_as_uint(x);
  return (unsigned short)((u + 0x7FFFu + ((u >> 16) & 1u)) >> 16);
}

// ---------------------------------------------------------------------------
// K0: per-point precompute. sq, bf16 pos (hi only -- k1 distances are hi*hi;
// error ~0.2 val-units vs ~10.6-unit selection margin, and k2a re-ranks in
// exact fp32), factored layer-1 (a, g). Blocks 0-1 additionally emit the
// W2 bf16 B-fragment swizzle (fused former k0b -- saves a launch).
// ---------------------------------------------------------------------------
__global__ __launch_bounds__(256) void k0_pre(
    const float* __restrict__ pos, const float* __restrict__ feat,
    const float* __restrict__ W1, const float* __restrict__ b1,
    const float* __restrict__ W2,
    float* __restrict__ sq, float* __restrict__ a_out, float* __restrict__ g_out,
    unsigned short* __restrict__ poshi, unsigned short* __restrict__ w2sw) {
  __shared__ float fLds[4][64];
  const int lane = threadIdx.x & 63;
  const int rl = threadIdx.x >> 6;
  const int r = blockIdx.x * 4 + rl;

  float p = pos[r * 64 + lane];
  float f = feat[r * 64 + lane];
  fLds[rl][lane] = f;  // wave-private row; wave lockstep

  poshi[r * 64 + lane] = bf16rne(p);

  float s = p * p;
#pragma unroll
  for (int off = 1; off < 64; off <<= 1) s += __shfl_xor(s, off, 64);
  if (lane == 0) sq[r] = s;

  float acc_a = b1[lane];
  float acc_g = 0.f;
  const float4* f4 = reinterpret_cast<const float4*>(fLds[rl]);
#pragma unroll
  for (int i = 0; i < 16; ++i) {
    float4 fv = f4[i];
    float fd[4] = {fv.x, fv.y, fv.z, fv.w};
#pragma unroll
    for (int j = 0; j < 4; ++j) {
      int d = 4 * i + j;
      float wt = W1[d * 64 + lane];
      float wb = W1[(64 + d) * 64 + lane];
      acc_a = fmaf(fd[j], wt - wb, acc_a);
      acc_g = fmaf(fd[j], wb, acc_g);
    }
  }
  a_out[r * 64 + lane] = acc_a;
  g_out[r * 64 + lane] = acc_g;

  // fused k0b: W2 -> bf16 B-fragment swizzle (frag f = seg*4 + t)
  if (blockIdx.x < 2) {
    const int u = blockIdx.x * 256 + threadIdx.x;  // [0, 512)
    const int fr = u >> 6, ul = u & 63;
    const int seg = fr >> 2, t = fr & 3;
    const int uq = ul >> 4, uc = ul & 15;
#pragma unroll
    for (int j = 0; j < 8; ++j) {
      int d = seg * 32 + uq * 8 + j;
      w2sw[u * 8 + j] = bf16rne(W2[d * 64 + t * 16 + uc]);
    }
  }
}

// ---------------------------------------------------------------------------
// K1a: tau_q >= sample-20th d-hat (overestimate widens superset: safe).
// 256 blocks; wave w covers cand cols 16w..16w+15; lane = (query l&31,
// cand-half l>>5); top-8 per 128-cand stream; tau = 20th of 64 kept, +0.5
// margin for hi-only d-hat error. Hi-only: 4 MFMAs/stripe, 2 loads/stripe.
// A[m=lane&15][k=quad*8+j]; D: col=lane&15, row=quad*4+reg (m89-verified).
// ---------------------------------------------------------------------------
__global__ __launch_bounds__(256) void k1a_tau(
    const unsigned short* __restrict__ poshi,
    const float* __restrict__ sq, float* __restrict__ tau_g) {
  __shared__ float vw[4][16][36];        // wave-private transpose, 9 KiB
  __shared__ float sqcLds[SAMPLE];       // 4 KiB
  __shared__ float topLds[8][8][33];     // [stream][k][q], 8.25 KiB
  const int lane = threadIdx.x & 63;
  const int w = threadIdx.x >> 6;
  const int qbase = blockIdx.x * QT1A;
  const int col = lane & 15;
  const int quad = lane >> 4;
  const int dimOff = quad * 8;
  const int qq = lane & 31;     // query owned in cascade phase
  const int h = lane >> 5;      // candidate half owned

  for (int i = threadIdx.x; i < SAMPLE; i += 256) sqcLds[i] = sq[i];

  bf16x8 Ahi[2][2];
#pragma unroll
  for (int s = 0; s < 2; ++s) {
    int row = qbase + s * 16 + col;
    Ahi[s][0] = *(const bf16x8*)(poshi + (size_t)row * 64 + dimOff);
    Ahi[s][1] = *(const bf16x8*)(poshi + (size_t)row * 64 + dimOff + 32);
  }
  __syncthreads();  // sqcLds ready

  const f32x4 zf = {0.f, 0.f, 0.f, 0.f};
  float bd[8];
#pragma unroll
  for (int k = 0; k < 8; ++k) bd[k] = FLT_MAX;

  bf16x8 Bh0 = *(const bf16x8*)(poshi + (size_t)(w * 16 + col) * 64 + dimOff);
  bf16x8 Bh1 = *(const bf16x8*)(poshi + (size_t)(w * 16 + col) * 64 + dimOff + 32);
  for (int c0 = 0; c0 < SAMPLE; c0 += 64) {
    const int nc0 = (c0 + 64 < SAMPLE) ? c0 + 64 : c0;
    bf16x8 Nh0 = *(const bf16x8*)(poshi + (size_t)(nc0 + w * 16 + col) * 64 + dimOff);
    bf16x8 Nh1 = *(const bf16x8*)(poshi + (size_t)(nc0 + w * 16 + col) * 64 + dimOff + 32);

    f32x4 acc[2] = {zf, zf};
#pragma unroll
    for (int s = 0; s < 2; ++s) {
      acc[s] = __builtin_amdgcn_mfma_f32_16x16x32_bf16(Ahi[s][0], Bh0, acc[s], 0, 0, 0);
      acc[s] = __builtin_amdgcn_mfma_f32_16x16x32_bf16(Ahi[s][1], Bh1, acc[s], 0, 0, 0);
    }
    const float sqcv = sqcLds[c0 + w * 16 + col] + 256.0f;
#pragma unroll
    for (int s = 0; s < 2; ++s) {
      float4 v4;
      v4.x = fmaf(-2.f, acc[s][0], sqcv);
      v4.y = fmaf(-2.f, acc[s][1], sqcv);
      v4.z = fmaf(-2.f, acc[s][2], sqcv);
      v4.w = fmaf(-2.f, acc[s][3], sqcv);
      *reinterpret_cast<float4*>(&vw[w][col][s * 16 + quad * 4]) = v4;
    }
    __builtin_amdgcn_wave_barrier();  // wave-private region, lockstep
#pragma unroll
    for (int i = 0; i < 8; ++i) {
      float cd = vw[w][h * 8 + i][qq];
#pragma unroll
      for (int k = 0; k < 8; ++k) {  // branch-free sorted insert (top-8)
        float lo = fminf(cd, bd[k]);
        cd = fmaxf(cd, bd[k]);
        bd[k] = lo;
      }
    }
    __builtin_amdgcn_wave_barrier();
    Bh0 = Nh0; Bh1 = Nh1;
  }

#pragma unroll
  for (int k = 0; k < 8; ++k) topLds[w * 2 + h][k][qq] = bd[k];
  __syncthreads();

  if (threadIdx.x < QT1A) {
    const int l = threadIdx.x;
    int ix[8] = {0, 0, 0, 0, 0, 0, 0, 0};
    float tau = FLT_MAX;
    for (int k = 0; k < KNN; ++k) {
      float best = FLT_MAX;
      int bs = 0;
#pragma unroll
      for (int st = 0; st < 8; ++st) {
        float v = (ix[st] < 8) ? topLds[st][ix[st]][l] : FLT_MAX;
        if (v < best) { best = v; bs = st; }
      }
      ix[bs]++;
      tau = best;
    }
    tau_g[qbase + l] = tau + 0.5f;  // margin covers hi-only d-hat error
  }
}

// ---------------------------------------------------------------------------
// K1b v6: hi-only distances; ALL 8 stripes' B preloaded into registers.
// __launch_bounds__(256, 1) relaxes the VGPR budget so the preload STAYS
// resident (round-10's VGPR_Count=76 proved the compiler rematerialized the
// loads into the loop under the default occupancy target). The stripe loop
// then has zero global loads -> no per-stripe vmcnt stalls.
// Collect val <= tau_q as packed u32 key (19-bit val-bits | 13-bit idx),
// transposed layout for K2a coalescing.
// ---------------------------------------------------------------------------
__global__ __launch_bounds__(256, 1) void k1b_collect(
    const unsigned short* __restrict__ poshi,
    const float* __restrict__ sq, const float* __restrict__ tau_g,
    unsigned* __restrict__ list, unsigned* __restrict__ cnt_ws) {
  __shared__ float sqcLds[CPB];
  __shared__ float tauLds[QT];
  __shared__ unsigned cntLds[QT];

  const int lane = threadIdx.x & 63;
  const int w = threadIdx.x >> 6;
  const int qbase = blockIdx.x * QT;
  const int cbase = blockIdx.y * CPB;
  const int col = lane & 15;
  const int quad = lane >> 4;
  const int dimOff = quad * 8;

  // B preload first: 16 loads in flight while the rest of setup runs
  bf16x8 B[8][2];
#pragma unroll
  for (int st = 0; st < 8; ++st) {
    const size_t row = (size_t)(cbase + st * 64 + w * 16 + col) * 64;
    B[st][0] = *(const bf16x8*)(poshi + row + dimOff);
    B[st][1] = *(const bf16x8*)(poshi + row + dimOff + 32);
  }

  for (int i = threadIdx.x; i < CPB; i += 256) sqcLds[i] = sq[cbase + i];
  if (threadIdx.x < QT) {
    tauLds[threadIdx.x] = tau_g[qbase + threadIdx.x];
    cntLds[threadIdx.x] = 0;
  }

  bf16x8 Ahi[4][2];
#pragma unroll
  for (int s = 0; s < 4; ++s) {
    int row = qbase + s * 16 + col;
    Ahi[s][0] = *(const bf16x8*)(poshi + (size_t)row * 64 + dimOff);
    Ahi[s][1] = *(const bf16x8*)(poshi + (size_t)row * 64 + dimOff + 32);
  }
  __syncthreads();

  float tau_l[4][4];
#pragma unroll
  for (int s = 0; s < 4; ++s)
#pragma unroll
    for (int r = 0; r < 4; ++r) tau_l[s][r] = tauLds[s * 16 + quad * 4 + r];

  const f32x4 zf = {0.f, 0.f, 0.f, 0.f};
#pragma unroll
  for (int st = 0; st < 8; ++st) {
    f32x4 acc[4] = {zf, zf, zf, zf};
#pragma unroll
    for (int s = 0; s < 4; ++s) {
      acc[s] = __builtin_amdgcn_mfma_f32_16x16x32_bf16(Ahi[s][0], B[st][0], acc[s], 0, 0, 0);
      acc[s] = __builtin_amdgcn_mfma_f32_16x16x32_bf16(Ahi[s][1], B[st][1], acc[s], 0, 0, 0);
    }
    const int candRow = cbase + st * 64 + w * 16 + col;
    const float sqcv = sqcLds[st * 64 + w * 16 + col] + 256.0f;
#pragma unroll
    for (int s = 0; s < 4; ++s) {
#pragma unroll
      for (int r = 0; r < 4; ++r) {
        float val = fmaf(-2.f, acc[s][r], sqcv);
        const int qrow = s * 16 + quad * 4 + r;
        if (val <= tau_l[s][r]) {  // ~2% of lanes
          unsigned slot = atomicAdd(&cntLds[qrow], 1u);
          if (slot < CAP)
            list[(size_t)(blockIdx.y * CAP + slot) * M_TOTAL + qbase + qrow] =
                (__float_as_uint(val) & 0xFFFFE000u) | (unsigned)candRow;
        }
      }
    }
  }
  __syncthreads();
  if (threadIdx.x < QT) {
    unsigned c = cntLds[threadIdx.x];
    cnt_ws[blockIdx.y * M_TOTAL + qbase + threadIdx.x] = c > CAP ? CAP : c;
  }
}

// ---------------------------------------------------------------------------
// K2a: 32 queries x 8 slices; chunk-8 batched key loads; guard +3 quanta
// (0.75 val) covers hi-only d-hat error in the quantized keys.
// ---------------------------------------------------------------------------
__global__ __launch_bounds__(256) void k2a_select(
    const float* __restrict__ pos, const float* __restrict__ sq,
    const unsigned* __restrict__ list, const unsigned* __restrict__ cnt_ws,
    int* __restrict__ nbr) {
  __shared__ unsigned topLds[NSLICE][QT2][9];           // 9.2 KiB (pad 9)
  __shared__ unsigned TLds[QT2];
  __shared__ unsigned ccnt[QT2];
  __shared__ unsigned candLds[QT2][GCAP];               // 5.1 KiB
  __shared__ unsigned long long rrLds[NSLICE][QT2][6];  // 12.3 KiB (pad 6)

  const int l = threadIdx.x & 31;   // query lane
  const int s = threadIdx.x >> 5;   // slice: partitions 2s, 2s+1
  const int q = blockIdx.x * QT2 + l;

  // ---- phase 1: per-slice top-8 over collected keys (chunked loads) ----
  unsigned bd[8];
#pragma unroll
  for (int k = 0; k < 8; ++k) bd[k] = 0xFFFFFFFFu;
#pragma unroll
  for (int pp = 0; pp < 2; ++pp) {
    const int p = s * 2 + pp;
    const unsigned c = cnt_ws[p * M_TOTAL + q];
    const unsigned* base = list + (size_t)(p * CAP) * M_TOTAL + q;
    for (unsigned sl0 = 0; sl0 < c; sl0 += 8) {
      unsigned kk[8];
#pragma unroll
      for (int j = 0; j < 8; ++j) {
        unsigned slj = sl0 + j;
        kk[j] = base[(size_t)(slj < c ? slj : 0) * M_TOTAL];  // 8 loads in flight
      }
#pragma unroll
      for (int j = 0; j < 8; ++j) {
        unsigned cd = (sl0 + j < c) ? kk[j] : 0xFFFFFFFFu;
#pragma unroll
        for (int k = 0; k < 8; ++k) {
          unsigned lo = cd < bd[k] ? cd : bd[k];
          cd = cd < bd[k] ? bd[k] : cd;
          bd[k] = lo;
        }
      }
    }
  }
#pragma unroll
  for (int k = 0; k < 8; ++k) topLds[s][l][k] = bd[k];
  __syncthreads();

  // ---- phase 2: 8-way merge -> 20th of kept -> guard T ----
  if (threadIdx.x < QT2) {
    int i0 = 0, i1 = 0, i2 = 0, i3 = 0, i4 = 0, i5 = 0, i6 = 0, i7 = 0;
    unsigned m = 0;
    for (int k = 0; k < KNN; ++k) {
      unsigned v0 = (i0 < 8) ? topLds[0][l][i0] : 0xFFFFFFFFu;
      unsigned v1 = (i1 < 8) ? topLds[1][l][i1] : 0xFFFFFFFFu;
      unsigned v2 = (i2 < 8) ? topLds[2][l][i2] : 0xFFFFFFFFu;
      unsigned v3 = (i3 < 8) ? topLds[3][l][i3] : 0xFFFFFFFFu;
      unsigned v4 = (i4 < 8) ? topLds[4][l][i4] : 0xFFFFFFFFu;
      unsigned v5 = (i5 < 8) ? topLds[5][l][i5] : 0xFFFFFFFFu;
      unsigned v6 = (i6 < 8) ? topLds[6][l][i6] : 0xFFFFFFFFu;
      unsigned v7 = (i7 < 8) ? topLds[7][l][i7] : 0xFFFFFFFFu;
      unsigned a01 = v0 < v1 ? v0 : v1;
      unsigned a23 = v2 < v3 ? v2 : v3;
      unsigned a45 = v4 < v5 ? v4 : v5;
      unsigned a67 = v6 < v7 ? v6 : v7;
      unsigned a03 = a01 < a23 ? a01 : a23;
      unsigned a47 = a45 < a67 ? a45 : a67;
      m = a03 < a47 ? a03 : a47;
      if (m == v0) i0++;
      else if (m == v1) i1++;
      else if (m == v2) i2++;
      else if (m == v3) i3++;
      else if (m == v4) i4++;
      else if (m == v5) i5++;
      else if (m == v6) i6++;
      else i7++;
    }
    TLds[l] = (m >> 13) + 3;
    ccnt[l] = 0;
  }
  __syncthreads();

  // ---- phase 3: rescan, collect guard set (chunked loads) ----
  const unsigned T = TLds[l];
#pragma unroll
  for (int pp = 0; pp < 2; ++pp) {
    const int p = s * 2 + pp;
    const unsigned c = cnt_ws[p * M_TOTAL + q];
    const unsigned* base = list + (size_t)(p * CAP) * M_TOTAL + q;
    for (unsigned sl0 = 0; sl0 < c; sl0 += 8) {
      unsigned kk[8];
#pragma unroll
      for (int j = 0; j < 8; ++j) {
        unsigned slj = sl0 + j;
        kk[j] = base[(size_t)(slj < c ? slj : 0) * M_TOTAL];
      }
#pragma unroll
      for (int j = 0; j < 8; ++j) {
        if (sl0 + j < c && (kk[j] >> 13) <= T) {
          unsigned pos_ = atomicAdd(&ccnt[l], 1u);
          if (pos_ < GCAP) candLds[l][pos_] = kk[j] & 0x1FFFu;
        }
      }
    }
  }
  __syncthreads();

  // ---- phase 4: exact fp32 d2 re-rank of the guard set ----
  const int cc = min(ccnt[l], (unsigned)GCAP);
  const float sqq = sq[q];
  const float4* qp4 = reinterpret_cast<const float4*>(pos + (size_t)q * 64);
  unsigned long long kb[5];
#pragma unroll
  for (int j = 0; j < 5; ++j) kb[j] = ~0ull;
  for (int j = s; j < cc; j += NSLICE) {
    const unsigned idx = candLds[l][j];
    const float4* cp4 = reinterpret_cast<const float4*>(pos + (size_t)idx * 64);
    float d0 = 0.f, d1 = 0.f, d2 = 0.f, d3 = 0.f;
#pragma unroll
    for (int t = 0; t < 16; ++t) {
      float4 cv = cp4[t];
      float4 qv = qp4[t];  // L1/L2-hot
      d0 = fmaf(cv.x, qv.x, d0);
      d1 = fmaf(cv.y, qv.y, d1);
      d2 = fmaf(cv.z, qv.z, d2);
      d3 = fmaf(cv.w, qv.w, d3);
    }
    float dot = (d0 + d1) + (d2 + d3);
    float dd = fmaxf(fmaf(-2.f, dot, sqq + sq[idx]), 0.f);
    unsigned long long cd = ((unsigned long long)__float_as_uint(dd) << 32) | idx;
#pragma unroll
    for (int k = 0; k < 5; ++k) {  // sorted-5 insert (tie -> smaller idx)
      unsigned long long lo = cd < kb[k] ? cd : kb[k];
      cd = cd < kb[k] ? kb[k] : cd;
      kb[k] = lo;
    }
  }
#pragma unroll
  for (int j = 0; j < 5; ++j) rrLds[s][l][j] = kb[j];
  __syncthreads();

  if (threadIdx.x < QT2) {
    int i0 = 0, i1 = 0, i2 = 0, i3 = 0, i4 = 0, i5 = 0, i6 = 0, i7 = 0;
    for (int k = 0; k < KNN; ++k) {
      unsigned long long v0 = (i0 < 5) ? rrLds[0][l][i0] : ~0ull;
      unsigned long long v1 = (i1 < 5) ? rrLds[1][l][i1] : ~0ull;
      unsigned long long v2 = (i2 < 5) ? rrLds[2][l][i2] : ~0ull;
      unsigned long long v3 = (i3 < 5) ? rrLds[3][l][i3] : ~0ull;
      unsigned long long v4 = (i4 < 5) ? rrLds[4][l][i4] : ~0ull;
      unsigned long long v5 = (i5 < 5) ? rrLds[5][l][i5] : ~0ull;
      unsigned long long v6 = (i6 < 5) ? rrLds[6][l][i6] : ~0ull;
      unsigned long long v7 = (i7 < 5) ? rrLds[7][l][i7] : ~0ull;
      unsigned long long a01 = v0 < v1 ? v0 : v1;
      unsigned long long a23 = v2 < v3 ? v2 : v3;
      unsigned long long a45 = v4 < v5 ? v4 : v5;
      unsigned long long a67 = v6 < v7 ? v6 : v7;
      unsigned long long a03 = a01 < a23 ? a01 : a23;
      unsigned long long a47 = a45 < a67 ? a45 : a67;
      unsigned long long m = a03 < a47 ? a03 : a47;
      if (m == v0) i0++;
      else if (m == v1) i1++;
      else if (m == v2) i2++;
      else if (m == v3) i3++;
      else if (m == v4) i4++;
      else if (m == v5) i5++;
      else if (m == v6) i6++;
      else i7++;
      nbr[q * KNN + k] = (int)(unsigned)(m & 0xFFFFFFFFu);
    }
  }
}

// ---------------------------------------------------------------------------
// K2b: MLP + max-aggregation via MFMA. One wave per query. (unchanged)
// ---------------------------------------------------------------------------
__global__ __launch_bounds__(256) void k2b_mlp(
    const float* __restrict__ a_in, const float* __restrict__ g_in,
    const unsigned short* __restrict__ w2sw, const float* __restrict__ b2,
    const int* __restrict__ nbr, float* __restrict__ out) {
  const int lane = threadIdx.x & 63;
  const int wv = threadIdx.x >> 6;
  const int q = blockIdx.x * 4 + wv;
  const int col = lane & 15;
  const int quad = lane >> 4;

  const int n0 = nbr[q * KNN + col];
  const int n1 = nbr[q * KNN + ((16 + col) % KNN)];

  bf16x8 Bf[8];
#pragma unroll
  for (int f = 0; f < 8; ++f)
    Bf[f] = *(const bf16x8*)(w2sw + ((size_t)f * 64 + lane) * 8);

  const f32x4 zf = {0.f, 0.f, 0.f, 0.f};
  f32x4 acc0[4] = {zf, zf, zf, zf};
  f32x4 acc1[4] = {zf, zf, zf, zf};

#pragma unroll
  for (int seg = 0; seg < 2; ++seg) {
    const int dOff = seg * 32 + quad * 8;
    const float4* ap = reinterpret_cast<const float4*>(a_in + (size_t)q * 64 + dOff);
    const float4* g0p = reinterpret_cast<const float4*>(g_in + (size_t)n0 * 64 + dOff);
    const float4* g1p = reinterpret_cast<const float4*>(g_in + (size_t)n1 * 64 + dOff);
    float4 aa0 = ap[0], aa1 = ap[1];
    float4 gg0 = g0p[0], gg1 = g0p[1];
    float4 hh0 = g1p[0], hh1 = g1p[1];
    float av[8] = {aa0.x, aa0.y, aa0.z, aa0.w, aa1.x, aa1.y, aa1.z, aa1.w};
    float g0v[8] = {gg0.x, gg0.y, gg0.z, gg0.w, gg1.x, gg1.y, gg1.z, gg1.w};
    float g1v[8] = {hh0.x, hh0.y, hh0.z, hh0.w, hh1.x, hh1.y, hh1.z, hh1.w};
    bf16x8 A0, A1;
#pragma unroll
    for (int j = 0; j < 8; ++j) {
      A0[j] = (short)bf16rne(fmaxf(av[j] + g0v[j], 0.f));
      A1[j] = (short)bf16rne(fmaxf(av[j] + g1v[j], 0.f));
    }
#pragma unroll
    for (int t = 0; t < 4; ++t) {
      acc0[t] = __builtin_amdgcn_mfma_f32_16x16x32_bf16(A0, Bf[seg * 4 + t], acc0[t], 0, 0, 0);
      acc1[t] = __builtin_amdgcn_mfma_f32_16x16x32_bf16(A1, Bf[seg * 4 + t], acc1[t], 0, 0, 0);
    }
  }

  float res = 0.f;
#pragma unroll
  for (int t = 0; t < 4; ++t) {
    float m = fmaxf(fmaxf(fmaxf(acc0[t][0], acc1[t][0]), fmaxf(acc0[t][1], acc1[t][1])),
                    fmaxf(fmaxf(acc0[t][2], acc1[t][2]), fmaxf(acc0[t][3], acc1[t][3])));
    m = fmaxf(m, __shfl_xor(m, 16, 64));
    m = fmaxf(m, __shfl_xor(m, 32, 64));
    res = (quad == t) ? m : res;
  }
  out[(size_t)q * 64 + lane] = res + b2[lane];
}

// ---------------------------------------------------------------------------
extern "C" void kernel_launch(void* const* d_in, const int* in_sizes, int n_in,
                              void* d_out, int out_size, void* d_ws, size_t ws_size,
                              hipStream_t stream) {
  const float* pos = (const float*)d_in[0];
  const float* feat = (const float*)d_in[1];
  const float* W1 = (const float*)d_in[2];
  const float* b1 = (const float*)d_in[3];
  const float* W2 = (const float*)d_in[4];
  const float* b2 = (const float*)d_in[5];
  float* out = (float*)d_out;

  // ws layout (bytes), total ~23.3 MiB:
  //   sq    @ 0         32 KiB
  //   a     @ 32768     2 MiB
  //   g     @ 2129920   2 MiB
  //   poshi @ 4227072   1 MiB
  //   w2sw  @ 6324224   8 KiB
  //   list  @ 6332416   16 MiB  (512 slots x 8192 queries, transposed u32 keys)
  //   cnt   @ 23109632  512 KiB (16 x 8192, transposed)
  //   tau   @ 23633920  32 KiB
  //   nbr   @ 23666688  640 KiB (8192 * 20 * 4)
  char* ws = (char*)d_ws;
  float* sq = (float*)ws;
  float* a = (float*)(ws + 32768);
  float* g = (float*)(ws + 2129920);
  unsigned short* poshi = (unsigned short*)(ws + 4227072);
  unsigned short* w2sw = (unsigned short*)(ws + 6324224);
  unsigned* list = (unsigned*)(ws + 6332416);
  unsigned* cnt_ws = (unsigned*)(ws + 23109632);
  float* tau_g = (float*)(ws + 23633920);
  int* nbr = (int*)(ws + 23666688);

  k0_pre<<<M_TOTAL / 4, 256, 0, stream>>>(pos, feat, W1, b1, W2, sq, a, g, poshi, w2sw);
  k1a_tau<<<M_TOTAL / QT1A, 256, 0, stream>>>(poshi, sq, tau_g);
  k1b_collect<<<dim3(M_TOTAL / QT, PPART), 256, 0, stream>>>(poshi, sq, tau_g, list, cnt_ws);
  k2a_select<<<M_TOTAL / QT2, 256, 0, stream>>>(pos, sq, list, cnt_ws, nbr);
  k2b_mlp<<<M_TOTAL / 4, 256, 0, stream>>>(a, g, w2sw, b2, nbr, out);
}

// Round 12
// 190.966 us; speedup vs baseline: 1.8970x; 1.0037x over previous
//
#include <hip/hip_runtime.h>
#include <cfloat>
#include <cstdint>

// Problem constants (B=4, N=2048, C=64, O=64, K=20)
#define M_TOTAL 8192
#define KNN 20
#define PPART 16                 // candidate partitions
#define CPB (M_TOTAL / PPART)    // 512 candidates per K1b block
#define QT 64                    // queries per K1b block
#define QT1A 32                  // queries per K1a block
#define SAMPLE 1024              // tau sample = candidates [0, 1024)
#define CAP 32                   // collect capacity per (query,partition)
#define SLOTS (PPART * CAP)      // 512
#define QT2 32                   // queries per K2a block
#define NSLICE 8                 // slices per K2a block (2 partitions each)
#define GCAP 40                  // guard-collect cap in k2a

typedef __attribute__((ext_vector_type(8))) short bf16x8;  // 8 bf16 (4 VGPRs)
typedef __attribute__((ext_vector_type(4))) float f32x4;

__device__ __forceinline__ unsigned short bf16rne(float x) {
  unsigned u = __float_as_uint(x);
  return (unsigned short)((u + 0x7FFFu + ((u >> 16) & 1u)) >> 16);
}

// ---------------------------------------------------------------------------
// K0: per-point precompute. sq, bf16 pos (hi only -- k1 distances are hi*hi;
// error ~0.2 val-units vs ~10.6-unit selection margin, and k2a re-ranks in
// exact fp32), factored layer-1 (a, g). Blocks 0-1 additionally emit the
// W2 bf16 B-fragment swizzle (fused former k0b).
// ---------------------------------------------------------------------------
__global__ __launch_bounds__(256) void k0_pre(
    const float* __restrict__ pos, const float* __restrict__ feat,
    const float* __restrict__ W1, const float* __restrict__ b1,
    const float* __restrict__ W2,
    float* __restrict__ sq, float* __restrict__ a_out, float* __restrict__ g_out,
    unsigned short* __restrict__ poshi, unsigned short* __restrict__ w2sw) {
  __shared__ float fLds[4][64];
  const int lane = threadIdx.x & 63;
  const int rl = threadIdx.x >> 6;
  const int r = blockIdx.x * 4 + rl;

  float p = pos[r * 64 + lane];
  float f = feat[r * 64 + lane];
  fLds[rl][lane] = f;  // wave-private row; wave lockstep

  poshi[r * 64 + lane] = bf16rne(p);

  float s = p * p;
#pragma unroll
  for (int off = 1; off < 64; off <<= 1) s += __shfl_xor(s, off, 64);
  if (lane == 0) sq[r] = s;

  float acc_a = b1[lane];
  float acc_g = 0.f;
  const float4* f4 = reinterpret_cast<const float4*>(fLds[rl]);
#pragma unroll
  for (int i = 0; i < 16; ++i) {
    float4 fv = f4[i];
    float fd[4] = {fv.x, fv.y, fv.z, fv.w};
#pragma unroll
    for (int j = 0; j < 4; ++j) {
      int d = 4 * i + j;
      float wt = W1[d * 64 + lane];
      float wb = W1[(64 + d) * 64 + lane];
      acc_a = fmaf(fd[j], wt - wb, acc_a);
      acc_g = fmaf(fd[j], wb, acc_g);
    }
  }
  a_out[r * 64 + lane] = acc_a;
  g_out[r * 64 + lane] = acc_g;

  // fused k0b: W2 -> bf16 B-fragment swizzle (frag f = seg*4 + t)
  if (blockIdx.x < 2) {
    const int u = blockIdx.x * 256 + threadIdx.x;  // [0, 512)
    const int fr = u >> 6, ul = u & 63;
    const int seg = fr >> 2, t = fr & 3;
    const int uq = ul >> 4, uc = ul & 15;
#pragma unroll
    for (int j = 0; j < 8; ++j) {
      int d = seg * 32 + uq * 8 + j;
      w2sw[u * 8 + j] = bf16rne(W2[d * 64 + t * 16 + uc]);
    }
  }
}

// ---------------------------------------------------------------------------
// K1a: tau_q >= sample-20th d-hat (overestimate widens superset: safe).
// 256 blocks; top-8 per 128-cand stream; tau = 20th of 64 kept, +0.5 margin
// for hi-only d-hat error.
// A[m=lane&15][k=quad*8+j]; D: col=lane&15, row=quad*4+reg (m89-verified).
// ---------------------------------------------------------------------------
__global__ __launch_bounds__(256) void k1a_tau(
    const unsigned short* __restrict__ poshi,
    const float* __restrict__ sq, float* __restrict__ tau_g) {
  __shared__ float vw[4][16][36];        // wave-private transpose, 9 KiB
  __shared__ float sqcLds[SAMPLE];       // 4 KiB
  __shared__ float topLds[8][8][33];     // [stream][k][q], 8.25 KiB
  const int lane = threadIdx.x & 63;
  const int w = threadIdx.x >> 6;
  const int qbase = blockIdx.x * QT1A;
  const int col = lane & 15;
  const int quad = lane >> 4;
  const int dimOff = quad * 8;
  const int qq = lane & 31;     // query owned in cascade phase
  const int h = lane >> 5;      // candidate half owned

  for (int i = threadIdx.x; i < SAMPLE; i += 256) sqcLds[i] = sq[i];

  bf16x8 Ahi[2][2];
#pragma unroll
  for (int s = 0; s < 2; ++s) {
    int row = qbase + s * 16 + col;
    Ahi[s][0] = *(const bf16x8*)(poshi + (size_t)row * 64 + dimOff);
    Ahi[s][1] = *(const bf16x8*)(poshi + (size_t)row * 64 + dimOff + 32);
  }
  __syncthreads();  // sqcLds ready

  const f32x4 zf = {0.f, 0.f, 0.f, 0.f};
  float bd[8];
#pragma unroll
  for (int k = 0; k < 8; ++k) bd[k] = FLT_MAX;

  bf16x8 Bh0 = *(const bf16x8*)(poshi + (size_t)(w * 16 + col) * 64 + dimOff);
  bf16x8 Bh1 = *(const bf16x8*)(poshi + (size_t)(w * 16 + col) * 64 + dimOff + 32);
  for (int c0 = 0; c0 < SAMPLE; c0 += 64) {
    const int nc0 = (c0 + 64 < SAMPLE) ? c0 + 64 : c0;
    bf16x8 Nh0 = *(const bf16x8*)(poshi + (size_t)(nc0 + w * 16 + col) * 64 + dimOff);
    bf16x8 Nh1 = *(const bf16x8*)(poshi + (size_t)(nc0 + w * 16 + col) * 64 + dimOff + 32);

    f32x4 acc[2] = {zf, zf};
#pragma unroll
    for (int s = 0; s < 2; ++s) {
      acc[s] = __builtin_amdgcn_mfma_f32_16x16x32_bf16(Ahi[s][0], Bh0, acc[s], 0, 0, 0);
      acc[s] = __builtin_amdgcn_mfma_f32_16x16x32_bf16(Ahi[s][1], Bh1, acc[s], 0, 0, 0);
    }
    const float sqcv = sqcLds[c0 + w * 16 + col] + 256.0f;
#pragma unroll
    for (int s = 0; s < 2; ++s) {
      float4 v4;
      v4.x = fmaf(-2.f, acc[s][0], sqcv);
      v4.y = fmaf(-2.f, acc[s][1], sqcv);
      v4.z = fmaf(-2.f, acc[s][2], sqcv);
      v4.w = fmaf(-2.f, acc[s][3], sqcv);
      *reinterpret_cast<float4*>(&vw[w][col][s * 16 + quad * 4]) = v4;
    }
    __builtin_amdgcn_wave_barrier();  // wave-private region, lockstep
#pragma unroll
    for (int i = 0; i < 8; ++i) {
      float cd = vw[w][h * 8 + i][qq];
#pragma unroll
      for (int k = 0; k < 8; ++k) {  // branch-free sorted insert (top-8)
        float lo = fminf(cd, bd[k]);
        cd = fmaxf(cd, bd[k]);
        bd[k] = lo;
      }
    }
    __builtin_amdgcn_wave_barrier();
    Bh0 = Nh0; Bh1 = Nh1;
  }

#pragma unroll
  for (int k = 0; k < 8; ++k) topLds[w * 2 + h][k][qq] = bd[k];
  __syncthreads();

  if (threadIdx.x < QT1A) {
    const int l = threadIdx.x;
    int ix[8] = {0, 0, 0, 0, 0, 0, 0, 0};
    float tau = FLT_MAX;
    for (int k = 0; k < KNN; ++k) {
      float best = FLT_MAX;
      int bs = 0;
#pragma unroll
      for (int st = 0; st < 8; ++st) {
        float v = (ix[st] < 8) ? topLds[st][ix[st]][l] : FLT_MAX;
        if (v < best) { best = v; bs = st; }
      }
      ix[bs]++;
      tau = best;
    }
    tau_g[qbase + l] = tau + 0.5f;  // margin covers hi-only d-hat error
  }
}

// ---------------------------------------------------------------------------
// K1b v7: hi-only distances; ALL 8 stripes' B preloaded into registers and
// PINNED with an empty asm use ("+v") -- rematerialization of the loads is
// then illegal (the asm may have modified the values), so the stripe loop
// is provably load-free. Round-10/11 VGPR_Count=76 proved the bare preload
// was being rematerialized back into the loop; the testable signature of
// this fix is VGPR_Count >= ~130.
// Collect val <= tau_q as packed u32 key (19-bit val-bits | 13-bit idx),
// transposed layout for K2a coalescing.
// ---------------------------------------------------------------------------
__global__ __launch_bounds__(256, 1) void k1b_collect(
    const unsigned short* __restrict__ poshi,
    const float* __restrict__ sq, const float* __restrict__ tau_g,
    unsigned* __restrict__ list, unsigned* __restrict__ cnt_ws) {
  __shared__ float sqcLds[CPB];
  __shared__ float tauLds[QT];
  __shared__ unsigned cntLds[QT];

  const int lane = threadIdx.x & 63;
  const int w = threadIdx.x >> 6;
  const int qbase = blockIdx.x * QT;
  const int cbase = blockIdx.y * CPB;
  const int col = lane & 15;
  const int quad = lane >> 4;
  const int dimOff = quad * 8;

  // B preload first: 16 loads in flight while the rest of setup runs
  bf16x8 B[8][2];
#pragma unroll
  for (int st = 0; st < 8; ++st) {
    const size_t row = (size_t)(cbase + st * 64 + w * 16 + col) * 64;
    B[st][0] = *(const bf16x8*)(poshi + row + dimOff);
    B[st][1] = *(const bf16x8*)(poshi + row + dimOff + 32);
  }

  for (int i = threadIdx.x; i < CPB; i += 256) sqcLds[i] = sq[cbase + i];
  if (threadIdx.x < QT) {
    tauLds[threadIdx.x] = tau_g[qbase + threadIdx.x];
    cntLds[threadIdx.x] = 0;
  }

  bf16x8 Ahi[4][2];
#pragma unroll
  for (int s = 0; s < 4; ++s) {
    int row = qbase + s * 16 + col;
    Ahi[s][0] = *(const bf16x8*)(poshi + (size_t)row * 64 + dimOff);
    Ahi[s][1] = *(const bf16x8*)(poshi + (size_t)row * 64 + dimOff + 32);
  }
  __syncthreads();

  // PIN: forbid rematerialization of the B preload into the loop.
#pragma unroll
  for (int st = 0; st < 8; ++st) {
    asm volatile("" : "+v"(B[st][0]), "+v"(B[st][1]));
  }

  float tau_l[4][4];
#pragma unroll
  for (int s = 0; s < 4; ++s)
#pragma unroll
    for (int r = 0; r < 4; ++r) tau_l[s][r] = tauLds[s * 16 + quad * 4 + r];

  const f32x4 zf = {0.f, 0.f, 0.f, 0.f};
#pragma unroll
  for (int st = 0; st < 8; ++st) {
    f32x4 acc[4] = {zf, zf, zf, zf};
#pragma unroll
    for (int s = 0; s < 4; ++s) {
      acc[s] = __builtin_amdgcn_mfma_f32_16x16x32_bf16(Ahi[s][0], B[st][0], acc[s], 0, 0, 0);
      acc[s] = __builtin_amdgcn_mfma_f32_16x16x32_bf16(Ahi[s][1], B[st][1], acc[s], 0, 0, 0);
    }
    const int candRow = cbase + st * 64 + w * 16 + col;
    const float sqcv = sqcLds[st * 64 + w * 16 + col] + 256.0f;
#pragma unroll
    for (int s = 0; s < 4; ++s) {
#pragma unroll
      for (int r = 0; r < 4; ++r) {
        float val = fmaf(-2.f, acc[s][r], sqcv);
        const int qrow = s * 16 + quad * 4 + r;
        if (val <= tau_l[s][r]) {  // ~2% of lanes
          unsigned slot = atomicAdd(&cntLds[qrow], 1u);
          if (slot < CAP)
            list[(size_t)(blockIdx.y * CAP + slot) * M_TOTAL + qbase + qrow] =
                (__float_as_uint(val) & 0xFFFFE000u) | (unsigned)candRow;
        }
      }
    }
  }
  __syncthreads();
  if (threadIdx.x < QT) {
    unsigned c = cntLds[threadIdx.x];
    cnt_ws[blockIdx.y * M_TOTAL + qbase + threadIdx.x] = c > CAP ? CAP : c;
  }
}

// ---------------------------------------------------------------------------
// K2a: 32 queries x 8 slices; chunk-8 batched key loads; guard +3 quanta
// (0.75 val) covers hi-only d-hat error in the quantized keys.
// ---------------------------------------------------------------------------
__global__ __launch_bounds__(256) void k2a_select(
    const float* __restrict__ pos, const float* __restrict__ sq,
    const unsigned* __restrict__ list, const unsigned* __restrict__ cnt_ws,
    int* __restrict__ nbr) {
  __shared__ unsigned topLds[NSLICE][QT2][9];           // 9.2 KiB (pad 9)
  __shared__ unsigned TLds[QT2];
  __shared__ unsigned ccnt[QT2];
  __shared__ unsigned candLds[QT2][GCAP];               // 5.1 KiB
  __shared__ unsigned long long rrLds[NSLICE][QT2][6];  // 12.3 KiB (pad 6)

  const int l = threadIdx.x & 31;   // query lane
  const int s = threadIdx.x >> 5;   // slice: partitions 2s, 2s+1
  const int q = blockIdx.x * QT2 + l;

  // ---- phase 1: per-slice top-8 over collected keys (chunked loads) ----
  unsigned bd[8];
#pragma unroll
  for (int k = 0; k < 8; ++k) bd[k] = 0xFFFFFFFFu;
#pragma unroll
  for (int pp = 0; pp < 2; ++pp) {
    const int p = s * 2 + pp;
    const unsigned c = cnt_ws[p * M_TOTAL + q];
    const unsigned* base = list + (size_t)(p * CAP) * M_TOTAL + q;
    for (unsigned sl0 = 0; sl0 < c; sl0 += 8) {
      unsigned kk[8];
#pragma unroll
      for (int j = 0; j < 8; ++j) {
        unsigned slj = sl0 + j;
        kk[j] = base[(size_t)(slj < c ? slj : 0) * M_TOTAL];  // 8 loads in flight
      }
#pragma unroll
      for (int j = 0; j < 8; ++j) {
        unsigned cd = (sl0 + j < c) ? kk[j] : 0xFFFFFFFFu;
#pragma unroll
        for (int k = 0; k < 8; ++k) {
          unsigned lo = cd < bd[k] ? cd : bd[k];
          cd = cd < bd[k] ? bd[k] : cd;
          bd[k] = lo;
        }
      }
    }
  }
#pragma unroll
  for (int k = 0; k < 8; ++k) topLds[s][l][k] = bd[k];
  __syncthreads();

  // ---- phase 2: 8-way merge -> 20th of kept -> guard T ----
  if (threadIdx.x < QT2) {
    int i0 = 0, i1 = 0, i2 = 0, i3 = 0, i4 = 0, i5 = 0, i6 = 0, i7 = 0;
    unsigned m = 0;
    for (int k = 0; k < KNN; ++k) {
      unsigned v0 = (i0 < 8) ? topLds[0][l][i0] : 0xFFFFFFFFu;
      unsigned v1 = (i1 < 8) ? topLds[1][l][i1] : 0xFFFFFFFFu;
      unsigned v2 = (i2 < 8) ? topLds[2][l][i2] : 0xFFFFFFFFu;
      unsigned v3 = (i3 < 8) ? topLds[3][l][i3] : 0xFFFFFFFFu;
      unsigned v4 = (i4 < 8) ? topLds[4][l][i4] : 0xFFFFFFFFu;
      unsigned v5 = (i5 < 8) ? topLds[5][l][i5] : 0xFFFFFFFFu;
      unsigned v6 = (i6 < 8) ? topLds[6][l][i6] : 0xFFFFFFFFu;
      unsigned v7 = (i7 < 8) ? topLds[7][l][i7] : 0xFFFFFFFFu;
      unsigned a01 = v0 < v1 ? v0 : v1;
      unsigned a23 = v2 < v3 ? v2 : v3;
      unsigned a45 = v4 < v5 ? v4 : v5;
      unsigned a67 = v6 < v7 ? v6 : v7;
      unsigned a03 = a01 < a23 ? a01 : a23;
      unsigned a47 = a45 < a67 ? a45 : a67;
      m = a03 < a47 ? a03 : a47;
      if (m == v0) i0++;
      else if (m == v1) i1++;
      else if (m == v2) i2++;
      else if (m == v3) i3++;
      else if (m == v4) i4++;
      else if (m == v5) i5++;
      else if (m == v6) i6++;
      else i7++;
    }
    TLds[l] = (m >> 13) + 3;
    ccnt[l] = 0;
  }
  __syncthreads();

  // ---- phase 3: rescan, collect guard set (chunked loads) ----
  const unsigned T = TLds[l];
#pragma unroll
  for (int pp = 0; pp < 2; ++pp) {
    const int p = s * 2 + pp;
    const unsigned c = cnt_ws[p * M_TOTAL + q];
    const unsigned* base = list + (size_t)(p * CAP) * M_TOTAL + q;
    for (unsigned sl0 = 0; sl0 < c; sl0 += 8) {
      unsigned kk[8];
#pragma unroll
      for (int j = 0; j < 8; ++j) {
        unsigned slj = sl0 + j;
        kk[j] = base[(size_t)(slj < c ? slj : 0) * M_TOTAL];
      }
#pragma unroll
      for (int j = 0; j < 8; ++j) {
        if (sl0 + j < c && (kk[j] >> 13) <= T) {
          unsigned pos_ = atomicAdd(&ccnt[l], 1u);
          if (pos_ < GCAP) candLds[l][pos_] = kk[j] & 0x1FFFu;
        }
      }
    }
  }
  __syncthreads();

  // ---- phase 4: exact fp32 d2 re-rank of the guard set ----
  const int cc = min(ccnt[l], (unsigned)GCAP);
  const float sqq = sq[q];
  const float4* qp4 = reinterpret_cast<const float4*>(pos + (size_t)q * 64);
  unsigned long long kb[5];
#pragma unroll
  for (int j = 0; j < 5; ++j) kb[j] = ~0ull;
  for (int j = s; j < cc; j += NSLICE) {
    const unsigned idx = candLds[l][j];
    const float4* cp4 = reinterpret_cast<const float4*>(pos + (size_t)idx * 64);
    float d0 = 0.f, d1 = 0.f, d2 = 0.f, d3 = 0.f;
#pragma unroll
    for (int t = 0; t < 16; ++t) {
      float4 cv = cp4[t];
      float4 qv = qp4[t];  // L1/L2-hot
      d0 = fmaf(cv.x, qv.x, d0);
      d1 = fmaf(cv.y, qv.y, d1);
      d2 = fmaf(cv.z, qv.z, d2);
      d3 = fmaf(cv.w, qv.w, d3);
    }
    float dot = (d0 + d1) + (d2 + d3);
    float dd = fmaxf(fmaf(-2.f, dot, sqq + sq[idx]), 0.f);
    unsigned long long cd = ((unsigned long long)__float_as_uint(dd) << 32) | idx;
#pragma unroll
    for (int k = 0; k < 5; ++k) {  // sorted-5 insert (tie -> smaller idx)
      unsigned long long lo = cd < kb[k] ? cd : kb[k];
      cd = cd < kb[k] ? kb[k] : cd;
      kb[k] = lo;
    }
  }
#pragma unroll
  for (int j = 0; j < 5; ++j) rrLds[s][l][j] = kb[j];
  __syncthreads();

  if (threadIdx.x < QT2) {
    int i0 = 0, i1 = 0, i2 = 0, i3 = 0, i4 = 0, i5 = 0, i6 = 0, i7 = 0;
    for (int k = 0; k < KNN; ++k) {
      unsigned long long v0 = (i0 < 5) ? rrLds[0][l][i0] : ~0ull;
      unsigned long long v1 = (i1 < 5) ? rrLds[1][l][i1] : ~0ull;
      unsigned long long v2 = (i2 < 5) ? rrLds[2][l][i2] : ~0ull;
      unsigned long long v3 = (i3 < 5) ? rrLds[3][l][i3] : ~0ull;
      unsigned long long v4 = (i4 < 5) ? rrLds[4][l][i4] : ~0ull;
      unsigned long long v5 = (i5 < 5) ? rrLds[5][l][i5] : ~0ull;
      unsigned long long v6 = (i6 < 5) ? rrLds[6][l][i6] : ~0ull;
      unsigned long long v7 = (i7 < 5) ? rrLds[7][l][i7] : ~0ull;
      unsigned long long a01 = v0 < v1 ? v0 : v1;
      unsigned long long a23 = v2 < v3 ? v2 : v3;
      unsigned long long a45 = v4 < v5 ? v4 : v5;
      unsigned long long a67 = v6 < v7 ? v6 : v7;
      unsigned long long a03 = a01 < a23 ? a01 : a23;
      unsigned long long a47 = a45 < a67 ? a45 : a67;
      unsigned long long m = a03 < a47 ? a03 : a47;
      if (m == v0) i0++;
      else if (m == v1) i1++;
      else if (m == v2) i2++;
      else if (m == v3) i3++;
      else if (m == v4) i4++;
      else if (m == v5) i5++;
      else if (m == v6) i6++;
      else i7++;
      nbr[q * KNN + k] = (int)(unsigned)(m & 0xFFFFFFFFu);
    }
  }
}

// ---------------------------------------------------------------------------
// K2b: MLP + max-aggregation via MFMA. One wave per query. (unchanged)
// ---------------------------------------------------------------------------
__global__ __launch_bounds__(256) void k2b_mlp(
    const float* __restrict__ a_in, const float* __restrict__ g_in,
    const unsigned short* __restrict__ w2sw, const float* __restrict__ b2,
    const int* __restrict__ nbr, float* __restrict__ out) {
  const int lane = threadIdx.x & 63;
  const int wv = threadIdx.x >> 6;
  const int q = blockIdx.x * 4 + wv;
  const int col = lane & 15;
  const int quad = lane >> 4;

  const int n0 = nbr[q * KNN + col];
  const int n1 = nbr[q * KNN + ((16 + col) % KNN)];

  bf16x8 Bf[8];
#pragma unroll
  for (int f = 0; f < 8; ++f)
    Bf[f] = *(const bf16x8*)(w2sw + ((size_t)f * 64 + lane) * 8);

  const f32x4 zf = {0.f, 0.f, 0.f, 0.f};
  f32x4 acc0[4] = {zf, zf, zf, zf};
  f32x4 acc1[4] = {zf, zf, zf, zf};

#pragma unroll
  for (int seg = 0; seg < 2; ++seg) {
    const int dOff = seg * 32 + quad * 8;
    const float4* ap = reinterpret_cast<const float4*>(a_in + (size_t)q * 64 + dOff);
    const float4* g0p = reinterpret_cast<const float4*>(g_in + (size_t)n0 * 64 + dOff);
    const float4* g1p = reinterpret_cast<const float4*>(g_in + (size_t)n1 * 64 + dOff);
    float4 aa0 = ap[0], aa1 = ap[1];
    float4 gg0 = g0p[0], gg1 = g0p[1];
    float4 hh0 = g1p[0], hh1 = g1p[1];
    float av[8] = {aa0.x, aa0.y, aa0.z, aa0.w, aa1.x, aa1.y, aa1.z, aa1.w};
    float g0v[8] = {gg0.x, gg0.y, gg0.z, gg0.w, gg1.x, gg1.y, gg1.z, gg1.w};
    float g1v[8] = {hh0.x, hh0.y, hh0.z, hh0.w, hh1.x, hh1.y, hh1.z, hh1.w};
    bf16x8 A0, A1;
#pragma unroll
    for (int j = 0; j < 8; ++j) {
      A0[j] = (short)bf16rne(fmaxf(av[j] + g0v[j], 0.f));
      A1[j] = (short)bf16rne(fmaxf(av[j] + g1v[j], 0.f));
    }
#pragma unroll
    for (int t = 0; t < 4; ++t) {
      acc0[t] = __builtin_amdgcn_mfma_f32_16x16x32_bf16(A0, Bf[seg * 4 + t], acc0[t], 0, 0, 0);
      acc1[t] = __builtin_amdgcn_mfma_f32_16x16x32_bf16(A1, Bf[seg * 4 + t], acc1[t], 0, 0, 0);
    }
  }

  float res = 0.f;
#pragma unroll
  for (int t = 0; t < 4; ++t) {
    float m = fmaxf(fmaxf(fmaxf(acc0[t][0], acc1[t][0]), fmaxf(acc0[t][1], acc1[t][1])),
                    fmaxf(fmaxf(acc0[t][2], acc1[t][2]), fmaxf(acc0[t][3], acc1[t][3])));
    m = fmaxf(m, __shfl_xor(m, 16, 64));
    m = fmaxf(m, __shfl_xor(m, 32, 64));
    res = (quad == t) ? m : res;
  }
  out[(size_t)q * 64 + lane] = res + b2[lane];
}

// ---------------------------------------------------------------------------
extern "C" void kernel_launch(void* const* d_in, const int* in_sizes, int n_in,
                              void* d_out, int out_size, void* d_ws, size_t ws_size,
                              hipStream_t stream) {
  const float* pos = (const float*)d_in[0];
  const float* feat = (const float*)d_in[1];
  const float* W1 = (const float*)d_in[2];
  const float* b1 = (const float*)d_in[3];
  const float* W2 = (const float*)d_in[4];
  const float* b2 = (const float*)d_in[5];
  float* out = (float*)d_out;

  // ws layout (bytes), total ~23.3 MiB:
  //   sq    @ 0         32 KiB
  //   a     @ 32768     2 MiB
  //   g     @ 2129920   2 MiB
  //   poshi @ 4227072   1 MiB
  //   w2sw  @ 6324224   8 KiB
  //   list  @ 6332416   16 MiB  (512 slots x 8192 queries, transposed u32 keys)
  //   cnt   @ 23109632  512 KiB (16 x 8192, transposed)
  //   tau   @ 23633920  32 KiB
  //   nbr   @ 23666688  640 KiB (8192 * 20 * 4)
  char* ws = (char*)d_ws;
  float* sq = (float*)ws;
  float* a = (float*)(ws + 32768);
  float* g = (float*)(ws + 2129920);
  unsigned short* poshi = (unsigned short*)(ws + 4227072);
  unsigned short* w2sw = (unsigned short*)(ws + 6324224);
  unsigned* list = (unsigned*)(ws + 6332416);
  unsigned* cnt_ws = (unsigned*)(ws + 23109632);
  float* tau_g = (float*)(ws + 23633920);
  int* nbr = (int*)(ws + 23666688);

  k0_pre<<<M_TOTAL / 4, 256, 0, stream>>>(pos, feat, W1, b1, W2, sq, a, g, poshi, w2sw);
  k1a_tau<<<M_TOTAL / QT1A, 256, 0, stream>>>(poshi, sq, tau_g);
  k1b_collect<<<dim3(M_TOTAL / QT, PPART), 256, 0, stream>>>(poshi, sq, tau_g, list, cnt_ws);
  k2a_select<<<M_TOTAL / QT2, 256, 0, stream>>>(pos, sq, list, cnt_ws, nbr);
  k2b_mlp<<<M_TOTAL / 4, 256, 0, stream>>>(a, g, w2sw, b2, nbr, out);
}

// Round 13
// 187.901 us; speedup vs baseline: 1.9280x; 1.0163x over previous
//
#include <hip/hip_runtime.h>
#include <cfloat>
#include <cstdint>

// Problem constants (B=4, N=2048, C=64, O=64, K=20)
#define M_TOTAL 8192
#define KNN 20
#define PPART 8                  // candidate partitions
#define CPB (M_TOTAL / PPART)    // 1024 candidates per K1b block
#define QT 128                   // queries per K1b block (big blocks: amortize setup)
#define QT1A 32                  // queries per K1a block
#define SAMPLE 1024              // tau sample = candidates [0, 1024)
#define CAP 64                   // collect capacity per (query,partition); E~22, 9 sigma
#define SLOTS (PPART * CAP)      // 512
#define QT2 32                   // queries per K2ab block
#define NSLICE 8                 // slices per K2ab block (1 partition each)
#define GCAP 40                  // guard-collect cap in k2ab

typedef __attribute__((ext_vector_type(8))) short bf16x8;  // 8 bf16 (4 VGPRs)
typedef __attribute__((ext_vector_type(4))) float f32x4;

__device__ __forceinline__ unsigned short bf16rne(float x) {
  unsigned u = __float_as_uint(x);
  return (unsigned short)((u + 0x7FFFu + ((u >> 16) & 1u)) >> 16);
}

// ---------------------------------------------------------------------------
// K0: per-point precompute. sq, bf16 pos (hi only; k2ab re-ranks exact fp32),
// factored layer-1 (a, g). Blocks 0-1 also emit the W2 B-frag swizzle.
// ---------------------------------------------------------------------------
__global__ __launch_bounds__(256) void k0_pre(
    const float* __restrict__ pos, const float* __restrict__ feat,
    const float* __restrict__ W1, const float* __restrict__ b1,
    const float* __restrict__ W2,
    float* __restrict__ sq, float* __restrict__ a_out, float* __restrict__ g_out,
    unsigned short* __restrict__ poshi, unsigned short* __restrict__ w2sw) {
  __shared__ float fLds[4][64];
  const int lane = threadIdx.x & 63;
  const int rl = threadIdx.x >> 6;
  const int r = blockIdx.x * 4 + rl;

  float p = pos[r * 64 + lane];
  float f = feat[r * 64 + lane];
  fLds[rl][lane] = f;  // wave-private row; wave lockstep

  poshi[r * 64 + lane] = bf16rne(p);

  float s = p * p;
#pragma unroll
  for (int off = 1; off < 64; off <<= 1) s += __shfl_xor(s, off, 64);
  if (lane == 0) sq[r] = s;

  float acc_a = b1[lane];
  float acc_g = 0.f;
  const float4* f4 = reinterpret_cast<const float4*>(fLds[rl]);
#pragma unroll
  for (int i = 0; i < 16; ++i) {
    float4 fv = f4[i];
    float fd[4] = {fv.x, fv.y, fv.z, fv.w};
#pragma unroll
    for (int j = 0; j < 4; ++j) {
      int d = 4 * i + j;
      float wt = W1[d * 64 + lane];
      float wb = W1[(64 + d) * 64 + lane];
      acc_a = fmaf(fd[j], wt - wb, acc_a);
      acc_g = fmaf(fd[j], wb, acc_g);
    }
  }
  a_out[r * 64 + lane] = acc_a;
  g_out[r * 64 + lane] = acc_g;

  if (blockIdx.x < 2) {  // fused W2 swizzle (frag f = seg*4 + t)
    const int u = blockIdx.x * 256 + threadIdx.x;  // [0, 512)
    const int fr = u >> 6, ul = u & 63;
    const int seg = fr >> 2, t = fr & 3;
    const int uq = ul >> 4, uc = ul & 15;
#pragma unroll
    for (int j = 0; j < 8; ++j) {
      int d = seg * 32 + uq * 8 + j;
      w2sw[u * 8 + j] = bf16rne(W2[d * 64 + t * 16 + uc]);
    }
  }
}

// ---------------------------------------------------------------------------
// K1a: tau_q >= sample-20th d-hat (overestimate widens superset: safe).
// 256 blocks; top-8 per 128-cand stream; tau = 20th of 64 kept, +0.5 margin
// for hi-only d-hat error. A[m=lane&15][k=quad*8+j]; D: col=lane&15,
// row=quad*4+reg (m89-verified).
// ---------------------------------------------------------------------------
__global__ __launch_bounds__(256) void k1a_tau(
    const unsigned short* __restrict__ poshi,
    const float* __restrict__ sq, float* __restrict__ tau_g) {
  __shared__ float vw[4][16][36];        // wave-private transpose, 9 KiB
  __shared__ float sqcLds[SAMPLE];       // 4 KiB
  __shared__ float topLds[8][8][33];     // [stream][k][q], 8.25 KiB
  const int lane = threadIdx.x & 63;
  const int w = threadIdx.x >> 6;
  const int qbase = blockIdx.x * QT1A;
  const int col = lane & 15;
  const int quad = lane >> 4;
  const int dimOff = quad * 8;
  const int qq = lane & 31;     // query owned in cascade phase
  const int h = lane >> 5;      // candidate half owned

  for (int i = threadIdx.x; i < SAMPLE; i += 256) sqcLds[i] = sq[i];

  bf16x8 Ahi[2][2];
#pragma unroll
  for (int s = 0; s < 2; ++s) {
    int row = qbase + s * 16 + col;
    Ahi[s][0] = *(const bf16x8*)(poshi + (size_t)row * 64 + dimOff);
    Ahi[s][1] = *(const bf16x8*)(poshi + (size_t)row * 64 + dimOff + 32);
  }
  __syncthreads();  // sqcLds ready

  const f32x4 zf = {0.f, 0.f, 0.f, 0.f};
  float bd[8];
#pragma unroll
  for (int k = 0; k < 8; ++k) bd[k] = FLT_MAX;

  bf16x8 Bh0 = *(const bf16x8*)(poshi + (size_t)(w * 16 + col) * 64 + dimOff);
  bf16x8 Bh1 = *(const bf16x8*)(poshi + (size_t)(w * 16 + col) * 64 + dimOff + 32);
  for (int c0 = 0; c0 < SAMPLE; c0 += 64) {
    const int nc0 = (c0 + 64 < SAMPLE) ? c0 + 64 : c0;
    bf16x8 Nh0 = *(const bf16x8*)(poshi + (size_t)(nc0 + w * 16 + col) * 64 + dimOff);
    bf16x8 Nh1 = *(const bf16x8*)(poshi + (size_t)(nc0 + w * 16 + col) * 64 + dimOff + 32);

    f32x4 acc[2] = {zf, zf};
#pragma unroll
    for (int s = 0; s < 2; ++s) {
      acc[s] = __builtin_amdgcn_mfma_f32_16x16x32_bf16(Ahi[s][0], Bh0, acc[s], 0, 0, 0);
      acc[s] = __builtin_amdgcn_mfma_f32_16x16x32_bf16(Ahi[s][1], Bh1, acc[s], 0, 0, 0);
    }
    const float sqcv = sqcLds[c0 + w * 16 + col] + 256.0f;
#pragma unroll
    for (int s = 0; s < 2; ++s) {
      float4 v4;
      v4.x = fmaf(-2.f, acc[s][0], sqcv);
      v4.y = fmaf(-2.f, acc[s][1], sqcv);
      v4.z = fmaf(-2.f, acc[s][2], sqcv);
      v4.w = fmaf(-2.f, acc[s][3], sqcv);
      *reinterpret_cast<float4*>(&vw[w][col][s * 16 + quad * 4]) = v4;
    }
    __builtin_amdgcn_wave_barrier();  // wave-private region, lockstep
#pragma unroll
    for (int i = 0; i < 8; ++i) {
      float cd = vw[w][h * 8 + i][qq];
#pragma unroll
      for (int k = 0; k < 8; ++k) {  // branch-free sorted insert (top-8)
        float lo = fminf(cd, bd[k]);
        cd = fmaxf(cd, bd[k]);
        bd[k] = lo;
      }
    }
    __builtin_amdgcn_wave_barrier();
    Bh0 = Nh0; Bh1 = Nh1;
  }

#pragma unroll
  for (int k = 0; k < 8; ++k) topLds[w * 2 + h][k][qq] = bd[k];
  __syncthreads();

  if (threadIdx.x < QT1A) {
    const int l = threadIdx.x;
    int ix[8] = {0, 0, 0, 0, 0, 0, 0, 0};
    float tau = FLT_MAX;
    for (int k = 0; k < KNN; ++k) {
      float best = FLT_MAX;
      int bs = 0;
#pragma unroll
      for (int st = 0; st < 8; ++st) {
        float v = (ix[st] < 8) ? topLds[st][ix[st]][l] : FLT_MAX;
        if (v < best) { best = v; bs = st; }
      }
      ix[bs]++;
      tau = best;
    }
    tau_g[qbase + l] = tau + 0.5f;  // margin covers hi-only d-hat error
  }
}

// ---------------------------------------------------------------------------
// K1b v8: BIG blocks. 128 queries x 1024 candidates per block -> 512 blocks
// (was 2048). Rationale (round-12 post-mortem): per-block work was ~2 us but
// blocks ran ~14 us latency-bound at ~2 blocks/CU -- short-block setup and
// per-stripe epilogue overhead dominated. 4x queries/block amortizes setup,
// reuses each B-tile across 8 A-groups (16 MFMAs/stripe), halves VALU/val.
// Collect val <= tau_q as packed u32 key (19-bit val-bits | 13-bit idx),
// transposed layout for K2ab coalescing.
// ---------------------------------------------------------------------------
__global__ __launch_bounds__(256, 1) void k1b_collect(
    const unsigned short* __restrict__ poshi,
    const float* __restrict__ sq, const float* __restrict__ tau_g,
    unsigned* __restrict__ list, unsigned* __restrict__ cnt_ws) {
  __shared__ float sqcLds[CPB];      // 4 KiB
  __shared__ float tauLds[QT];
  __shared__ unsigned cntLds[QT];

  const int lane = threadIdx.x & 63;
  const int w = threadIdx.x >> 6;
  const int qbase = blockIdx.x * QT;
  const int cbase = blockIdx.y * CPB;
  const int col = lane & 15;
  const int quad = lane >> 4;
  const int dimOff = quad * 8;

  for (int i = threadIdx.x; i < CPB; i += 256) sqcLds[i] = sq[cbase + i];
  if (threadIdx.x < QT) {
    tauLds[threadIdx.x] = tau_g[qbase + threadIdx.x];
    cntLds[threadIdx.x] = 0;
  }

  // A-fragments: 8 groups of 16 queries (loaded once, reused for 16 stripes)
  bf16x8 Ahi[8][2];
#pragma unroll
  for (int s = 0; s < 8; ++s) {
    int row = qbase + s * 16 + col;
    Ahi[s][0] = *(const bf16x8*)(poshi + (size_t)row * 64 + dimOff);
    Ahi[s][1] = *(const bf16x8*)(poshi + (size_t)row * 64 + dimOff + 32);
  }
  __syncthreads();

  float tau_l[8][4];
#pragma unroll
  for (int s = 0; s < 8; ++s)
#pragma unroll
    for (int r = 0; r < 4; ++r) tau_l[s][r] = tauLds[s * 16 + quad * 4 + r];

  const f32x4 zf = {0.f, 0.f, 0.f, 0.f};
  bf16x8 Bh0 = *(const bf16x8*)(poshi + (size_t)(cbase + w * 16 + col) * 64 + dimOff);
  bf16x8 Bh1 = *(const bf16x8*)(poshi + (size_t)(cbase + w * 16 + col) * 64 + dimOff + 32);
  for (int c0 = 0; c0 < CPB; c0 += 64) {
    const int nc0 = (c0 + 64 < CPB) ? c0 + 64 : c0;
    bf16x8 Nh0 = *(const bf16x8*)(poshi + (size_t)(cbase + nc0 + w * 16 + col) * 64 + dimOff);
    bf16x8 Nh1 = *(const bf16x8*)(poshi + (size_t)(cbase + nc0 + w * 16 + col) * 64 + dimOff + 32);

    f32x4 acc[8] = {zf, zf, zf, zf, zf, zf, zf, zf};
#pragma unroll
    for (int s = 0; s < 8; ++s) {
      acc[s] = __builtin_amdgcn_mfma_f32_16x16x32_bf16(Ahi[s][0], Bh0, acc[s], 0, 0, 0);
      acc[s] = __builtin_amdgcn_mfma_f32_16x16x32_bf16(Ahi[s][1], Bh1, acc[s], 0, 0, 0);
    }
    const int candRow = cbase + c0 + w * 16 + col;
    const float sqcv = sqcLds[c0 + w * 16 + col] + 256.0f;
#pragma unroll
    for (int s = 0; s < 8; ++s) {
#pragma unroll
      for (int r = 0; r < 4; ++r) {
        float val = fmaf(-2.f, acc[s][r], sqcv);
        const int qrow = s * 16 + quad * 4 + r;  // D row = quad*4+reg
        if (val <= tau_l[s][r]) {  // ~2% of lanes
          unsigned slot = atomicAdd(&cntLds[qrow], 1u);
          if (slot < CAP)
            list[(size_t)(blockIdx.y * CAP + slot) * M_TOTAL + qbase + qrow] =
                (__float_as_uint(val) & 0xFFFFE000u) | (unsigned)candRow;
        }
      }
    }
    Bh0 = Nh0; Bh1 = Nh1;
  }
  __syncthreads();
  if (threadIdx.x < QT) {
    unsigned c = cntLds[threadIdx.x];
    cnt_ws[blockIdx.y * M_TOTAL + qbase + threadIdx.x] = c > CAP ? CAP : c;
  }
}

// ---------------------------------------------------------------------------
// K2ab: fused selection + MLP. 32 queries x 8 slices (1 partition each).
// Ph1: per-slice top-8 (coalesced; kept-20th >= true-20th, safe T).
// Ph2: 8-way merge -> 20th of kept -> guard T (+3 quanta for hi-only error).
// Ph3: rescan, collect quant <= T (~22/query).
// Ph4: 8 thr/query exact fp32 d2, sorted-5 each; merge top-20 -> nbrLds.
// Ph5 (fused former k2b): MLP via MFMA, 4 waves x 8 rounds over the block's
// 32 queries; nbr never leaves LDS; coalesced out store.
// ---------------------------------------------------------------------------
__global__ __launch_bounds__(256) void k2ab(
    const float* __restrict__ pos, const float* __restrict__ sq,
    const unsigned* __restrict__ list, const unsigned* __restrict__ cnt_ws,
    const float* __restrict__ a_in, const float* __restrict__ g_in,
    const unsigned short* __restrict__ w2sw, const float* __restrict__ b2,
    float* __restrict__ out) {
  __shared__ unsigned topLds[NSLICE][QT2][9];           // 9.2 KiB (pad 9)
  __shared__ unsigned TLds[QT2];
  __shared__ unsigned ccnt[QT2];
  __shared__ unsigned candLds[QT2][GCAP];               // 5.1 KiB
  __shared__ unsigned long long rrLds[NSLICE][QT2][6];  // 12.3 KiB (pad 6)
  __shared__ int nbrLds[QT2][KNN];                      // 2.5 KiB

  const int l = threadIdx.x & 31;   // query lane
  const int s = threadIdx.x >> 5;   // slice: partition s
  const int q = blockIdx.x * QT2 + l;

  // ---- phase 1: per-slice top-8 over collected keys (chunked loads) ----
  unsigned bd[8];
#pragma unroll
  for (int k = 0; k < 8; ++k) bd[k] = 0xFFFFFFFFu;
  {
    const unsigned c = cnt_ws[s * M_TOTAL + q];
    const unsigned* base = list + (size_t)(s * CAP) * M_TOTAL + q;
    for (unsigned sl0 = 0; sl0 < c; sl0 += 8) {
      unsigned kk[8];
#pragma unroll
      for (int j = 0; j < 8; ++j) {
        unsigned slj = sl0 + j;
        kk[j] = base[(size_t)(slj < c ? slj : 0) * M_TOTAL];  // 8 loads in flight
      }
#pragma unroll
      for (int j = 0; j < 8; ++j) {
        unsigned cd = (sl0 + j < c) ? kk[j] : 0xFFFFFFFFu;
#pragma unroll
        for (int k = 0; k < 8; ++k) {
          unsigned lo = cd < bd[k] ? cd : bd[k];
          cd = cd < bd[k] ? bd[k] : cd;
          bd[k] = lo;
        }
      }
    }
  }
#pragma unroll
  for (int k = 0; k < 8; ++k) topLds[s][l][k] = bd[k];
  __syncthreads();

  // ---- phase 2: 8-way merge -> 20th of kept -> guard T ----
  if (threadIdx.x < QT2) {
    int ix[8] = {0, 0, 0, 0, 0, 0, 0, 0};
    unsigned m = 0;
    for (int k = 0; k < KNN; ++k) {
      unsigned best = 0xFFFFFFFFu;
      int bs = 0;
#pragma unroll
      for (int st = 0; st < 8; ++st) {
        unsigned v = (ix[st] < 8) ? topLds[st][l][ix[st]] : 0xFFFFFFFFu;
        if (v < best) { best = v; bs = st; }
      }
      ix[bs]++;
      m = best;
    }
    TLds[l] = (m >> 13) + 3;
    ccnt[l] = 0;
  }
  __syncthreads();

  // ---- phase 3: rescan, collect guard set (chunked loads) ----
  const unsigned T = TLds[l];
  {
    const unsigned c = cnt_ws[s * M_TOTAL + q];
    const unsigned* base = list + (size_t)(s * CAP) * M_TOTAL + q;
    for (unsigned sl0 = 0; sl0 < c; sl0 += 8) {
      unsigned kk[8];
#pragma unroll
      for (int j = 0; j < 8; ++j) {
        unsigned slj = sl0 + j;
        kk[j] = base[(size_t)(slj < c ? slj : 0) * M_TOTAL];
      }
#pragma unroll
      for (int j = 0; j < 8; ++j) {
        if (sl0 + j < c && (kk[j] >> 13) <= T) {
          unsigned pos_ = atomicAdd(&ccnt[l], 1u);
          if (pos_ < GCAP) candLds[l][pos_] = kk[j] & 0x1FFFu;
        }
      }
    }
  }
  __syncthreads();

  // ---- phase 4: exact fp32 d2 re-rank of the guard set ----
  const int cc = min(ccnt[l], (unsigned)GCAP);
  const float sqq = sq[q];
  const float4* qp4 = reinterpret_cast<const float4*>(pos + (size_t)q * 64);
  unsigned long long kb[5];
#pragma unroll
  for (int j = 0; j < 5; ++j) kb[j] = ~0ull;
  for (int j = s; j < cc; j += NSLICE) {
    const unsigned idx = candLds[l][j];
    const float4* cp4 = reinterpret_cast<const float4*>(pos + (size_t)idx * 64);
    float d0 = 0.f, d1 = 0.f, d2 = 0.f, d3 = 0.f;
#pragma unroll
    for (int t = 0; t < 16; ++t) {
      float4 cv = cp4[t];
      float4 qv = qp4[t];  // L1/L2-hot
      d0 = fmaf(cv.x, qv.x, d0);
      d1 = fmaf(cv.y, qv.y, d1);
      d2 = fmaf(cv.z, qv.z, d2);
      d3 = fmaf(cv.w, qv.w, d3);
    }
    float dot = (d0 + d1) + (d2 + d3);
    float dd = fmaxf(fmaf(-2.f, dot, sqq + sq[idx]), 0.f);
    unsigned long long cd = ((unsigned long long)__float_as_uint(dd) << 32) | idx;
#pragma unroll
    for (int k = 0; k < 5; ++k) {  // sorted-5 insert (tie -> smaller idx)
      unsigned long long lo = cd < kb[k] ? cd : kb[k];
      cd = cd < kb[k] ? kb[k] : cd;
      kb[k] = lo;
    }
  }
#pragma unroll
  for (int j = 0; j < 5; ++j) rrLds[s][l][j] = kb[j];
  __syncthreads();

  if (threadIdx.x < QT2) {
    int ix[8] = {0, 0, 0, 0, 0, 0, 0, 0};
    for (int k = 0; k < KNN; ++k) {
      unsigned long long best = ~0ull;
      int bs = 0;
#pragma unroll
      for (int st = 0; st < 8; ++st) {
        unsigned long long v = (ix[st] < 5) ? rrLds[st][l][ix[st]] : ~0ull;
        if (v < best) { best = v; bs = st; }
      }
      ix[bs]++;
      nbrLds[l][k] = (int)(unsigned)(best & 0xFFFFFFFFu);
    }
  }
  __syncthreads();

  // ---- phase 5 (fused k2b): MLP + max-agg via MFMA, 4 waves x 8 rounds ----
  const int lane = threadIdx.x & 63;
  const int wv = threadIdx.x >> 6;
  const int col = lane & 15;
  const int quad = lane >> 4;

  bf16x8 Bf[8];
#pragma unroll
  for (int f = 0; f < 8; ++f)
    Bf[f] = *(const bf16x8*)(w2sw + ((size_t)f * 64 + lane) * 8);
  const float bias = b2[lane];

  for (int t = 0; t < 8; ++t) {
    const int li = t * 4 + wv;                 // local query 0..31
    const int q2 = blockIdx.x * QT2 + li;
    const int n0 = nbrLds[li][col];
    const int n1 = nbrLds[li][(16 + col) % KNN];

    const f32x4 zf = {0.f, 0.f, 0.f, 0.f};
    f32x4 acc0[4] = {zf, zf, zf, zf};
    f32x4 acc1[4] = {zf, zf, zf, zf};
#pragma unroll
    for (int seg = 0; seg < 2; ++seg) {
      const int dOff = seg * 32 + quad * 8;
      const float4* ap = reinterpret_cast<const float4*>(a_in + (size_t)q2 * 64 + dOff);
      const float4* g0p = reinterpret_cast<const float4*>(g_in + (size_t)n0 * 64 + dOff);
      const float4* g1p = reinterpret_cast<const float4*>(g_in + (size_t)n1 * 64 + dOff);
      float4 aa0 = ap[0], aa1 = ap[1];
      float4 gg0 = g0p[0], gg1 = g0p[1];
      float4 hh0 = g1p[0], hh1 = g1p[1];
      float av[8] = {aa0.x, aa0.y, aa0.z, aa0.w, aa1.x, aa1.y, aa1.z, aa1.w};
      float g0v[8] = {gg0.x, gg0.y, gg0.z, gg0.w, gg1.x, gg1.y, gg1.z, gg1.w};
      float g1v[8] = {hh0.x, hh0.y, hh0.z, hh0.w, hh1.x, hh1.y, hh1.z, hh1.w};
      bf16x8 A0, A1;
#pragma unroll
      for (int j = 0; j < 8; ++j) {
        A0[j] = (short)bf16rne(fmaxf(av[j] + g0v[j], 0.f));
        A1[j] = (short)bf16rne(fmaxf(av[j] + g1v[j], 0.f));
      }
#pragma unroll
      for (int tt = 0; tt < 4; ++tt) {
        acc0[tt] = __builtin_amdgcn_mfma_f32_16x16x32_bf16(A0, Bf[seg * 4 + tt], acc0[tt], 0, 0, 0);
        acc1[tt] = __builtin_amdgcn_mfma_f32_16x16x32_bf16(A1, Bf[seg * 4 + tt], acc1[tt], 0, 0, 0);
      }
    }
    float res = 0.f;
#pragma unroll
    for (int tt = 0; tt < 4; ++tt) {
      float m = fmaxf(fmaxf(fmaxf(acc0[tt][0], acc1[tt][0]), fmaxf(acc0[tt][1], acc1[tt][1])),
                      fmaxf(fmaxf(acc0[tt][2], acc1[tt][2]), fmaxf(acc0[tt][3], acc1[tt][3])));
      m = fmaxf(m, __shfl_xor(m, 16, 64));
      m = fmaxf(m, __shfl_xor(m, 32, 64));
      res = (quad == tt) ? m : res;  // o = tt*16+col == lane iff quad==tt
    }
    out[(size_t)q2 * 64 + lane] = res + bias;
  }
}

// ---------------------------------------------------------------------------
extern "C" void kernel_launch(void* const* d_in, const int* in_sizes, int n_in,
                              void* d_out, int out_size, void* d_ws, size_t ws_size,
                              hipStream_t stream) {
  const float* pos = (const float*)d_in[0];
  const float* feat = (const float*)d_in[1];
  const float* W1 = (const float*)d_in[2];
  const float* b1 = (const float*)d_in[3];
  const float* W2 = (const float*)d_in[4];
  const float* b2 = (const float*)d_in[5];
  float* out = (float*)d_out;

  // ws layout (bytes), total ~23.3 MiB:
  //   sq    @ 0         32 KiB
  //   a     @ 32768     2 MiB
  //   g     @ 2129920   2 MiB
  //   poshi @ 4227072   1 MiB
  //   w2sw  @ 6324224   8 KiB
  //   list  @ 6332416   16 MiB  (512 slots x 8192 queries, transposed u32 keys)
  //   cnt   @ 23109632  256 KiB (8 x 8192, transposed)
  //   tau   @ 23633920  32 KiB
  char* ws = (char*)d_ws;
  float* sq = (float*)ws;
  float* a = (float*)(ws + 32768);
  float* g = (float*)(ws + 2129920);
  unsigned short* poshi = (unsigned short*)(ws + 4227072);
  unsigned short* w2sw = (unsigned short*)(ws + 6324224);
  unsigned* list = (unsigned*)(ws + 6332416);
  unsigned* cnt_ws = (unsigned*)(ws + 23109632);
  float* tau_g = (float*)(ws + 23633920);

  k0_pre<<<M_TOTAL / 4, 256, 0, stream>>>(pos, feat, W1, b1, W2, sq, a, g, poshi, w2sw);
  k1a_tau<<<M_TOTAL / QT1A, 256, 0, stream>>>(poshi, sq, tau_g);
  k1b_collect<<<dim3(M_TOTAL / QT, PPART), 256, 0, stream>>>(poshi, sq, tau_g, list, cnt_ws);
  k2ab<<<M_TOTAL / QT2, 256, 0, stream>>>(pos, sq, list, cnt_ws, a, g, w2sw, b2, out);
}